// Round 1
// baseline (2908.322 us; speedup 1.0000x reference)
//
#include <hip/hip_runtime.h>
#include <math.h>

// ---------------- constants ----------------
constexpr int Bsz = 8, HIMG = 24, WIMG = 24;
constexpr int Lq = 576;              // H*W
constexpr int WIDTH = 1024, NCH = 8, CW = 128;
constexpr int NHEADS = 8, HD = 16, HALF = 8;
constexpr int NFREQ = 32, HIDDEN = 4096;
constexpr float EPS = 1e-6f;
constexpr float LAMINIT = 0.2f;       // 0.8 - 0.6*exp(0)
constexpr int ROWS = Bsz * Lq;        // 4608

// workspace layout (float offsets)
constexpr long O_H   = 0;                       // 4608*1024
constexpr long O_G2  = O_H  + (long)ROWS*WIDTH; // 4608*1024
constexpr long O_T   = O_G2 + (long)ROWS*WIDTH; // 1152*4096 chunk / per-ch bufs
constexpr long O_POS = O_T  + 1152L*4096;       // 576*1024
constexpr long O_ENC = O_POS + (long)Lq*WIDTH;  // 576*128
constexpr long O_SE  = O_ENC + (long)Lq*128;    // 8*1024
constexpr long O_S2  = O_SE + Bsz*WIDTH;        // 8*1024
constexpr long O_RW  = O_S2 + Bsz*WIDTH;        // 64
constexpr long O_LAM = O_RW + 64;               // 8
// total ~14.84M floats ~= 59.4 MB

// per-channel sub-buffers inside O_T region (4718592 floats available)
constexpr long SZ_QKV = (long)ROWS * 384;          // 1769472
constexpr long SZ_O   = (long)Bsz*NHEADS*Lq*HD;    // 589824
constexpr long SZ_DC  = (long)ROWS * CW;           // 589824

// ---------------- helpers ----------------
__device__ __forceinline__ float blockReduceSum256(float v, float* red) {
  #pragma unroll
  for (int off = 32; off; off >>= 1) v += __shfl_down(v, off, 64);
  int lane = threadIdx.x & 63, wid = threadIdx.x >> 6;
  if (lane == 0) red[wid] = v;
  __syncthreads();
  float total = 0.f;
  #pragma unroll
  for (int i = 0; i < 4; i++) total += red[i];
  return total;
}

__device__ __forceinline__ float silu(float x) { return x / (1.f + __expf(-x)); }

// ---------------- positional encoding ----------------
__global__ void k_enc(const float* __restrict__ fh, const float* __restrict__ fw,
                      const float* __restrict__ ph, const float* __restrict__ pw,
                      float* __restrict__ enc) {
  int idx = blockIdx.x * blockDim.x + threadIdx.x;
  if (idx >= Lq * 4 * NFREQ) return;
  int l = idx >> 7, c = idx & 127;
  int hh = l / WIMG, ww = l % WIMG;
  float v;
  if (c < 64) {
    int f = c & 31;
    float fr = log1pf(__expf(fh[f])) * 10.f;
    float a = (hh / (float)HIMG) * fr + ph[f];
    v = (c < 32) ? sinf(a) : cosf(a);
  } else {
    int f = c & 31;
    float fr = log1pf(__expf(fw[f])) * 10.f;
    float a = (ww / (float)WIMG) * fr + pw[f];
    v = (c < 96) ? sinf(a) : cosf(a);
  }
  enc[idx] = v;
}

// ---------------- generic tiled GEMM: C = act(A@W + bias) ----------------
// A: M x K (lda), W: K x N (ldw), C: M x N (ldc). M%64==0, N%64==0, K%16==0 assumed for loads.
template <int ACT>  // 0 = none, 1 = silu
__global__ __launch_bounds__(256) void gemm_k(
    const float* __restrict__ A, int lda,
    const float* __restrict__ W, int ldw,
    const float* __restrict__ bias,
    float* __restrict__ C, int ldc,
    int M, int N, int K) {
  __shared__ float As[16][64];
  __shared__ float Ws[16][64];
  int tid = threadIdx.x;
  int tx = tid & 15, ty = tid >> 4;
  int m0 = blockIdx.y * 64, n0 = blockIdx.x * 64;
  float acc[4][4] = {};
  for (int k0 = 0; k0 < K; k0 += 16) {
    {
      int m = tid >> 2, kk = (tid & 3) * 4;
      const float4 av = *(const float4*)(A + (long)(m0 + m) * lda + k0 + kk);
      As[kk + 0][m] = av.x; As[kk + 1][m] = av.y; As[kk + 2][m] = av.z; As[kk + 3][m] = av.w;
    }
    {
      int k = tid >> 4, n = (tid & 15) * 4;
      const float4 wv = *(const float4*)(W + (long)(k0 + k) * ldw + n0 + n);
      Ws[k][n] = wv.x; Ws[k][n + 1] = wv.y; Ws[k][n + 2] = wv.z; Ws[k][n + 3] = wv.w;
    }
    __syncthreads();
    #pragma unroll
    for (int k = 0; k < 16; k++) {
      float a[4], b[4];
      #pragma unroll
      for (int i = 0; i < 4; i++) a[i] = As[k][ty * 4 + i];
      #pragma unroll
      for (int j = 0; j < 4; j++) b[j] = Ws[k][tx * 4 + j];
      #pragma unroll
      for (int i = 0; i < 4; i++)
        #pragma unroll
        for (int j = 0; j < 4; j++) acc[i][j] += a[i] * b[j];
    }
    __syncthreads();
  }
  #pragma unroll
  for (int i = 0; i < 4; i++) {
    int m = m0 + ty * 4 + i;
    if (m >= M) continue;
    #pragma unroll
    for (int j = 0; j < 4; j++) {
      int n = n0 + tx * 4 + j;
      if (n >= N) continue;
      float v = acc[i][j] + (bias ? bias[n] : 0.f);
      if (ACT == 1) v = silu(v);
      C[(long)m * ldc + n] = v;
    }
  }
}

// ---------------- embed + rmsnorm ----------------
__global__ __launch_bounds__(256) void k_embed(const float* __restrict__ x,
    const float* __restrict__ emb, const float* __restrict__ pos,
    const float* __restrict__ nw, float* __restrict__ h) {
  __shared__ float red[4];
  int row = blockIdx.x;           // b*L + l
  int l = row % Lq;
  int xi = (int)(x[row] * 255.f);
  xi = min(max(xi, 0), 255);
  const float* er = emb + (long)xi * WIDTH;
  const float* pr = pos + (long)l * WIDTH;
  int c0 = threadIdx.x * 4;
  float v[4]; float ss = 0.f;
  #pragma unroll
  for (int i = 0; i < 4; i++) { v[i] = er[c0 + i] + pr[c0 + i]; ss += v[i] * v[i]; }
  ss = blockReduceSum256(ss, red);
  float r = rsqrtf(ss / WIDTH + EPS);
  float* hr = h + (long)row * WIDTH;
  #pragma unroll
  for (int i = 0; i < 4; i++) hr[c0 + i] = v[i] * r * nw[c0 + i];
}

// ---------------- mean over L ----------------
__global__ void k_meanl(const float* __restrict__ h, float* __restrict__ s) {
  int idx = blockIdx.x * blockDim.x + threadIdx.x;   // b*1024 + c
  if (idx >= Bsz * WIDTH) return;
  int b = idx >> 10, c = idx & 1023;
  const float* p = h + (long)b * Lq * WIDTH + c;
  float acc = 0.f;
  for (int l = 0; l < Lq; l++) acc += p[(long)l * WIDTH];
  s[idx] = acc / Lq;
}

// ---------------- SE block: s = sigmoid(silu(s@w1+b1)@w2+b2) ----------------
__global__ __launch_bounds__(256) void k_se(float* __restrict__ s,
    const float* __restrict__ w1, const float* __restrict__ b1,
    const float* __restrict__ w2, const float* __restrict__ b2) {
  __shared__ float sv[WIDTH];
  __shared__ float t1[256];
  int b = blockIdx.x, tid = threadIdx.x;
  for (int c = tid; c < WIDTH; c += 256) sv[c] = s[b * WIDTH + c];
  __syncthreads();
  float acc = b1[tid];
  for (int c = 0; c < WIDTH; c++) acc += sv[c] * w1[c * 256 + tid];
  t1[tid] = silu(acc);
  __syncthreads();
  for (int j = tid; j < WIDTH; j += 256) {
    float a = b2[j];
    for (int c = 0; c < 256; c++) a += t1[c] * w2[c * WIDTH + j];
    s[b * WIDTH + j] = 1.f / (1.f + __expf(-a));
  }
}

// ---------------- mix: h += rmsnorm(h*(s-1), mw) ----------------
__global__ __launch_bounds__(256) void k_mix(float* __restrict__ h,
    const float* __restrict__ s, const float* __restrict__ mw) {
  __shared__ float red[4];
  int row = blockIdx.x;
  int b = row / Lq;
  float* hr = h + (long)row * WIDTH;
  const float* sb = s + b * WIDTH;
  int c0 = threadIdx.x * 4;
  float y[4]; float ss = 0.f;
  #pragma unroll
  for (int i = 0; i < 4; i++) { float hv = hr[c0 + i]; y[i] = hv * (sb[c0 + i] - 1.f); ss += y[i] * y[i]; }
  ss = blockReduceSum256(ss, red);
  float r = rsqrtf(ss / WIDTH + EPS);
  #pragma unroll
  for (int i = 0; i < 4; i++) hr[c0 + i] += y[i] * r * mw[c0 + i];
}

// ---------------- h += rmsnorm(g, mw) ----------------
__global__ __launch_bounds__(256) void k_addnorm(float* __restrict__ h,
    const float* __restrict__ g, const float* __restrict__ mw) {
  __shared__ float red[4];
  int row = blockIdx.x;
  float* hr = h + (long)row * WIDTH;
  const float* gr = g + (long)row * WIDTH;
  int c0 = threadIdx.x * 4;
  float y[4]; float ss = 0.f;
  #pragma unroll
  for (int i = 0; i < 4; i++) { y[i] = gr[c0 + i]; ss += y[i] * y[i]; }
  ss = blockReduceSum256(ss, red);
  float r = rsqrtf(ss / WIDTH + EPS);
  #pragma unroll
  for (int i = 0; i < 4; i++) hr[c0 + i] += y[i] * r * mw[c0 + i];
}

// ---------------- router: logits -> top4 softmax scatter; also lambda per channel ----------------
__global__ void k_router(const float* __restrict__ s2, const float* __restrict__ rwgt,
    const float* __restrict__ rb,
    const float* __restrict__ lq1, const float* __restrict__ lk1,
    const float* __restrict__ lq2, const float* __restrict__ lk2,
    float* __restrict__ rw, float* __restrict__ lam) {
  __shared__ float lg[64];
  int t = threadIdx.x;   // 64 threads
  int b = t >> 3, j = t & 7;
  float acc = rb[j];
  const float* sb = s2 + b * WIDTH;
  for (int c = 0; c < WIDTH; c++) acc += sb[c] * rwgt[c * 8 + j];
  lg[t] = acc;
  __syncthreads();
  if (t < 8) {
    float v[8]; bool sel[8];
    #pragma unroll
    for (int i = 0; i < 8; i++) { v[i] = lg[t * 8 + i]; sel[i] = false; }
    int idxs[4]; float vals[4];
    for (int s = 0; s < 4; s++) {
      int bi = -1; float bv = -1e30f;
      for (int i = 0; i < 8; i++) if (!sel[i] && v[i] > bv) { bv = v[i]; bi = i; }
      sel[bi] = true; idxs[s] = bi; vals[s] = bv;
    }
    float m = vals[0], den = 0.f, e[4];
    for (int s = 0; s < 4; s++) { e[s] = __expf(vals[s] - m); den += e[s]; }
    for (int i = 0; i < 8; i++) rw[t * 8 + i] = 0.f;
    for (int s = 0; s < 4; s++) rw[t * 8 + idxs[s]] = e[s] / den;
    // lambda for channel t
    float d1 = 0.f, d2 = 0.f;
    for (int i = 0; i < 8; i++) { d1 += lq1[t * 8 + i] * lk1[t * 8 + i]; d2 += lq2[t * 8 + i] * lk2[t * 8 + i]; }
    lam[t] = __expf(d1) - __expf(d2) + LAMINIT;
  }
}

// ---------------- q/k rmsnorm (in place, per 8-elem half) ----------------
__device__ __forceinline__ void norm8(float* p, const float* w) {
  float ss = 0.f;
  #pragma unroll
  for (int i = 0; i < 8; i++) ss += p[i] * p[i];
  float r = rsqrtf(ss / 8.f + EPS);
  #pragma unroll
  for (int i = 0; i < 8; i++) p[i] = p[i] * r * w[i];
}

__global__ __launch_bounds__(256) void k_qknorm(float* __restrict__ qkv,
    const float* __restrict__ qn, const float* __restrict__ kn) {
  int idx = blockIdx.x * blockDim.x + threadIdx.x;  // row*8 + head
  if (idx >= ROWS * NHEADS) return;
  int row = idx >> 3, head = idx & 7;
  float* q = qkv + (long)row * 384 + head * 16;
  float* k = q + 128;
  norm8(q, qn); norm8(q + 8, qn);
  norm8(k, kn); norm8(k + 8, kn);
}

// ---------------- causal attention (one block per (which, head, b)) ----------------
__global__ __launch_bounds__(256) void k_attn(const float* __restrict__ qkv, float* __restrict__ o_base) {
  __shared__ float sk[Lq * HALF];
  __shared__ float sv[Lq * HD];
  int which = blockIdx.x, head = blockIdx.y, b = blockIdx.z;
  int tid = threadIdx.x;
  const float* qkvb = qkv + (long)b * Lq * 384;
  for (int i = tid; i < Lq * HALF; i += 256) {
    int l = i >> 3, d = i & 7;
    sk[i] = qkvb[(long)l * 384 + 128 + head * 16 + which * 8 + d];
  }
  for (int i = tid; i < Lq * HD; i += 256) {
    int l = i >> 4, d = i & 15;
    sv[i] = qkvb[(long)l * 384 + 256 + head * 16 + d];
  }
  __syncthreads();
  const float scale = 0.35355339059327373f;  // 1/sqrt(8)
  float* o = o_base + (long)which * SZ_O;
  for (int qi = tid; qi < Lq; qi += 256) {
    float qv[8];
    const float* qp = qkvb + (long)qi * 384 + head * 16 + which * 8;
    #pragma unroll
    for (int d = 0; d < 8; d++) qv[d] = qp[d];
    float accv[16];
    #pragma unroll
    for (int d = 0; d < 16; d++) accv[d] = 0.f;
    float den = 0.f;
    for (int j = 0; j <= qi; j++) {
      const float* kr = sk + j * 8;
      float sdot = 0.f;
      #pragma unroll
      for (int d = 0; d < 8; d++) sdot += qv[d] * kr[d];
      float e = __expf(sdot * scale);
      den += e;
      const float* vr = sv + j * 16;
      #pragma unroll
      for (int d = 0; d < 16; d++) accv[d] += e * vr[d];
    }
    float inv = 1.f / den;
    float* op = o + ((long)(b * NHEADS + head) * Lq + qi) * HD;
    #pragma unroll
    for (int d = 0; d < 16; d++) op[d] = accv[d] * inv;
  }
}

// ---------------- combine: dcomb = rmsnorm(o1 - lam*o2, hn_w) * 0.8 ----------------
__global__ __launch_bounds__(256) void k_combine(const float* __restrict__ o1,
    const float* __restrict__ o2, const float* __restrict__ hnw,
    const float* __restrict__ lam, int ch, float* __restrict__ dc) {
  int idx = blockIdx.x * blockDim.x + threadIdx.x;  // row*8 + head
  if (idx >= ROWS * NHEADS) return;
  int row = idx >> 3, head = idx & 7;
  int b = row / Lq, l = row % Lq;
  float lm = lam[ch];
  const float* p1 = o1 + ((long)(b * NHEADS + head) * Lq + l) * HD;
  const float* p2 = o2 + ((long)(b * NHEADS + head) * Lq + l) * HD;
  float d[16]; float ss = 0.f;
  #pragma unroll
  for (int i = 0; i < 16; i++) { d[i] = p1[i] - lm * p2[i]; ss += d[i] * d[i]; }
  float r = rsqrtf(ss / HD + EPS);
  float* out = dc + (long)row * CW + head * HD;
  #pragma unroll
  for (int i = 0; i < 16; i++) out[i] = d[i] * r * hnw[i] * (1.f - LAMINIT);
}

// ---------------- seg: g2 = (h_ch + rmsnorm(oproj, segw)) * rw ----------------
__global__ __launch_bounds__(128) void k_seg(const float* __restrict__ h,
    const float* __restrict__ op, const float* __restrict__ segw,
    const float* __restrict__ rw, int ch, float* __restrict__ g2) {
  __shared__ float red[2];
  int row = blockIdx.x;
  int b = row / Lq;
  int c = threadIdx.x;  // 128 threads
  float y = op[(long)row * CW + c];
  float ss = y * y;
  #pragma unroll
  for (int off = 32; off; off >>= 1) ss += __shfl_down(ss, off, 64);
  int lane = c & 63, wid = c >> 6;
  if (lane == 0) red[wid] = ss;
  __syncthreads();
  float tot = red[0] + red[1];
  float r = rsqrtf(tot / CW + EPS);
  float hv = h[(long)row * WIDTH + ch * CW + c];
  float outv = (hv + y * r * segw[c]) * rw[b * NCH + ch];
  g2[(long)row * WIDTH + ch * CW + c] = outv;
}

// ---------------- head: out = pooled @ head_w + head_b ----------------
__global__ void k_head(const float* __restrict__ pooled, const float* __restrict__ hw,
                       const float* __restrict__ hb, float* __restrict__ out) {
  int t = threadIdx.x;
  if (t >= Bsz * 10) return;
  int b = t / 10, j = t % 10;
  float acc = hb[j];
  const float* p = pooled + b * WIDTH;
  for (int c = 0; c < WIDTH; c++) acc += p[c] * hw[c * 10 + j];
  out[t] = acc;
}

// ---------------- launcher ----------------
extern "C" void kernel_launch(void* const* d_in, const int* in_sizes, int n_in,
                              void* d_out, int out_size, void* d_ws, size_t ws_size,
                              hipStream_t stream) {
  const float* x          = (const float*)d_in[0];
  // d_in[1] = top_k (always 4)
  const float* pixel_embed= (const float*)d_in[2];
  const float* freq_h     = (const float*)d_in[3];
  const float* freq_w     = (const float*)d_in[4];
  const float* phase_h    = (const float*)d_in[5];
  const float* phase_w    = (const float*)d_in[6];
  const float* pos_proj_w = (const float*)d_in[7];
  const float* pos_proj_b = (const float*)d_in[8];
  const float* embed_norm = (const float*)d_in[9];
  const float* se_w1      = (const float*)d_in[10];
  const float* se_b1      = (const float*)d_in[11];
  const float* se_w2      = (const float*)d_in[12];
  const float* se_b2      = (const float*)d_in[13];
  const float* mix_norm   = (const float*)d_in[14];
  const float* mlp_w1     = (const float*)d_in[15];
  const float* mlp_b1     = (const float*)d_in[16];
  const float* mlp_w2     = (const float*)d_in[17];
  const float* mlp_b2     = (const float*)d_in[18];
  const float* mlp_norm   = (const float*)d_in[19];
  const float* router_w   = (const float*)d_in[20];
  const float* router_b   = (const float*)d_in[21];
  const float* qkv_w      = (const float*)d_in[22];
  const float* qkv_b      = (const float*)d_in[23];
  const float* q_norm_w   = (const float*)d_in[24];
  const float* k_norm_w   = (const float*)d_in[25];
  const float* head_norm_w= (const float*)d_in[26];
  const float* lam_q1     = (const float*)d_in[27];
  const float* lam_k1     = (const float*)d_in[28];
  const float* lam_q2     = (const float*)d_in[29];
  const float* lam_k2     = (const float*)d_in[30];
  const float* out_w      = (const float*)d_in[31];
  const float* out_b      = (const float*)d_in[32];
  const float* seg_norm_w = (const float*)d_in[33];
  const float* head_w     = (const float*)d_in[34];
  const float* head_b     = (const float*)d_in[35];
  float* ws  = (float*)d_ws;
  float* out = (float*)d_out;

  // 1. positional encoding features + projection
  k_enc<<<288, 256, 0, stream>>>(freq_h, freq_w, phase_h, phase_w, ws + O_ENC);
  gemm_k<0><<<dim3(16, 9), 256, 0, stream>>>(ws + O_ENC, 128, pos_proj_w, 1024,
                                             pos_proj_b, ws + O_POS, 1024, Lq, 1024, 128);
  // 2. embed + rmsnorm
  k_embed<<<ROWS, 256, 0, stream>>>(x, pixel_embed, ws + O_POS, embed_norm, ws + O_H);
  // 3. SE gate
  k_meanl<<<32, 256, 0, stream>>>(ws + O_H, ws + O_SE);
  k_se<<<Bsz, 256, 0, stream>>>(ws + O_SE, se_w1, se_b1, se_w2, se_b2);
  k_mix<<<ROWS, 256, 0, stream>>>(ws + O_H, ws + O_SE, mix_norm);
  // 4. MLP (chunked: 4 x 1152 rows to keep ws small)
  for (int c = 0; c < 4; c++) {
    gemm_k<1><<<dim3(64, 18), 256, 0, stream>>>(ws + O_H + (long)c * 1152 * 1024, 1024,
        mlp_w1, 4096, mlp_b1, ws + O_T, 4096, 1152, 4096, 1024);
    gemm_k<0><<<dim3(16, 18), 256, 0, stream>>>(ws + O_T, 4096,
        mlp_w2, 1024, mlp_b2, ws + O_G2 + (long)c * 1152 * 1024, 1024, 1152, 1024, 4096);
  }
  k_addnorm<<<ROWS, 256, 0, stream>>>(ws + O_H, ws + O_G2, mlp_norm);
  // 5. router + lambdas
  k_meanl<<<32, 256, 0, stream>>>(ws + O_H, ws + O_S2);
  k_router<<<1, 64, 0, stream>>>(ws + O_S2, router_w, router_b,
                                 lam_q1, lam_k1, lam_q2, lam_k2, ws + O_RW, ws + O_LAM);
  // 6. per-channel differential attention
  for (int ch = 0; ch < NCH; ch++) {
    float* qkvB = ws + O_T;
    float* o1B  = qkvB + SZ_QKV;
    float* dcB  = o1B + 2 * SZ_O;
    float* opB  = dcB + SZ_DC;
    gemm_k<1><<<dim3(6, 72), 256, 0, stream>>>(ws + O_H + ch * CW, 1024,
        qkv_w + (long)ch * 128 * 384, 384, qkv_b + ch * 384, qkvB, 384, ROWS, 384, 128);
    k_qknorm<<<144, 256, 0, stream>>>(qkvB, q_norm_w + ch * 8, k_norm_w + ch * 8);
    k_attn<<<dim3(2, NHEADS, Bsz), 256, 0, stream>>>(qkvB, o1B);
    k_combine<<<144, 256, 0, stream>>>(o1B, o1B + SZ_O, head_norm_w + ch * 16,
                                       ws + O_LAM, ch, dcB);
    gemm_k<1><<<dim3(2, 72), 256, 0, stream>>>(dcB, 128,
        out_w + (long)ch * 128 * 128, 128, out_b + ch * 128, opB, 128, ROWS, 128, 128);
    k_seg<<<ROWS, 128, 0, stream>>>(ws + O_H, opB, seg_norm_w + ch * 128,
                                    ws + O_RW, ch, ws + O_G2);
  }
  // 7. pool + head
  k_meanl<<<32, 256, 0, stream>>>(ws + O_G2, ws + O_S2);
  k_head<<<1, 128, 0, stream>>>(ws + O_S2, head_w, head_b, out);
}

// Round 2
// 939.329 us; speedup vs baseline: 3.0962x; 3.0962x over previous
//
#include <hip/hip_runtime.h>
#include <math.h>

typedef __bf16 bf16;
typedef __bf16 bf16x8 __attribute__((ext_vector_type(8)));
typedef float f32x4 __attribute__((ext_vector_type(4)));

// ---------------- constants ----------------
constexpr int Bsz = 8, HIMG = 24, WIMG = 24;
constexpr int Lq = 576;
constexpr int WIDTH = 1024, NCH = 8, CW = 128;
constexpr int NHEADS = 8, HD = 16, HALF = 8;
constexpr int HIDDEN = 4096;
constexpr float EPS = 1e-6f;
constexpr float LAMINIT = 0.2f;
constexpr int ROWS = Bsz * Lq;              // 4608
constexpr long SZO = (long)Bsz * NHEADS * Lq * HD;  // 589824

// ---------------- workspace byte offsets ----------------
constexpr size_t B_HB    = 0;                        // bf16 h [4608][1024]
constexpr size_t B_G2B   = B_HB    + 9437184;        // bf16 g2 [4608][1024]
constexpr size_t B_ENCB  = B_G2B   + 9437184;        // bf16 enc [640][128]
constexpr size_t B_POSWT = B_ENCB  + 163840;         // bf16 [1024][128]
constexpr size_t B_QKVWT = B_POSWT + 262144;         // bf16 [8][384][128]
constexpr size_t B_OWT   = B_QKVWT + 786432;         // bf16 [8][128][128]
constexpr size_t B_SE    = B_OWT   + 262144;         // f32 [8][1024]
constexpr size_t B_S2    = B_SE    + 32768;          // f32 [8][1024]
constexpr size_t B_RW    = B_S2    + 32768;          // f32 [64]
constexpr size_t B_LAM   = B_RW    + 256;            // f32 [8]
constexpr size_t B_POOL  = B_LAM   + 256;            // phase-shared pool (~36 MB)
// pool (MLP phase):  W1T @+0 (8388608), W2T @+8388608, HID @+16777216 (18874368)
// pool (pos phase):  POS f32 @+0 (2621440)
// pool (chan phase): QKV @+0 (14155776), O12 @+14155776 (9437184),
//                    DC @+23592960 (4718592), OP @+28311552 (4718592)

// ---------------- helpers ----------------
__device__ __forceinline__ float blockReduceSum256(float v, float* red) {
  #pragma unroll
  for (int off = 32; off; off >>= 1) v += __shfl_down(v, off, 64);
  int lane = threadIdx.x & 63, wid = threadIdx.x >> 6;
  if (lane == 0) red[wid] = v;
  __syncthreads();
  float total = 0.f;
  #pragma unroll
  for (int i = 0; i < 4; i++) total += red[i];
  return total;
}
__device__ __forceinline__ float silu(float x) { return x / (1.f + __expf(-x)); }

__device__ __forceinline__ void gl16(const bf16* g, bf16* l) {
  __builtin_amdgcn_global_load_lds(
      (const __attribute__((address_space(1))) void*)g,
      (__attribute__((address_space(3))) void*)l, 16, 0, 0);
}

// ---------------- cast+transpose: W fp32 [K][N] -> Wt bf16 [N][K] ----------------
__global__ __launch_bounds__(256) void k_tcast(const float* __restrict__ W,
    bf16* __restrict__ Wt, int K, int N) {
  __shared__ float t[32][33];
  int n0 = blockIdx.x * 32, k0 = blockIdx.y * 32;
  long zo = (long)blockIdx.z * K * N;
  int tid = threadIdx.x;
  int r = tid >> 3, c4 = (tid & 7) * 4;
  const float4 v = *(const float4*)(W + zo + (long)(k0 + r) * N + n0 + c4);
  t[c4 + 0][r] = v.x; t[c4 + 1][r] = v.y; t[c4 + 2][r] = v.z; t[c4 + 3][r] = v.w;
  __syncthreads();
  bf16* dst = Wt + zo + (long)(n0 + r) * K + k0 + c4;
  dst[0] = (bf16)t[r][c4 + 0]; dst[1] = (bf16)t[r][c4 + 1];
  dst[2] = (bf16)t[r][c4 + 2]; dst[3] = (bf16)t[r][c4 + 3];
}

// ---------------- positional encoding (bf16 out) ----------------
__global__ void k_enc_b(const float* __restrict__ fh, const float* __restrict__ fw,
                        const float* __restrict__ ph, const float* __restrict__ pw,
                        bf16* __restrict__ enc) {
  int idx = blockIdx.x * blockDim.x + threadIdx.x;
  if (idx >= Lq * 128) return;
  int l = idx >> 7, c = idx & 127;
  int hh = l / WIMG, ww = l % WIMG;
  float v;
  if (c < 64) {
    int f = c & 31;
    float fr = log1pf(__expf(fh[f])) * 10.f;
    float a = (hh / (float)HIMG) * fr + ph[f];
    v = (c < 32) ? sinf(a) : cosf(a);
  } else {
    int f = c & 31;
    float fr = log1pf(__expf(fw[f])) * 10.f;
    float a = (ww / (float)WIMG) * fr + pw[f];
    v = (c < 96) ? sinf(a) : cosf(a);
  }
  enc[idx] = (bf16)v;
}

// ---------------- bf16 MFMA GEMM: C = act(A @ Bt^T + bias) ----------------
// A: bf16 M x K row-major (lda).  Bt: bf16 N x K row-major (ldb = K).
// 128x128 tile, BK=32, 4 waves, 16x16x32 MFMA, global_load_lds staging.
// Requires M%128==0, N%128==0, K%32==0, 16B-aligned rows.
template <int ACT, int OUTBF>   // ACT: 0 none, 1 silu.  OUTBF: 1 bf16 out, 0 f32 out
__global__ __launch_bounds__(256) void gemm_bt(
    const bf16* __restrict__ A, int lda, long aZs,
    const bf16* __restrict__ Bt, long bZs,
    const float* __restrict__ bias, int biasZs,
    void* __restrict__ Cv, int ldc, long cZs,
    int M, int N, int K) {
  __shared__ bf16 As[128 * 32];
  __shared__ bf16 Bs[128 * 32];
  int tid = threadIdx.x;
  int m0 = blockIdx.y * 128, n0 = blockIdx.x * 128;
  int z = blockIdx.z;
  const bf16* Ab = A + (long)z * aZs;
  const bf16* Bb = Bt + (long)z * bZs;
  f32x4 acc[4][4] = {};
  int wv = tid >> 6, lane = tid & 63;
  int wrow = (wv >> 1) * 64, wcol = (wv & 1) * 64;
  int lm = lane & 15, lq = lane >> 4;
  const bf16* ag = Ab + (long)(m0 + (tid >> 2)) * lda + (tid & 3) * 8;
  const bf16* bg = Bb + (long)(n0 + (tid >> 2)) * K + (tid & 3) * 8;
  bf16* asd = As + tid * 8;
  bf16* bsd = Bs + tid * 8;
  for (int k0 = 0; k0 < K; k0 += 32) {
    gl16(ag + k0, asd);
    gl16(ag + k0 + 64L * lda, asd + 2048);
    gl16(bg + k0, bsd);
    gl16(bg + k0 + 64L * K, bsd + 2048);
    __syncthreads();
    bf16x8 af[4], bfr[4];
    #pragma unroll
    for (int i = 0; i < 4; i++) {
      af[i]  = *(const bf16x8*)(As + (wrow + i * 16 + lm) * 32 + lq * 8);
      bfr[i] = *(const bf16x8*)(Bs + (wcol + i * 16 + lm) * 32 + lq * 8);
    }
    #pragma unroll
    for (int i = 0; i < 4; i++)
      #pragma unroll
      for (int j = 0; j < 4; j++)
        acc[i][j] = __builtin_amdgcn_mfma_f32_16x16x32_bf16(af[i], bfr[j], acc[i][j], 0, 0, 0);
    __syncthreads();
  }
  long cz = (long)z * cZs;
  const float* bz = bias ? bias + (long)z * biasZs : nullptr;
  #pragma unroll
  for (int i = 0; i < 4; i++) {
    int row = m0 + wrow + i * 16 + lq * 4;
    #pragma unroll
    for (int j = 0; j < 4; j++) {
      int col = n0 + wcol + j * 16 + lm;
      float bv = bz ? bz[col] : 0.f;
      #pragma unroll
      for (int r = 0; r < 4; r++) {
        float v = acc[i][j][r] + bv;
        if (ACT == 1) v = silu(v);
        long off = cz + (long)(row + r) * ldc + col;
        if (OUTBF) ((bf16*)Cv)[off] = (bf16)v;
        else       ((float*)Cv)[off] = v;
      }
    }
  }
}

// ---------------- embed + rmsnorm -> bf16 h ----------------
__global__ __launch_bounds__(256) void k_embed(const float* __restrict__ x,
    const float* __restrict__ emb, const float* __restrict__ pos,
    const float* __restrict__ nw, bf16* __restrict__ h) {
  __shared__ float red[4];
  int row = blockIdx.x;
  int l = row % Lq;
  int xi = (int)(x[row] * 255.f);
  xi = min(max(xi, 0), 255);
  const float* er = emb + (long)xi * WIDTH;
  const float* pr = pos + (long)l * WIDTH;
  int c0 = threadIdx.x * 4;
  float v[4]; float ss = 0.f;
  #pragma unroll
  for (int i = 0; i < 4; i++) { v[i] = er[c0 + i] + pr[c0 + i]; ss += v[i] * v[i]; }
  ss = blockReduceSum256(ss, red);
  float r = rsqrtf(ss / WIDTH + EPS);
  bf16* hr = h + (long)row * WIDTH;
  #pragma unroll
  for (int i = 0; i < 4; i++) hr[c0 + i] = (bf16)(v[i] * r * nw[c0 + i]);
}

// ---------------- mean over L (bf16 in, f32 out) ----------------
__global__ void k_meanl_b(const bf16* __restrict__ h, float* __restrict__ s) {
  int idx = blockIdx.x * blockDim.x + threadIdx.x;
  if (idx >= Bsz * WIDTH) return;
  int b = idx >> 10, c = idx & 1023;
  const bf16* p = h + (long)b * Lq * WIDTH + c;
  float acc = 0.f;
  for (int l = 0; l < Lq; l++) acc += (float)p[(long)l * WIDTH];
  s[idx] = acc / Lq;
}

// ---------------- SE block (fp32) ----------------
__global__ __launch_bounds__(256) void k_se(float* __restrict__ s,
    const float* __restrict__ w1, const float* __restrict__ b1,
    const float* __restrict__ w2, const float* __restrict__ b2) {
  __shared__ float sv[WIDTH];
  __shared__ float t1[256];
  int b = blockIdx.x, tid = threadIdx.x;
  for (int c = tid; c < WIDTH; c += 256) sv[c] = s[b * WIDTH + c];
  __syncthreads();
  float acc = b1[tid];
  for (int c = 0; c < WIDTH; c++) acc += sv[c] * w1[c * 256 + tid];
  t1[tid] = silu(acc);
  __syncthreads();
  for (int j = tid; j < WIDTH; j += 256) {
    float a = b2[j];
    for (int c = 0; c < 256; c++) a += t1[c] * w2[c * WIDTH + j];
    s[b * WIDTH + j] = 1.f / (1.f + __expf(-a));
  }
}

// ---------------- mix: h += rmsnorm(h*(s-1), mw)  (bf16 h) ----------------
__global__ __launch_bounds__(256) void k_mix_b(bf16* __restrict__ h,
    const float* __restrict__ s, const float* __restrict__ mw) {
  __shared__ float red[4];
  int row = blockIdx.x;
  int b = row / Lq;
  bf16* hr = h + (long)row * WIDTH;
  const float* sb = s + b * WIDTH;
  int c0 = threadIdx.x * 4;
  float hv[4], y[4]; float ss = 0.f;
  #pragma unroll
  for (int i = 0; i < 4; i++) {
    hv[i] = (float)hr[c0 + i];
    y[i] = hv[i] * (sb[c0 + i] - 1.f); ss += y[i] * y[i];
  }
  ss = blockReduceSum256(ss, red);
  float r = rsqrtf(ss / WIDTH + EPS);
  #pragma unroll
  for (int i = 0; i < 4; i++) hr[c0 + i] = (bf16)(hv[i] + y[i] * r * mw[c0 + i]);
}

// ---------------- h += rmsnorm(g, mw) (bf16) ----------------
__global__ __launch_bounds__(256) void k_addnorm_b(bf16* __restrict__ h,
    const bf16* __restrict__ g, const float* __restrict__ mw) {
  __shared__ float red[4];
  int row = blockIdx.x;
  bf16* hr = h + (long)row * WIDTH;
  const bf16* gr = g + (long)row * WIDTH;
  int c0 = threadIdx.x * 4;
  float y[4]; float ss = 0.f;
  #pragma unroll
  for (int i = 0; i < 4; i++) { y[i] = (float)gr[c0 + i]; ss += y[i] * y[i]; }
  ss = blockReduceSum256(ss, red);
  float r = rsqrtf(ss / WIDTH + EPS);
  #pragma unroll
  for (int i = 0; i < 4; i++)
    hr[c0 + i] = (bf16)((float)hr[c0 + i] + y[i] * r * mw[c0 + i]);
}

// ---------------- router + lambdas (fp32) ----------------
__global__ void k_router(const float* __restrict__ s2, const float* __restrict__ rwgt,
    const float* __restrict__ rb,
    const float* __restrict__ lq1, const float* __restrict__ lk1,
    const float* __restrict__ lq2, const float* __restrict__ lk2,
    float* __restrict__ rw, float* __restrict__ lam) {
  __shared__ float lg[64];
  int t = threadIdx.x;
  int b = t >> 3, j = t & 7;
  float acc = rb[j];
  const float* sb = s2 + b * WIDTH;
  for (int c = 0; c < WIDTH; c++) acc += sb[c] * rwgt[c * 8 + j];
  lg[t] = acc;
  __syncthreads();
  if (t < 8) {
    float v[8]; bool sel[8];
    #pragma unroll
    for (int i = 0; i < 8; i++) { v[i] = lg[t * 8 + i]; sel[i] = false; }
    int idxs[4]; float vals[4];
    for (int s = 0; s < 4; s++) {
      int bi = -1; float bv = -1e30f;
      for (int i = 0; i < 8; i++) if (!sel[i] && v[i] > bv) { bv = v[i]; bi = i; }
      sel[bi] = true; idxs[s] = bi; vals[s] = bv;
    }
    float m = vals[0], den = 0.f, e[4];
    for (int s = 0; s < 4; s++) { e[s] = __expf(vals[s] - m); den += e[s]; }
    for (int i = 0; i < 8; i++) rw[t * 8 + i] = 0.f;
    for (int s = 0; s < 4; s++) rw[t * 8 + idxs[s]] = e[s] / den;
    float d1 = 0.f, d2 = 0.f;
    for (int i = 0; i < 8; i++) { d1 += lq1[t * 8 + i] * lk1[t * 8 + i]; d2 += lq2[t * 8 + i] * lk2[t * 8 + i]; }
    lam[t] = __expf(d1) - __expf(d2) + LAMINIT;
  }
}

// ---------------- q/k rmsnorm, batched over 4 channels (bf16) ----------------
__device__ __forceinline__ void norm8b(bf16* p, const float* w) {
  float v[8]; float ss = 0.f;
  #pragma unroll
  for (int i = 0; i < 8; i++) { v[i] = (float)p[i]; ss += v[i] * v[i]; }
  float r = rsqrtf(ss / 8.f + EPS);
  #pragma unroll
  for (int i = 0; i < 8; i++) p[i] = (bf16)(v[i] * r * w[i]);
}

__global__ __launch_bounds__(256) void k_qknorm_b(bf16* __restrict__ qkv,
    const float* __restrict__ qn, const float* __restrict__ kn, int chBase) {
  int idx = blockIdx.x * blockDim.x + threadIdx.x;
  if (idx >= 4 * ROWS * NHEADS) return;
  int z = idx / (ROWS * NHEADS);
  int rem = idx - z * (ROWS * NHEADS);
  int row = rem >> 3, head = rem & 7;
  int ch = chBase + z;
  bf16* q = qkv + (long)z * ROWS * 384 + (long)row * 384 + head * 16;
  bf16* k = q + 128;
  norm8b(q, qn + ch * 8);     norm8b(q + 8, qn + ch * 8);
  norm8b(k, kn + ch * 8);     norm8b(k + 8, kn + ch * 8);
}

// ---------------- causal attention, batched over 4 channels ----------------
__global__ __launch_bounds__(256) void k_attn_b(const bf16* __restrict__ qkv,
                                                bf16* __restrict__ o12) {
  __shared__ float sk[Lq * HALF];
  __shared__ float sv[Lq * HD];
  int which = blockIdx.x, head = blockIdx.y;
  int zz = blockIdx.z; int zc = zz >> 3, b = zz & 7;
  int tid = threadIdx.x;
  const bf16* qkvb = qkv + (long)zc * ROWS * 384 + (long)b * Lq * 384;
  for (int i = tid; i < Lq * HALF; i += 256) {
    int l = i >> 3, d = i & 7;
    sk[i] = (float)qkvb[(long)l * 384 + 128 + head * 16 + which * 8 + d];
  }
  for (int i = tid; i < Lq * HD; i += 256) {
    int l = i >> 4, d = i & 15;
    sv[i] = (float)qkvb[(long)l * 384 + 256 + head * 16 + d];
  }
  __syncthreads();
  const float scale = 0.35355339059327373f;
  bf16* o = o12 + ((long)zc * 2 + which) * SZO;
  for (int qi = tid; qi < Lq; qi += 256) {
    float qv[8];
    const bf16* qp = qkvb + (long)qi * 384 + head * 16 + which * 8;
    #pragma unroll
    for (int d = 0; d < 8; d++) qv[d] = (float)qp[d];
    float accv[16];
    #pragma unroll
    for (int d = 0; d < 16; d++) accv[d] = 0.f;
    float den = 0.f;
    for (int j = 0; j <= qi; j++) {
      const float* kr = sk + j * 8;
      float sdot = 0.f;
      #pragma unroll
      for (int d = 0; d < 8; d++) sdot += qv[d] * kr[d];
      float e = __expf(sdot * scale);
      den += e;
      const float* vr = sv + j * 16;
      #pragma unroll
      for (int d = 0; d < 16; d++) accv[d] += e * vr[d];
    }
    float inv = 1.f / den;
    bf16* op = o + ((long)(b * NHEADS + head) * Lq + qi) * HD;
    #pragma unroll
    for (int d = 0; d < 16; d++) op[d] = (bf16)(accv[d] * inv);
  }
}

// ---------------- combine: dc = rmsnorm(o1 - lam*o2, hn_w) * 0.8 ----------------
__global__ __launch_bounds__(256) void k_combine_b(const bf16* __restrict__ o12,
    const float* __restrict__ hnw, const float* __restrict__ lam, int chBase,
    bf16* __restrict__ dc) {
  int idx = blockIdx.x * blockDim.x + threadIdx.x;
  if (idx >= 4 * ROWS * NHEADS) return;
  int z = idx / (ROWS * NHEADS);
  int rem = idx - z * (ROWS * NHEADS);
  int row = rem >> 3, head = rem & 7;
  int b = row / Lq, l = row % Lq;
  int ch = chBase + z;
  float lm = lam[ch];
  const bf16* p1 = o12 + ((long)z * 2 + 0) * SZO + ((long)(b * NHEADS + head) * Lq + l) * HD;
  const bf16* p2 = o12 + ((long)z * 2 + 1) * SZO + ((long)(b * NHEADS + head) * Lq + l) * HD;
  float d[16]; float ss = 0.f;
  #pragma unroll
  for (int i = 0; i < 16; i++) {
    d[i] = (float)p1[i] - lm * (float)p2[i]; ss += d[i] * d[i];
  }
  float r = rsqrtf(ss / HD + EPS);
  const float* w = hnw + ch * 16;
  bf16* out = dc + (long)z * ROWS * CW + (long)row * CW + head * HD;
  #pragma unroll
  for (int i = 0; i < 16; i++) out[i] = (bf16)(d[i] * r * w[i] * (1.f - LAMINIT));
}

// ---------------- seg: g2 = (h_ch + rmsnorm(oproj, segw)) * rw ----------------
__global__ __launch_bounds__(128) void k_seg_b(const bf16* __restrict__ h,
    const bf16* __restrict__ op, const float* __restrict__ segw,
    const float* __restrict__ rw, int chBase, bf16* __restrict__ g2) {
  __shared__ float red[2];
  int row = blockIdx.x;
  int z = blockIdx.y;
  int ch = chBase + z;
  int b = row / Lq;
  int c = threadIdx.x;
  float y = (float)op[(long)z * ROWS * CW + (long)row * CW + c];
  float ss = y * y;
  #pragma unroll
  for (int off = 32; off; off >>= 1) ss += __shfl_down(ss, off, 64);
  int lane = c & 63, wid = c >> 6;
  if (lane == 0) red[wid] = ss;
  __syncthreads();
  float tot = red[0] + red[1];
  float r = rsqrtf(tot / CW + EPS);
  float hv = (float)h[(long)row * WIDTH + ch * CW + c];
  float outv = (hv + y * r * segw[ch * CW + c]) * rw[b * NCH + ch];
  g2[(long)row * WIDTH + ch * CW + c] = (bf16)outv;
}

// ---------------- head ----------------
__global__ void k_head(const float* __restrict__ pooled, const float* __restrict__ hw,
                       const float* __restrict__ hb, float* __restrict__ out) {
  int t = threadIdx.x;
  if (t >= Bsz * 10) return;
  int b = t / 10, j = t % 10;
  float acc = hb[j];
  const float* p = pooled + b * WIDTH;
  for (int c = 0; c < WIDTH; c++) acc += p[c] * hw[c * 10 + j];
  out[t] = acc;
}

// ---------------- launcher ----------------
extern "C" void kernel_launch(void* const* d_in, const int* in_sizes, int n_in,
                              void* d_out, int out_size, void* d_ws, size_t ws_size,
                              hipStream_t stream) {
  const float* x          = (const float*)d_in[0];
  const float* pixel_embed= (const float*)d_in[2];
  const float* freq_h     = (const float*)d_in[3];
  const float* freq_w     = (const float*)d_in[4];
  const float* phase_h    = (const float*)d_in[5];
  const float* phase_w    = (const float*)d_in[6];
  const float* pos_proj_w = (const float*)d_in[7];
  const float* pos_proj_b = (const float*)d_in[8];
  const float* embed_norm = (const float*)d_in[9];
  const float* se_w1      = (const float*)d_in[10];
  const float* se_b1      = (const float*)d_in[11];
  const float* se_w2      = (const float*)d_in[12];
  const float* se_b2      = (const float*)d_in[13];
  const float* mix_norm   = (const float*)d_in[14];
  const float* mlp_w1     = (const float*)d_in[15];
  const float* mlp_b1     = (const float*)d_in[16];
  const float* mlp_w2     = (const float*)d_in[17];
  const float* mlp_b2     = (const float*)d_in[18];
  const float* mlp_norm   = (const float*)d_in[19];
  const float* router_w   = (const float*)d_in[20];
  const float* router_b   = (const float*)d_in[21];
  const float* qkv_w      = (const float*)d_in[22];
  const float* qkv_b      = (const float*)d_in[23];
  const float* q_norm_w   = (const float*)d_in[24];
  const float* k_norm_w   = (const float*)d_in[25];
  const float* head_norm_w= (const float*)d_in[26];
  const float* lam_q1     = (const float*)d_in[27];
  const float* lam_k1     = (const float*)d_in[28];
  const float* lam_q2     = (const float*)d_in[29];
  const float* lam_k2     = (const float*)d_in[30];
  const float* out_w      = (const float*)d_in[31];
  const float* out_b      = (const float*)d_in[32];
  const float* seg_norm_w = (const float*)d_in[33];
  const float* head_w     = (const float*)d_in[34];
  const float* head_b     = (const float*)d_in[35];

  char* W = (char*)d_ws;
  bf16*  HB    = (bf16*)(W + B_HB);
  bf16*  G2B   = (bf16*)(W + B_G2B);
  bf16*  ENCB  = (bf16*)(W + B_ENCB);
  bf16*  POSWT = (bf16*)(W + B_POSWT);
  bf16*  QKVWT = (bf16*)(W + B_QKVWT);
  bf16*  OWT   = (bf16*)(W + B_OWT);
  float* SE    = (float*)(W + B_SE);
  float* S2    = (float*)(W + B_S2);
  float* RW    = (float*)(W + B_RW);
  float* LAM   = (float*)(W + B_LAM);
  char*  P     = W + B_POOL;
  float* POS   = (float*)P;
  bf16*  W1T   = (bf16*)P;
  bf16*  W2T   = (bf16*)(P + 8388608);
  bf16*  HID   = (bf16*)(P + 16777216);
  bf16*  QKV   = (bf16*)P;
  bf16*  O12   = (bf16*)(P + 14155776);
  bf16*  DC    = (bf16*)(P + 23592960);
  bf16*  OP    = (bf16*)(P + 28311552);
  float* out   = (float*)d_out;

  // 1. positional encoding -> bf16, weight cast, gemm -> POS (f32)
  k_enc_b<<<288, 256, 0, stream>>>(freq_h, freq_w, phase_h, phase_w, ENCB);
  k_tcast<<<dim3(32, 4, 1), 256, 0, stream>>>(pos_proj_w, POSWT, 128, 1024);
  gemm_bt<0, 0><<<dim3(8, 5, 1), 256, 0, stream>>>(
      ENCB, 128, 0, POSWT, 0, pos_proj_b, 0, POS, 1024, 0, 640, 1024, 128);
  // 2. embed + rmsnorm -> bf16 h
  k_embed<<<ROWS, 256, 0, stream>>>(x, pixel_embed, POS, embed_norm, HB);
  // 3. SE gate
  k_meanl_b<<<32, 256, 0, stream>>>(HB, SE);
  k_se<<<Bsz, 256, 0, stream>>>(SE, se_w1, se_b1, se_w2, se_b2);
  k_mix_b<<<ROWS, 256, 0, stream>>>(HB, SE, mix_norm);
  // 4. MLP (bf16 MFMA, 2 chunks of 2304 rows)
  k_tcast<<<dim3(128, 32, 1), 256, 0, stream>>>(mlp_w1, W1T, 1024, 4096);
  k_tcast<<<dim3(32, 128, 1), 256, 0, stream>>>(mlp_w2, W2T, 4096, 1024);
  for (int c = 0; c < 2; c++) {
    gemm_bt<1, 1><<<dim3(32, 18, 1), 256, 0, stream>>>(
        HB + (long)c * 2304 * 1024, 1024, 0, W1T, 0, mlp_b1, 0,
        HID, 4096, 0, 2304, 4096, 1024);
    gemm_bt<0, 1><<<dim3(8, 18, 1), 256, 0, stream>>>(
        HID, 4096, 0, W2T, 0, mlp_b2, 0,
        G2B + (long)c * 2304 * 1024, 1024, 0, 2304, 1024, 4096);
  }
  k_addnorm_b<<<ROWS, 256, 0, stream>>>(HB, G2B, mlp_norm);
  // 5. router + lambdas
  k_meanl_b<<<32, 256, 0, stream>>>(HB, S2);
  k_router<<<1, 64, 0, stream>>>(S2, router_w, router_b,
                                 lam_q1, lam_k1, lam_q2, lam_k2, RW, LAM);
  // 6. channel weights cast
  k_tcast<<<dim3(12, 4, 8), 256, 0, stream>>>(qkv_w, QKVWT, 128, 384);
  k_tcast<<<dim3(4, 4, 8), 256, 0, stream>>>(out_w, OWT, 128, 128);
  // 7. channels in 2 groups of 4
  for (int g = 0; g < 2; g++) {
    gemm_bt<1, 1><<<dim3(3, 36, 4), 256, 0, stream>>>(
        HB + g * 4 * CW, 1024, CW,
        QKVWT + (long)g * 4 * 384 * 128, 384 * 128,
        qkv_b + g * 4 * 384, 384,
        QKV, 384, (long)ROWS * 384, ROWS, 384, 128);
    k_qknorm_b<<<576, 256, 0, stream>>>(QKV, q_norm_w, k_norm_w, g * 4);
    k_attn_b<<<dim3(2, NHEADS, 32), 256, 0, stream>>>(QKV, O12);
    k_combine_b<<<576, 256, 0, stream>>>(O12, head_norm_w, LAM, g * 4, DC);
    gemm_bt<1, 1><<<dim3(1, 36, 4), 256, 0, stream>>>(
        DC, 128, (long)ROWS * 128,
        OWT + (long)g * 4 * 128 * 128, 128 * 128,
        out_b + g * 4 * 128, 128,
        OP, 128, (long)ROWS * 128, ROWS, 128, 128);
    k_seg_b<<<dim3(ROWS, 4), 128, 0, stream>>>(HB, OP, seg_norm_w, RW, g * 4, G2B);
  }
  // 8. pool + head
  k_meanl_b<<<32, 256, 0, stream>>>(G2B, S2);
  k_head<<<1, 128, 0, stream>>>(S2, head_w, head_b, out);
}

// Round 3
// 704.504 us; speedup vs baseline: 4.1282x; 1.3333x over previous
//
#include <hip/hip_runtime.h>
#include <math.h>

typedef __bf16 bf16;
typedef __bf16 bf16x8 __attribute__((ext_vector_type(8)));
typedef __bf16 bf16x4 __attribute__((ext_vector_type(4)));
typedef float f32x4 __attribute__((ext_vector_type(4)));

// ---------------- constants ----------------
constexpr int Bsz = 8, HIMG = 24, WIMG = 24;
constexpr int Lq = 576;
constexpr int WIDTH = 1024, NCH = 8, CW = 128;
constexpr int NHEADS = 8, HD = 16, HALF = 8;
constexpr float EPS = 1e-6f;
constexpr float LAMINIT = 0.2f;
constexpr float QSCALE = 0.35355339059327373f;  // 1/sqrt(8)
constexpr int ROWS = Bsz * Lq;              // 4608

// ---------------- workspace byte offsets ----------------
constexpr size_t B_HB    = 0;                        // bf16 h [4608][1024]
constexpr size_t B_G2B   = B_HB    + 9437184;        // bf16 g2 [4608][1024]
constexpr size_t B_ENCB  = B_G2B   + 9437184;        // bf16 enc [640][128]
constexpr size_t B_POSWT = B_ENCB  + 163840;         // bf16 [1024][128]
constexpr size_t B_QKVWT = B_POSWT + 262144;         // bf16 [8][384][128]
constexpr size_t B_OWT   = B_QKVWT + 786432;         // bf16 [8][128][128]
constexpr size_t B_SE    = B_OWT   + 262144;         // f32 [8][1024]
constexpr size_t B_S2    = B_SE    + 32768;          // f32 [8][1024]
constexpr size_t B_MP    = B_S2    + 32768;          // f32 [8][8][1024] meanl partials
constexpr size_t B_RW    = B_MP    + 262144;         // f32 [64]
constexpr size_t B_LAM   = B_RW    + 256;            // f32 [8]
constexpr size_t B_POOL  = B_LAM   + 256;            // phase-shared pool
// pool (pos phase):  POS f32 [640][1024] = 2621440
// pool (MLP phase):  W1T 8388608 | W2T 8388608 | HID bf16 [4608][2048] 18874368  = 35651584
// pool (chan phase): QKV 14155776 | DC 4718592 | OP 4718592                      = 23592960
// high water: B_POOL + 35651584 = 56328704 bytes (< 59.4 MB proven in R1)

// ---------------- helpers ----------------
__device__ __forceinline__ float blockReduceSum256(float v, float* red) {
  #pragma unroll
  for (int off = 32; off; off >>= 1) v += __shfl_down(v, off, 64);
  int lane = threadIdx.x & 63, wid = threadIdx.x >> 6;
  if (lane == 0) red[wid] = v;
  __syncthreads();
  float total = 0.f;
  #pragma unroll
  for (int i = 0; i < 4; i++) total += red[i];
  return total;
}
__device__ __forceinline__ float silu(float x) { return x / (1.f + __expf(-x)); }

__device__ __forceinline__ void gl16(const bf16* g, bf16* l) {
  __builtin_amdgcn_global_load_lds(
      (const __attribute__((address_space(1))) void*)g,
      (__attribute__((address_space(3))) void*)l, 16, 0, 0);
}

// ---------------- cast+transpose: W fp32 [K][N] -> Wt bf16 [N][K] ----------------
__global__ __launch_bounds__(256) void k_tcast(const float* __restrict__ W,
    bf16* __restrict__ Wt, int K, int N) {
  __shared__ float t[32][33];
  int n0 = blockIdx.x * 32, k0 = blockIdx.y * 32;
  long zo = (long)blockIdx.z * K * N;
  int tid = threadIdx.x;
  int r = tid >> 3, c4 = (tid & 7) * 4;
  const float4 v = *(const float4*)(W + zo + (long)(k0 + r) * N + n0 + c4);
  t[c4 + 0][r] = v.x; t[c4 + 1][r] = v.y; t[c4 + 2][r] = v.z; t[c4 + 3][r] = v.w;
  __syncthreads();
  bf16* dst = Wt + zo + (long)(n0 + r) * K + k0 + c4;
  dst[0] = (bf16)t[r][c4 + 0]; dst[1] = (bf16)t[r][c4 + 1];
  dst[2] = (bf16)t[r][c4 + 2]; dst[3] = (bf16)t[r][c4 + 3];
}

// ---------------- positional encoding (bf16 out) ----------------
__global__ void k_enc_b(const float* __restrict__ fh, const float* __restrict__ fw,
                        const float* __restrict__ ph, const float* __restrict__ pw,
                        bf16* __restrict__ enc) {
  int idx = blockIdx.x * blockDim.x + threadIdx.x;
  if (idx >= Lq * 128) return;
  int l = idx >> 7, c = idx & 127;
  int hh = l / WIMG, ww = l % WIMG;
  float v;
  if (c < 64) {
    int f = c & 31;
    float fr = log1pf(__expf(fh[f])) * 10.f;
    float a = (hh / (float)HIMG) * fr + ph[f];
    v = (c < 32) ? sinf(a) : cosf(a);
  } else {
    int f = c & 31;
    float fr = log1pf(__expf(fw[f])) * 10.f;
    float a = (ww / (float)WIMG) * fr + pw[f];
    v = (c < 96) ? sinf(a) : cosf(a);
  }
  enc[idx] = (bf16)v;
}

// ---------------- bf16 MFMA GEMM 128x128: C = act(A @ Bt^T + bias) ----------------
template <int ACT, int OUTBF>
__global__ __launch_bounds__(256) void gemm_bt(
    const bf16* __restrict__ A, int lda, long aZs,
    const bf16* __restrict__ Bt, long bZs,
    const float* __restrict__ bias, int biasZs,
    void* __restrict__ Cv, int ldc, long cZs,
    int M, int N, int K) {
  __shared__ bf16 As[128 * 32];
  __shared__ bf16 Bs[128 * 32];
  int tid = threadIdx.x;
  int m0 = blockIdx.y * 128, n0 = blockIdx.x * 128;
  int z = blockIdx.z;
  const bf16* Ab = A + (long)z * aZs;
  const bf16* Bb = Bt + (long)z * bZs;
  f32x4 acc[4][4] = {};
  int wv = tid >> 6, lane = tid & 63;
  int wrow = (wv >> 1) * 64, wcol = (wv & 1) * 64;
  int lm = lane & 15, lq = lane >> 4;
  const bf16* ag = Ab + (long)(m0 + (tid >> 2)) * lda + (tid & 3) * 8;
  const bf16* bg = Bb + (long)(n0 + (tid >> 2)) * K + (tid & 3) * 8;
  bf16* asd = As + tid * 8;
  bf16* bsd = Bs + tid * 8;
  for (int k0 = 0; k0 < K; k0 += 32) {
    gl16(ag + k0, asd);
    gl16(ag + k0 + 64L * lda, asd + 2048);
    gl16(bg + k0, bsd);
    gl16(bg + k0 + 64L * K, bsd + 2048);
    __syncthreads();
    bf16x8 af[4], bfr[4];
    #pragma unroll
    for (int i = 0; i < 4; i++) {
      af[i]  = *(const bf16x8*)(As + (wrow + i * 16 + lm) * 32 + lq * 8);
      bfr[i] = *(const bf16x8*)(Bs + (wcol + i * 16 + lm) * 32 + lq * 8);
    }
    #pragma unroll
    for (int i = 0; i < 4; i++)
      #pragma unroll
      for (int j = 0; j < 4; j++)
        acc[i][j] = __builtin_amdgcn_mfma_f32_16x16x32_bf16(af[i], bfr[j], acc[i][j], 0, 0, 0);
    __syncthreads();
  }
  long cz = (long)z * cZs;
  const float* bz = bias ? bias + (long)z * biasZs : nullptr;
  #pragma unroll
  for (int i = 0; i < 4; i++) {
    int row = m0 + wrow + i * 16 + lq * 4;
    #pragma unroll
    for (int j = 0; j < 4; j++) {
      int col = n0 + wcol + j * 16 + lm;
      float bv = bz ? bz[col] : 0.f;
      #pragma unroll
      for (int r = 0; r < 4; r++) {
        float v = acc[i][j][r] + bv;
        if (ACT == 1) v = silu(v);
        long off = cz + (long)(row + r) * ldc + col;
        if (OUTBF) ((bf16*)Cv)[off] = (bf16)v;
        else       ((float*)Cv)[off] = v;
      }
    }
  }
}

// ---------------- bf16 MFMA GEMM 64x128 tile (better occupancy for wide-K / small-N) ----
template <int ACT, int OUTBF, int ACC>
__global__ __launch_bounds__(256) void gemm64(
    const bf16* __restrict__ A, int lda, long aZs,
    const bf16* __restrict__ Bt, int ldb, long bZs,
    const float* __restrict__ bias, int biasZs,
    void* __restrict__ Cv, int ldc, long cZs,
    int M, int N, int K) {
  __shared__ bf16 As[64 * 32];
  __shared__ bf16 Bs[128 * 32];
  int tid = threadIdx.x;
  int m0 = blockIdx.y * 64, n0 = blockIdx.x * 128;
  int z = blockIdx.z;
  const bf16* Ab = A + (long)z * aZs;
  const bf16* Bb = Bt + (long)z * bZs;
  f32x4 acc[4][2] = {};
  int wv = tid >> 6, lane = tid & 63;
  int lm = lane & 15, lq = lane >> 4;
  int wcol = wv * 32;
  const bf16* ag = Ab + (long)(m0 + (tid >> 2)) * lda + (tid & 3) * 8;
  const bf16* bg = Bb + (long)(n0 + (tid >> 2)) * ldb + (tid & 3) * 8;
  bf16* asd = As + tid * 8;
  bf16* bsd = Bs + tid * 8;
  for (int k0 = 0; k0 < K; k0 += 32) {
    if (tid < 256) gl16(ag + k0, asd);           // 64 rows x 32 k = exactly 256 lanes
    gl16(bg + k0, bsd);
    gl16(bg + k0 + 64L * ldb, bsd + 2048);
    __syncthreads();
    bf16x8 af[4], bfr[2];
    #pragma unroll
    for (int i = 0; i < 4; i++)
      af[i] = *(const bf16x8*)(As + (i * 16 + lm) * 32 + lq * 8);
    #pragma unroll
    for (int j = 0; j < 2; j++)
      bfr[j] = *(const bf16x8*)(Bs + (wcol + j * 16 + lm) * 32 + lq * 8);
    #pragma unroll
    for (int i = 0; i < 4; i++)
      #pragma unroll
      for (int j = 0; j < 2; j++)
        acc[i][j] = __builtin_amdgcn_mfma_f32_16x16x32_bf16(af[i], bfr[j], acc[i][j], 0, 0, 0);
    __syncthreads();
  }
  long cz = (long)z * cZs;
  const float* bz = bias ? bias + (long)z * biasZs : nullptr;
  #pragma unroll
  for (int i = 0; i < 4; i++) {
    int row = m0 + i * 16 + lq * 4;
    #pragma unroll
    for (int j = 0; j < 2; j++) {
      int col = n0 + wcol + j * 16 + lm;
      float bv = bz ? bz[col] : 0.f;
      #pragma unroll
      for (int r = 0; r < 4; r++) {
        float v = acc[i][j][r] + bv;
        long off = cz + (long)(row + r) * ldc + col;
        if (ACC) v += (float)((bf16*)Cv)[off];
        if (ACT == 1) v = silu(v);
        if (OUTBF) ((bf16*)Cv)[off] = (bf16)v;
        else       ((float*)Cv)[off] = v;
      }
    }
  }
}

// ---------------- embed + rmsnorm -> bf16 h ----------------
__global__ __launch_bounds__(256) void k_embed(const float* __restrict__ x,
    const float* __restrict__ emb, const float* __restrict__ pos,
    const float* __restrict__ nw, bf16* __restrict__ h) {
  __shared__ float red[4];
  int row = blockIdx.x;
  int l = row % Lq;
  int xi = (int)(x[row] * 255.f);
  xi = min(max(xi, 0), 255);
  const float* er = emb + (long)xi * WIDTH;
  const float* pr = pos + (long)l * WIDTH;
  int c0 = threadIdx.x * 4;
  float v[4]; float ss = 0.f;
  #pragma unroll
  for (int i = 0; i < 4; i++) { v[i] = er[c0 + i] + pr[c0 + i]; ss += v[i] * v[i]; }
  ss = blockReduceSum256(ss, red);
  float r = rsqrtf(ss / WIDTH + EPS);
  bf16* hr = h + (long)row * WIDTH;
  #pragma unroll
  for (int i = 0; i < 4; i++) hr[c0 + i] = (bf16)(v[i] * r * nw[c0 + i]);
}

// ---------------- mean over L: 2-phase ----------------
__global__ void k_meanl_p(const bf16* __restrict__ h, float* __restrict__ part) {
  int lp = blockIdx.x, b = blockIdx.y, t = threadIdx.x;
  const bf16* p = h + ((long)b * Lq + (long)lp * 72) * WIDTH + t * 4;
  float a0 = 0, a1 = 0, a2 = 0, a3 = 0;
  for (int l = 0; l < 72; l++) {
    bf16x4 v = *(const bf16x4*)(p + (long)l * WIDTH);
    a0 += (float)v[0]; a1 += (float)v[1]; a2 += (float)v[2]; a3 += (float)v[3];
  }
  float* dst = part + ((long)b * 8 + lp) * WIDTH + t * 4;
  dst[0] = a0; dst[1] = a1; dst[2] = a2; dst[3] = a3;
}
__global__ void k_meanl_r(const float* __restrict__ part, float* __restrict__ s) {
  int idx = blockIdx.x * 256 + threadIdx.x;
  if (idx >= Bsz * WIDTH) return;
  int b = idx >> 10, c = idx & 1023;
  float a = 0.f;
  for (int lp = 0; lp < 8; lp++) a += part[((long)b * 8 + lp) * WIDTH + c];
  s[idx] = a / 576.f;
}

// ---------------- SE block, one block per b, 1024 threads ----------------
__global__ __launch_bounds__(1024) void k_se(float* __restrict__ s,
    const float* __restrict__ w1, const float* __restrict__ b1,
    const float* __restrict__ w2, const float* __restrict__ b2) {
  __shared__ float sv[1024];
  __shared__ float red[1024];
  __shared__ float t1[256];
  int b = blockIdx.x, t = threadIdx.x;
  sv[t] = s[b * 1024 + t];
  __syncthreads();
  int j = t & 255, part = t >> 8;           // 4 parts x 256 c
  float acc = 0.f;
  for (int c = part * 256; c < part * 256 + 256; c++) acc += sv[c] * w1[c * 256 + j];
  red[t] = acc;
  __syncthreads();
  if (t < 256) t1[t] = silu(red[t] + red[t + 256] + red[t + 512] + red[t + 768] + b1[t]);
  __syncthreads();
  float a = b2[t];
  for (int c = 0; c < 256; c++) a += t1[c] * w2[c * 1024 + t];
  s[b * 1024 + t] = 1.f / (1.f + __expf(-a));
}

// ---------------- mix: h += rmsnorm(h*(s-1), mw)  (bf16 h) ----------------
__global__ __launch_bounds__(256) void k_mix_b(bf16* __restrict__ h,
    const float* __restrict__ s, const float* __restrict__ mw) {
  __shared__ float red[4];
  int row = blockIdx.x;
  int b = row / Lq;
  bf16* hr = h + (long)row * WIDTH;
  const float* sb = s + b * WIDTH;
  int c0 = threadIdx.x * 4;
  float hv[4], y[4]; float ss = 0.f;
  #pragma unroll
  for (int i = 0; i < 4; i++) {
    hv[i] = (float)hr[c0 + i];
    y[i] = hv[i] * (sb[c0 + i] - 1.f); ss += y[i] * y[i];
  }
  ss = blockReduceSum256(ss, red);
  float r = rsqrtf(ss / WIDTH + EPS);
  #pragma unroll
  for (int i = 0; i < 4; i++) hr[c0 + i] = (bf16)(hv[i] + y[i] * r * mw[c0 + i]);
}

// ---------------- h += rmsnorm(g, mw) (bf16) ----------------
__global__ __launch_bounds__(256) void k_addnorm_b(bf16* __restrict__ h,
    const bf16* __restrict__ g, const float* __restrict__ mw) {
  __shared__ float red[4];
  int row = blockIdx.x;
  bf16* hr = h + (long)row * WIDTH;
  const bf16* gr = g + (long)row * WIDTH;
  int c0 = threadIdx.x * 4;
  float y[4]; float ss = 0.f;
  #pragma unroll
  for (int i = 0; i < 4; i++) { y[i] = (float)gr[c0 + i]; ss += y[i] * y[i]; }
  ss = blockReduceSum256(ss, red);
  float r = rsqrtf(ss / WIDTH + EPS);
  #pragma unroll
  for (int i = 0; i < 4; i++)
    hr[c0 + i] = (bf16)((float)hr[c0 + i] + y[i] * r * mw[c0 + i]);
}

// ---------------- router + lambdas, one block per b ----------------
__global__ __launch_bounds__(256) void k_router(const float* __restrict__ s2,
    const float* __restrict__ rwgt, const float* __restrict__ rb,
    const float* __restrict__ lq1, const float* __restrict__ lk1,
    const float* __restrict__ lq2, const float* __restrict__ lk2,
    float* __restrict__ rw, float* __restrict__ lam) {
  __shared__ float red[256];
  __shared__ float lg[8];
  int b = blockIdx.x, t = threadIdx.x;
  int j = t & 7, part = t >> 3;             // 32 parts x 32 c
  const float* sb = s2 + b * 1024;
  float acc = 0.f;
  for (int c = part * 32; c < part * 32 + 32; c++) acc += sb[c] * rwgt[c * 8 + j];
  red[t] = acc;
  __syncthreads();
  if (t < 8) {
    float a = rb[t];
    for (int p = 0; p < 32; p++) a += red[p * 8 + t];
    lg[t] = a;
  }
  __syncthreads();
  if (t == 0) {
    float v[8]; bool sel[8];
    #pragma unroll
    for (int i = 0; i < 8; i++) { v[i] = lg[i]; sel[i] = false; }
    int idxs[4]; float vals[4];
    for (int s = 0; s < 4; s++) {
      int bi = -1; float bv = -1e30f;
      for (int i = 0; i < 8; i++) if (!sel[i] && v[i] > bv) { bv = v[i]; bi = i; }
      sel[bi] = true; idxs[s] = bi; vals[s] = bv;
    }
    float m = vals[0], den = 0.f, e[4];
    for (int s = 0; s < 4; s++) { e[s] = __expf(vals[s] - m); den += e[s]; }
    for (int i = 0; i < 8; i++) rw[b * 8 + i] = 0.f;
    for (int s = 0; s < 4; s++) rw[b * 8 + idxs[s]] = e[s] / den;
  }
  if (b == 0 && t >= 8 && t < 16) {
    int c = t - 8;
    float d1 = 0.f, d2 = 0.f;
    for (int i = 0; i < 8; i++) {
      d1 += lq1[c * 8 + i] * lk1[c * 8 + i];
      d2 += lq2[c * 8 + i] * lk2[c * 8 + i];
    }
    lam[c] = __expf(d1) - __expf(d2) + LAMINIT;
  }
}

// ---------------- q/k rmsnorm, vectorized; q pre-scaled by 1/sqrt(8) ----------------
__device__ __forceinline__ bf16x8 normv(bf16x8 x, const float* w, float mul) {
  float v[8]; float ss = 0.f;
  #pragma unroll
  for (int i = 0; i < 8; i++) { v[i] = (float)x[i]; ss += v[i] * v[i]; }
  float r = rsqrtf(ss / 8.f + EPS) * mul;
  bf16x8 o;
  #pragma unroll
  for (int i = 0; i < 8; i++) o[i] = (bf16)(v[i] * r * w[i]);
  return o;
}

__global__ __launch_bounds__(256) void k_qknorm_b(bf16* __restrict__ qkv,
    const float* __restrict__ qn, const float* __restrict__ kn, int chBase) {
  int idx = blockIdx.x * 256 + threadIdx.x;
  if (idx >= 4 * ROWS * NHEADS) return;
  int z = idx / (ROWS * NHEADS);
  int rem = idx - z * (ROWS * NHEADS);
  int row = rem >> 3, head = rem & 7;
  int ch = chBase + z;
  bf16* qp = qkv + (long)z * ROWS * 384 + (long)row * 384 + head * 16;
  bf16x8 q0 = *(bf16x8*)(qp),       q1 = *(bf16x8*)(qp + 8);
  bf16x8 k0 = *(bf16x8*)(qp + 128), k1 = *(bf16x8*)(qp + 136);
  *(bf16x8*)(qp)       = normv(q0, qn + ch * 8, QSCALE);
  *(bf16x8*)(qp + 8)   = normv(q1, qn + ch * 8, QSCALE);
  *(bf16x8*)(qp + 128) = normv(k0, kn + ch * 8, 1.f);
  *(bf16x8*)(qp + 136) = normv(k1, kn + ch * 8, 1.f);
}

// ---------------- MFMA causal differential attention + fused combine ----------------
// grid (2 qstripe-halves, 8 heads, 32 = zc*8+b), 256 threads = 4 waves.
// LDS: Qs[576][16] q1|q2 (prescaled,normed) 18432B; Ks[576][16] k1|k2 18432B;
//      Vt[16][584] padded 18688B; Ps[4 waves][16][40] 5120B  -> 60672B, 2 blk/CU
__global__ __launch_bounds__(256) void k_attn_mfma(
    const bf16* __restrict__ qkv, const float* __restrict__ lam,
    const float* __restrict__ hnw, int chBase, bf16* __restrict__ dc) {
  __shared__ bf16 Qs[576 * 16];
  __shared__ bf16 Ks[576 * 16];
  __shared__ bf16 Vt[16 * 584];
  __shared__ bf16 Ps[4][16 * 40];
  int tid = threadIdx.x;
  int head = blockIdx.y;
  int zz = blockIdx.z; int zc = zz >> 3, b = zz & 7;
  const bf16* qkvb = qkv + ((long)zc * ROWS + (long)b * Lq) * 384;
  for (int i = tid; i < 1152; i += 256) {
    int row = i >> 1, hf = i & 1;
    gl16(qkvb + (long)row * 384 + head * 16 + hf * 8, Qs + i * 8);
    gl16(qkvb + (long)row * 384 + 128 + head * 16 + hf * 8, Ks + i * 8);
  }
  for (int i = tid; i < 1152; i += 256) {
    int row = i >> 1, dh = i & 1;
    bf16x8 v = *(const bf16x8*)(qkvb + (long)row * 384 + 256 + head * 16 + dh * 8);
    #pragma unroll
    for (int j = 0; j < 8; j++) Vt[(dh * 8 + j) * 584 + row] = v[j];
  }
  __syncthreads();
  int wv = tid >> 6, lane = tid & 63;
  int lm = lane & 15, lq = lane >> 4;
  float lamv = lam[chBase + zc];
  float hwv = hnw[(chBase + zc) * 16 + lm];
  bf16* Pw = &Ps[wv][0];
  for (int qt = blockIdx.x * 4 + wv; qt < 36; qt += 8) {
    bf16x8 aq = {};
    if (lq < 2) aq = *(const bf16x8*)(Qs + (qt * 16 + lm) * 16 + lq * 8);
    f32x4 o[2] = {{0,0,0,0},{0,0,0,0}};
    float den[2][4] = {};
    int nch = (qt >> 1) + 1;
    for (int kc = 0; kc < nch; kc++) {
      f32x4 s[2][2] = {{{0,0,0,0},{0,0,0,0}},{{0,0,0,0},{0,0,0,0}}};
      #pragma unroll
      for (int t = 0; t < 2; t++) {
        int krow = kc * 32 + t * 16 + lm;
        bf16x8 b1 = {}, b2 = {};
        if (lq == 0) b1 = *(const bf16x8*)(Ks + krow * 16);
        if (lq == 1) b2 = *(const bf16x8*)(Ks + krow * 16 + 8);
        s[0][t] = __builtin_amdgcn_mfma_f32_16x16x32_bf16(aq, b1, s[0][t], 0, 0, 0);
        s[1][t] = __builtin_amdgcn_mfma_f32_16x16x32_bf16(aq, b2, s[1][t], 0, 0, 0);
      }
      bf16x8 vb = *(const bf16x8*)(Vt + lm * 584 + kc * 32 + lq * 8);
      #pragma unroll
      for (int w2 = 0; w2 < 2; w2++) {
        #pragma unroll
        for (int t = 0; t < 2; t++) {
          int gc = kc * 32 + t * 16 + lm;
          #pragma unroll
          for (int r = 0; r < 4; r++) {
            int gr = qt * 16 + lq * 4 + r;
            float e = (gc <= gr) ? __expf(s[w2][t][r]) : 0.f;
            bf16 pb = (bf16)e;
            Pw[(lq * 4 + r) * 40 + t * 16 + lm] = pb;
            den[w2][r] += (float)pb;
          }
        }
        bf16x8 pa = *(const bf16x8*)(Pw + lm * 40 + lq * 8);
        o[w2] = __builtin_amdgcn_mfma_f32_16x16x32_bf16(pa, vb, o[w2], 0, 0, 0);
      }
    }
    #pragma unroll
    for (int r = 0; r < 4; r++)
      #pragma unroll
      for (int m = 1; m < 16; m <<= 1) {
        den[0][r] += __shfl_xor(den[0][r], m);
        den[1][r] += __shfl_xor(den[1][r], m);
      }
    #pragma unroll
    for (int r = 0; r < 4; r++) {
      float dff = o[0][r] / den[0][r] - lamv * (o[1][r] / den[1][r]);
      float ss = dff * dff;
      #pragma unroll
      for (int m = 1; m < 16; m <<= 1) ss += __shfl_xor(ss, m);
      float rr = rsqrtf(ss / 16.f + EPS);
      long rowg = (long)zc * ROWS + (long)b * Lq + qt * 16 + lq * 4 + r;
      dc[rowg * 128 + head * 16 + lm] = (bf16)(dff * rr * hwv * (1.f - LAMINIT));
    }
  }
}

// ---------------- seg: g2 = (h_ch + rmsnorm(oproj, segw)) * rw ----------------
__global__ __launch_bounds__(128) void k_seg_b(const bf16* __restrict__ h,
    const bf16* __restrict__ op, const float* __restrict__ segw,
    const float* __restrict__ rw, int chBase, bf16* __restrict__ g2) {
  __shared__ float red[2];
  int row = blockIdx.x;
  int z = blockIdx.y;
  int ch = chBase + z;
  int b = row / Lq;
  int c = threadIdx.x;
  float y = (float)op[(long)z * ROWS * CW + (long)row * CW + c];
  float ss = y * y;
  #pragma unroll
  for (int off = 32; off; off >>= 1) ss += __shfl_down(ss, off, 64);
  int lane = c & 63, wid = c >> 6;
  if (lane == 0) red[wid] = ss;
  __syncthreads();
  float tot = red[0] + red[1];
  float r = rsqrtf(tot / CW + EPS);
  float hv = (float)h[(long)row * WIDTH + ch * CW + c];
  float outv = (hv + y * r * segw[ch * CW + c]) * rw[b * NCH + ch];
  g2[(long)row * WIDTH + ch * CW + c] = (bf16)outv;
}

// ---------------- head: one block per b ----------------
__global__ __launch_bounds__(256) void k_head(const float* __restrict__ pooled,
    const float* __restrict__ hw, const float* __restrict__ hb, float* __restrict__ out) {
  __shared__ float red[256];
  int b = blockIdx.x, t = threadIdx.x;
  int j = t & 15, part = t >> 4;            // 16 parts x 64 c
  float acc = 0.f;
  if (j < 10)
    for (int c = part * 64; c < part * 64 + 64; c++)
      acc += pooled[b * 1024 + c] * hw[c * 10 + j];
  red[t] = acc;
  __syncthreads();
  if (t < 10) {
    float a = hb[t];
    for (int p = 0; p < 16; p++) a += red[p * 16 + t];
    out[b * 10 + t] = a;
  }
}

// ---------------- launcher ----------------
extern "C" void kernel_launch(void* const* d_in, const int* in_sizes, int n_in,
                              void* d_out, int out_size, void* d_ws, size_t ws_size,
                              hipStream_t stream) {
  const float* x          = (const float*)d_in[0];
  const float* pixel_embed= (const float*)d_in[2];
  const float* freq_h     = (const float*)d_in[3];
  const float* freq_w     = (const float*)d_in[4];
  const float* phase_h    = (const float*)d_in[5];
  const float* phase_w    = (const float*)d_in[6];
  const float* pos_proj_w = (const float*)d_in[7];
  const float* pos_proj_b = (const float*)d_in[8];
  const float* embed_norm = (const float*)d_in[9];
  const float* se_w1      = (const float*)d_in[10];
  const float* se_b1      = (const float*)d_in[11];
  const float* se_w2      = (const float*)d_in[12];
  const float* se_b2      = (const float*)d_in[13];
  const float* mix_norm   = (const float*)d_in[14];
  const float* mlp_w1     = (const float*)d_in[15];
  const float* mlp_b1     = (const float*)d_in[16];
  const float* mlp_w2     = (const float*)d_in[17];
  const float* mlp_b2     = (const float*)d_in[18];
  const float* mlp_norm   = (const float*)d_in[19];
  const float* router_w   = (const float*)d_in[20];
  const float* router_b   = (const float*)d_in[21];
  const float* qkv_w      = (const float*)d_in[22];
  const float* qkv_b      = (const float*)d_in[23];
  const float* q_norm_w   = (const float*)d_in[24];
  const float* k_norm_w   = (const float*)d_in[25];
  const float* head_norm_w= (const float*)d_in[26];
  const float* lam_q1     = (const float*)d_in[27];
  const float* lam_k1     = (const float*)d_in[28];
  const float* lam_q2     = (const float*)d_in[29];
  const float* lam_k2     = (const float*)d_in[30];
  const float* out_w      = (const float*)d_in[31];
  const float* out_b      = (const float*)d_in[32];
  const float* seg_norm_w = (const float*)d_in[33];
  const float* head_w     = (const float*)d_in[34];
  const float* head_b     = (const float*)d_in[35];

  char* W = (char*)d_ws;
  bf16*  HB    = (bf16*)(W + B_HB);
  bf16*  G2B   = (bf16*)(W + B_G2B);
  bf16*  ENCB  = (bf16*)(W + B_ENCB);
  bf16*  POSWT = (bf16*)(W + B_POSWT);
  bf16*  QKVWT = (bf16*)(W + B_QKVWT);
  bf16*  OWT   = (bf16*)(W + B_OWT);
  float* SE    = (float*)(W + B_SE);
  float* S2    = (float*)(W + B_S2);
  float* MP    = (float*)(W + B_MP);
  float* RW    = (float*)(W + B_RW);
  float* LAM   = (float*)(W + B_LAM);
  char*  P     = W + B_POOL;
  float* POS   = (float*)P;
  bf16*  W1T   = (bf16*)P;
  bf16*  W2T   = (bf16*)(P + 8388608);
  bf16*  HID   = (bf16*)(P + 16777216);
  bf16*  QKV   = (bf16*)P;
  bf16*  DC    = (bf16*)(P + 14155776);
  bf16*  OP    = (bf16*)(P + 18874368);
  float* out   = (float*)d_out;

  // 1. positional encoding -> bf16, weight cast, gemm -> POS (f32)
  k_enc_b<<<288, 256, 0, stream>>>(freq_h, freq_w, phase_h, phase_w, ENCB);
  k_tcast<<<dim3(32, 4, 1), 256, 0, stream>>>(pos_proj_w, POSWT, 128, 1024);
  gemm64<0, 0, 0><<<dim3(8, 10, 1), 256, 0, stream>>>(
      ENCB, 128, 0, POSWT, 128, 0, pos_proj_b, 0, POS, 1024, 0, 640, 1024, 128);
  // 2. embed + rmsnorm -> bf16 h
  k_embed<<<ROWS, 256, 0, stream>>>(x, pixel_embed, POS, embed_norm, HB);
  // 3. SE gate
  k_meanl_p<<<dim3(8, 8), 256, 0, stream>>>(HB, MP);
  k_meanl_r<<<32, 256, 0, stream>>>(MP, SE);
  k_se<<<Bsz, 1024, 0, stream>>>(SE, se_w1, se_b1, se_w2, se_b2);
  k_mix_b<<<ROWS, 256, 0, stream>>>(HB, SE, mix_norm);
  // 4. MLP: split along hidden dim (2 halves of 2048), bf16 MFMA
  k_tcast<<<dim3(128, 32, 1), 256, 0, stream>>>(mlp_w1, W1T, 1024, 4096);
  k_tcast<<<dim3(32, 128, 1), 256, 0, stream>>>(mlp_w2, W2T, 4096, 1024);
  gemm_bt<1, 1><<<dim3(16, 36, 1), 256, 0, stream>>>(
      HB, 1024, 0, W1T, 0, mlp_b1, 0, HID, 2048, 0, 4608, 2048, 1024);
  gemm64<0, 1, 0><<<dim3(8, 72, 1), 256, 0, stream>>>(
      HID, 2048, 0, W2T, 4096, 0, mlp_b2, 0, G2B, 1024, 0, 4608, 1024, 2048);
  gemm_bt<1, 1><<<dim3(16, 36, 1), 256, 0, stream>>>(
      HB, 1024, 0, W1T + 2048L * 1024, 0, mlp_b1 + 2048, 0, HID, 2048, 0, 4608, 2048, 1024);
  gemm64<0, 1, 1><<<dim3(8, 72, 1), 256, 0, stream>>>(
      HID, 2048, 0, W2T + 2048, 4096, 0, nullptr, 0, G2B, 1024, 0, 4608, 1024, 2048);
  k_addnorm_b<<<ROWS, 256, 0, stream>>>(HB, G2B, mlp_norm);
  // 5. router + lambdas
  k_meanl_p<<<dim3(8, 8), 256, 0, stream>>>(HB, MP);
  k_meanl_r<<<32, 256, 0, stream>>>(MP, S2);
  k_router<<<8, 256, 0, stream>>>(S2, router_w, router_b,
                                  lam_q1, lam_k1, lam_q2, lam_k2, RW, LAM);
  // 6. channel weights cast
  k_tcast<<<dim3(12, 4, 8), 256, 0, stream>>>(qkv_w, QKVWT, 128, 384);
  k_tcast<<<dim3(4, 4, 8), 256, 0, stream>>>(out_w, OWT, 128, 128);
  // 7. channels in 2 groups of 4
  for (int g = 0; g < 2; g++) {
    gemm64<1, 1, 0><<<dim3(3, 72, 4), 256, 0, stream>>>(
        HB + g * 4 * CW, 1024, CW,
        QKVWT + (long)g * 4 * 384 * 128, 128, 384 * 128,
        qkv_b + g * 4 * 384, 384,
        QKV, 384, (long)ROWS * 384, ROWS, 384, 128);
    k_qknorm_b<<<576, 256, 0, stream>>>(QKV, q_norm_w, k_norm_w, g * 4);
    k_attn_mfma<<<dim3(2, NHEADS, 32), 256, 0, stream>>>(
        QKV, LAM, head_norm_w, g * 4, DC);
    gemm64<1, 1, 0><<<dim3(1, 72, 4), 256, 0, stream>>>(
        DC, 128, (long)ROWS * 128,
        OWT + (long)g * 4 * 128 * 128, 128, 128 * 128,
        out_b + g * 4 * 128, 128,
        OP, 128, (long)ROWS * 128, ROWS, 128, 128);
    k_seg_b<<<dim3(ROWS, 4), 128, 0, stream>>>(HB, OP, seg_norm_w, RW, g * 4, G2B);
  }
  // 8. pool + head
  k_meanl_p<<<dim3(8, 8), 256, 0, stream>>>(G2B, MP);
  k_meanl_r<<<32, 256, 0, stream>>>(MP, S2);
  k_head<<<8, 256, 0, stream>>>(S2, head_w, head_b, out);
}

// Round 4
// 598.875 us; speedup vs baseline: 4.8563x; 1.1764x over previous
//
#include <hip/hip_runtime.h>
#include <math.h>

typedef __bf16 bf16;
typedef __bf16 bf16x8 __attribute__((ext_vector_type(8)));
typedef __bf16 bf16x4 __attribute__((ext_vector_type(4)));
typedef float f32x4 __attribute__((ext_vector_type(4)));

// ---------------- constants ----------------
constexpr int Bsz = 8, HIMG = 24, WIMG = 24;
constexpr int Lq = 576;
constexpr int WIDTH = 1024, NCH = 8, CW = 128;
constexpr int NHEADS = 8, HD = 16, HALF = 8;
constexpr float EPS = 1e-6f;
constexpr float LAMINIT = 0.2f;
constexpr float QSCALE = 0.35355339059327373f;  // 1/sqrt(8)
constexpr int ROWS = Bsz * Lq;              // 4608

// ---------------- workspace byte offsets ----------------
constexpr size_t B_HB    = 0;                        // bf16 h [4608][1024]
constexpr size_t B_G2B   = B_HB    + 9437184;        // bf16 g2 [4608][1024]
constexpr size_t B_ENCB  = B_G2B   + 9437184;        // bf16 enc [640][128]
constexpr size_t B_POSWT = B_ENCB  + 163840;         // bf16 [1024][128]
constexpr size_t B_QKVWT = B_POSWT + 262144;         // bf16 [8][384][128]
constexpr size_t B_OWT   = B_QKVWT + 786432;         // bf16 [8][128][128]
constexpr size_t B_SE    = B_OWT   + 262144;         // f32 [8][1024]
constexpr size_t B_S2    = B_SE    + 32768;          // f32 [8][1024]
constexpr size_t B_T1    = B_S2    + 32768;          // f32 [8][256] SE hidden
constexpr size_t B_MP    = B_T1    + 8192;           // f32 [8][8][1024] meanl partials
constexpr size_t B_RW    = B_MP    + 262144;         // f32 [64]
constexpr size_t B_LAM   = B_RW    + 256;            // f32 [8]
constexpr size_t B_POOL  = B_LAM   + 256;            // phase-shared pool
// pool (pos phase):  POS f32 [640][1024] = 2621440
// pool (MLP phase):  W1T 8388608 | W2T 8388608 | HID bf16 [4608][2048] 18874368  = 35651584
// pool (chan phase): QKV 14155776 | DC 4718592 | OP 4718592                      = 23592960
// high water: B_POOL + 35651584 ~= 56.3 MB

// ---------------- helpers ----------------
__device__ __forceinline__ float blockReduceSum256(float v, float* red) {
  #pragma unroll
  for (int off = 32; off; off >>= 1) v += __shfl_down(v, off, 64);
  int lane = threadIdx.x & 63, wid = threadIdx.x >> 6;
  if (lane == 0) red[wid] = v;
  __syncthreads();
  float total = 0.f;
  #pragma unroll
  for (int i = 0; i < 4; i++) total += red[i];
  return total;
}
__device__ __forceinline__ float silu(float x) { return x / (1.f + __expf(-x)); }

__device__ __forceinline__ void gl16(const bf16* g, bf16* l) {
  __builtin_amdgcn_global_load_lds(
      (const __attribute__((address_space(1))) void*)g,
      (__attribute__((address_space(3))) void*)l, 16, 0, 0);
}

// ---------------- cast+transpose: W fp32 [K][N] -> Wt bf16 [N][K] ----------------
__global__ __launch_bounds__(256) void k_tcast(const float* __restrict__ W,
    bf16* __restrict__ Wt, int K, int N) {
  __shared__ float t[32][33];
  int n0 = blockIdx.x * 32, k0 = blockIdx.y * 32;
  long zo = (long)blockIdx.z * K * N;
  int tid = threadIdx.x;
  int r = tid >> 3, c4 = (tid & 7) * 4;
  const float4 v = *(const float4*)(W + zo + (long)(k0 + r) * N + n0 + c4);
  t[c4 + 0][r] = v.x; t[c4 + 1][r] = v.y; t[c4 + 2][r] = v.z; t[c4 + 3][r] = v.w;
  __syncthreads();
  bf16* dst = Wt + zo + (long)(n0 + r) * K + k0 + c4;
  dst[0] = (bf16)t[r][c4 + 0]; dst[1] = (bf16)t[r][c4 + 1];
  dst[2] = (bf16)t[r][c4 + 2]; dst[3] = (bf16)t[r][c4 + 3];
}

// ---------------- positional encoding (bf16 out) ----------------
__global__ void k_enc_b(const float* __restrict__ fh, const float* __restrict__ fw,
                        const float* __restrict__ ph, const float* __restrict__ pw,
                        bf16* __restrict__ enc) {
  int idx = blockIdx.x * blockDim.x + threadIdx.x;
  if (idx >= Lq * 128) return;
  int l = idx >> 7, c = idx & 127;
  int hh = l / WIMG, ww = l % WIMG;
  float v;
  if (c < 64) {
    int f = c & 31;
    float fr = log1pf(__expf(fh[f])) * 10.f;
    float a = (hh / (float)HIMG) * fr + ph[f];
    v = (c < 32) ? sinf(a) : cosf(a);
  } else {
    int f = c & 31;
    float fr = log1pf(__expf(fw[f])) * 10.f;
    float a = (ww / (float)WIMG) * fr + pw[f];
    v = (c < 96) ? sinf(a) : cosf(a);
  }
  enc[idx] = (bf16)v;
}

// ---------------- bf16 MFMA GEMM 128x128: C = act(A @ Bt^T + bias) ----------------
template <int ACT, int OUTBF>
__global__ __launch_bounds__(256) void gemm_bt(
    const bf16* __restrict__ A, int lda, long aZs,
    const bf16* __restrict__ Bt, long bZs,
    const float* __restrict__ bias, int biasZs,
    void* __restrict__ Cv, int ldc, long cZs,
    int M, int N, int K) {
  __shared__ bf16 As[128 * 32];
  __shared__ bf16 Bs[128 * 32];
  int tid = threadIdx.x;
  int m0 = blockIdx.y * 128, n0 = blockIdx.x * 128;
  int z = blockIdx.z;
  const bf16* Ab = A + (long)z * aZs;
  const bf16* Bb = Bt + (long)z * bZs;
  f32x4 acc[4][4] = {};
  int wv = tid >> 6, lane = tid & 63;
  int wrow = (wv >> 1) * 64, wcol = (wv & 1) * 64;
  int lm = lane & 15, lq = lane >> 4;
  const bf16* ag = Ab + (long)(m0 + (tid >> 2)) * lda + (tid & 3) * 8;
  const bf16* bg = Bb + (long)(n0 + (tid >> 2)) * K + (tid & 3) * 8;
  bf16* asd = As + tid * 8;
  bf16* bsd = Bs + tid * 8;
  for (int k0 = 0; k0 < K; k0 += 32) {
    gl16(ag + k0, asd);
    gl16(ag + k0 + 64L * lda, asd + 2048);
    gl16(bg + k0, bsd);
    gl16(bg + k0 + 64L * K, bsd + 2048);
    __syncthreads();
    bf16x8 af[4], bfr[4];
    #pragma unroll
    for (int i = 0; i < 4; i++) {
      af[i]  = *(const bf16x8*)(As + (wrow + i * 16 + lm) * 32 + lq * 8);
      bfr[i] = *(const bf16x8*)(Bs + (wcol + i * 16 + lm) * 32 + lq * 8);
    }
    #pragma unroll
    for (int i = 0; i < 4; i++)
      #pragma unroll
      for (int j = 0; j < 4; j++)
        acc[i][j] = __builtin_amdgcn_mfma_f32_16x16x32_bf16(af[i], bfr[j], acc[i][j], 0, 0, 0);
    __syncthreads();
  }
  long cz = (long)z * cZs;
  const float* bz = bias ? bias + (long)z * biasZs : nullptr;
  #pragma unroll
  for (int i = 0; i < 4; i++) {
    int row = m0 + wrow + i * 16 + lq * 4;
    #pragma unroll
    for (int j = 0; j < 4; j++) {
      int col = n0 + wcol + j * 16 + lm;
      float bv = bz ? bz[col] : 0.f;
      #pragma unroll
      for (int r = 0; r < 4; r++) {
        float v = acc[i][j][r] + bv;
        if (ACT == 1) v = silu(v);
        long off = cz + (long)(row + r) * ldc + col;
        if (OUTBF) ((bf16*)Cv)[off] = (bf16)v;
        else       ((float*)Cv)[off] = v;
      }
    }
  }
}

// ---------------- bf16 MFMA GEMM 64x128 tile ----------------
template <int ACT, int OUTBF, int ACC>
__global__ __launch_bounds__(256) void gemm64(
    const bf16* __restrict__ A, int lda, long aZs,
    const bf16* __restrict__ Bt, int ldb, long bZs,
    const float* __restrict__ bias, int biasZs,
    void* __restrict__ Cv, int ldc, long cZs,
    int M, int N, int K) {
  __shared__ bf16 As[64 * 32];
  __shared__ bf16 Bs[128 * 32];
  int tid = threadIdx.x;
  int m0 = blockIdx.y * 64, n0 = blockIdx.x * 128;
  int z = blockIdx.z;
  const bf16* Ab = A + (long)z * aZs;
  const bf16* Bb = Bt + (long)z * bZs;
  f32x4 acc[4][2] = {};
  int wv = tid >> 6, lane = tid & 63;
  int lm = lane & 15, lq = lane >> 4;
  int wcol = wv * 32;
  const bf16* ag = Ab + (long)(m0 + (tid >> 2)) * lda + (tid & 3) * 8;
  const bf16* bg = Bb + (long)(n0 + (tid >> 2)) * ldb + (tid & 3) * 8;
  bf16* asd = As + tid * 8;
  bf16* bsd = Bs + tid * 8;
  for (int k0 = 0; k0 < K; k0 += 32) {
    if (tid < 256) gl16(ag + k0, asd);
    gl16(bg + k0, bsd);
    gl16(bg + k0 + 64L * ldb, bsd + 2048);
    __syncthreads();
    bf16x8 af[4], bfr[2];
    #pragma unroll
    for (int i = 0; i < 4; i++)
      af[i] = *(const bf16x8*)(As + (i * 16 + lm) * 32 + lq * 8);
    #pragma unroll
    for (int j = 0; j < 2; j++)
      bfr[j] = *(const bf16x8*)(Bs + (wcol + j * 16 + lm) * 32 + lq * 8);
    #pragma unroll
    for (int i = 0; i < 4; i++)
      #pragma unroll
      for (int j = 0; j < 2; j++)
        acc[i][j] = __builtin_amdgcn_mfma_f32_16x16x32_bf16(af[i], bfr[j], acc[i][j], 0, 0, 0);
    __syncthreads();
  }
  long cz = (long)z * cZs;
  const float* bz = bias ? bias + (long)z * biasZs : nullptr;
  #pragma unroll
  for (int i = 0; i < 4; i++) {
    int row = m0 + i * 16 + lq * 4;
    #pragma unroll
    for (int j = 0; j < 2; j++) {
      int col = n0 + wcol + j * 16 + lm;
      float bv = bz ? bz[col] : 0.f;
      #pragma unroll
      for (int r = 0; r < 4; r++) {
        float v = acc[i][j][r] + bv;
        long off = cz + (long)(row + r) * ldc + col;
        if (ACC) v += (float)((bf16*)Cv)[off];
        if (ACT == 1) v = silu(v);
        if (OUTBF) ((bf16*)Cv)[off] = (bf16)v;
        else       ((float*)Cv)[off] = v;
      }
    }
  }
}

// ---------------- embed + rmsnorm -> bf16 h ----------------
__global__ __launch_bounds__(256) void k_embed(const float* __restrict__ x,
    const float* __restrict__ emb, const float* __restrict__ pos,
    const float* __restrict__ nw, bf16* __restrict__ h) {
  __shared__ float red[4];
  int row = blockIdx.x;
  int l = row % Lq;
  int xi = (int)(x[row] * 255.f);
  xi = min(max(xi, 0), 255);
  const float* er = emb + (long)xi * WIDTH;
  const float* pr = pos + (long)l * WIDTH;
  int c0 = threadIdx.x * 4;
  float v[4]; float ss = 0.f;
  #pragma unroll
  for (int i = 0; i < 4; i++) { v[i] = er[c0 + i] + pr[c0 + i]; ss += v[i] * v[i]; }
  ss = blockReduceSum256(ss, red);
  float r = rsqrtf(ss / WIDTH + EPS);
  bf16* hr = h + (long)row * WIDTH;
  #pragma unroll
  for (int i = 0; i < 4; i++) hr[c0 + i] = (bf16)(v[i] * r * nw[c0 + i]);
}

// ---------------- mean over L: 2-phase ----------------
__global__ void k_meanl_p(const bf16* __restrict__ h, float* __restrict__ part) {
  int lp = blockIdx.x, b = blockIdx.y, t = threadIdx.x;
  const bf16* p = h + ((long)b * Lq + (long)lp * 72) * WIDTH + t * 4;
  float a0 = 0, a1 = 0, a2 = 0, a3 = 0;
  for (int l = 0; l < 72; l++) {
    bf16x4 v = *(const bf16x4*)(p + (long)l * WIDTH);
    a0 += (float)v[0]; a1 += (float)v[1]; a2 += (float)v[2]; a3 += (float)v[3];
  }
  float* dst = part + ((long)b * 8 + lp) * WIDTH + t * 4;
  dst[0] = a0; dst[1] = a1; dst[2] = a2; dst[3] = a3;
}
__global__ void k_meanl_r(const float* __restrict__ part, float* __restrict__ s) {
  int idx = blockIdx.x * 256 + threadIdx.x;
  if (idx >= Bsz * WIDTH) return;
  int b = idx >> 10, c = idx & 1023;
  float a = 0.f;
  for (int lp = 0; lp < 8; lp++) a += part[((long)b * 8 + lp) * WIDTH + c];
  s[idx] = a / 576.f;
}

// ---------------- SE phase 1: t1 = silu(s @ w1 + b1), grid (32 jb, 8 b) ----------------
__global__ __launch_bounds__(256) void k_se1(const float* __restrict__ s,
    const float* __restrict__ w1, const float* __restrict__ b1,
    float* __restrict__ t1) {
  __shared__ float red[256];
  int jb = blockIdx.x, b = blockIdx.y, t = threadIdx.x;
  int j = t & 7, part = t >> 3;           // 8 j x 32 kparts (32 c each)
  int j0 = jb * 8;
  const float* sb = s + b * 1024;
  float acc = 0.f;
  int c0 = part * 32;
  #pragma unroll 8
  for (int c = c0; c < c0 + 32; c++) acc += sb[c] * w1[c * 256 + j0 + j];
  red[t] = acc;
  __syncthreads();
  if (t < 8) {
    float a = b1[j0 + t];
    #pragma unroll
    for (int p = 0; p < 32; p++) a += red[p * 8 + t];
    t1[b * 256 + j0 + t] = silu(a);
  }
}

// ---------------- SE phase 2: s = sigmoid(t1 @ w2 + b2), grid (32 jb, 8 b) ----------------
__global__ __launch_bounds__(256) void k_se2(const float* __restrict__ t1,
    const float* __restrict__ w2, const float* __restrict__ b2,
    float* __restrict__ s) {
  __shared__ float red[256];
  int jb = blockIdx.x, b = blockIdx.y, t = threadIdx.x;
  int j = t & 31, part = t >> 5;          // 32 j x 8 kparts (32 c each)
  int j0 = jb * 32;
  const float* tb = t1 + b * 256;
  float acc = 0.f;
  int c0 = part * 32;
  #pragma unroll 8
  for (int c = c0; c < c0 + 32; c++) acc += tb[c] * w2[c * 1024 + j0 + j];
  red[t] = acc;
  __syncthreads();
  if (t < 32) {
    float a = b2[j0 + t];
    #pragma unroll
    for (int p = 0; p < 8; p++) a += red[p * 32 + t];
    s[b * 1024 + j0 + t] = 1.f / (1.f + __expf(-a));
  }
}

// ---------------- mix: h += rmsnorm(h*(s-1), mw)  (bf16 h) ----------------
__global__ __launch_bounds__(256) void k_mix_b(bf16* __restrict__ h,
    const float* __restrict__ s, const float* __restrict__ mw) {
  __shared__ float red[4];
  int row = blockIdx.x;
  int b = row / Lq;
  bf16* hr = h + (long)row * WIDTH;
  const float* sb = s + b * WIDTH;
  int c0 = threadIdx.x * 4;
  float hv[4], y[4]; float ss = 0.f;
  #pragma unroll
  for (int i = 0; i < 4; i++) {
    hv[i] = (float)hr[c0 + i];
    y[i] = hv[i] * (sb[c0 + i] - 1.f); ss += y[i] * y[i];
  }
  ss = blockReduceSum256(ss, red);
  float r = rsqrtf(ss / WIDTH + EPS);
  #pragma unroll
  for (int i = 0; i < 4; i++) hr[c0 + i] = (bf16)(hv[i] + y[i] * r * mw[c0 + i]);
}

// ---------------- h += rmsnorm(g, mw) (bf16) ----------------
__global__ __launch_bounds__(256) void k_addnorm_b(bf16* __restrict__ h,
    const bf16* __restrict__ g, const float* __restrict__ mw) {
  __shared__ float red[4];
  int row = blockIdx.x;
  bf16* hr = h + (long)row * WIDTH;
  const bf16* gr = g + (long)row * WIDTH;
  int c0 = threadIdx.x * 4;
  float y[4]; float ss = 0.f;
  #pragma unroll
  for (int i = 0; i < 4; i++) { y[i] = (float)gr[c0 + i]; ss += y[i] * y[i]; }
  ss = blockReduceSum256(ss, red);
  float r = rsqrtf(ss / WIDTH + EPS);
  #pragma unroll
  for (int i = 0; i < 4; i++)
    hr[c0 + i] = (bf16)((float)hr[c0 + i] + y[i] * r * mw[c0 + i]);
}

// ---------------- router + lambdas, one block per b ----------------
__global__ __launch_bounds__(256) void k_router(const float* __restrict__ s2,
    const float* __restrict__ rwgt, const float* __restrict__ rb,
    const float* __restrict__ lq1, const float* __restrict__ lk1,
    const float* __restrict__ lq2, const float* __restrict__ lk2,
    float* __restrict__ rw, float* __restrict__ lam) {
  __shared__ float red[256];
  __shared__ float lg[8];
  int b = blockIdx.x, t = threadIdx.x;
  int j = t & 7, part = t >> 3;
  const float* sb = s2 + b * 1024;
  float acc = 0.f;
  int c0 = part * 32;
  #pragma unroll 8
  for (int c = c0; c < c0 + 32; c++) acc += sb[c] * rwgt[c * 8 + j];
  red[t] = acc;
  __syncthreads();
  if (t < 8) {
    float a = rb[t];
    for (int p = 0; p < 32; p++) a += red[p * 8 + t];
    lg[t] = a;
  }
  __syncthreads();
  if (t == 0) {
    float v[8]; bool sel[8];
    #pragma unroll
    for (int i = 0; i < 8; i++) { v[i] = lg[i]; sel[i] = false; }
    int idxs[4]; float vals[4];
    for (int s = 0; s < 4; s++) {
      int bi = -1; float bv = -1e30f;
      for (int i = 0; i < 8; i++) if (!sel[i] && v[i] > bv) { bv = v[i]; bi = i; }
      sel[bi] = true; idxs[s] = bi; vals[s] = bv;
    }
    float m = vals[0], den = 0.f, e[4];
    for (int s = 0; s < 4; s++) { e[s] = __expf(vals[s] - m); den += e[s]; }
    for (int i = 0; i < 8; i++) rw[b * 8 + i] = 0.f;
    for (int s = 0; s < 4; s++) rw[b * 8 + idxs[s]] = e[s] / den;
  }
  if (b == 0 && t >= 8 && t < 16) {
    int c = t - 8;
    float d1 = 0.f, d2 = 0.f;
    for (int i = 0; i < 8; i++) {
      d1 += lq1[c * 8 + i] * lk1[c * 8 + i];
      d2 += lq2[c * 8 + i] * lk2[c * 8 + i];
    }
    lam[c] = __expf(d1) - __expf(d2) + LAMINIT;
  }
}

// ---------------- q/k rmsnorm, vectorized; q pre-scaled by 1/sqrt(8) ----------------
__device__ __forceinline__ bf16x8 normv(bf16x8 x, const float* w, float mul) {
  float v[8]; float ss = 0.f;
  #pragma unroll
  for (int i = 0; i < 8; i++) { v[i] = (float)x[i]; ss += v[i] * v[i]; }
  float r = rsqrtf(ss / 8.f + EPS) * mul;
  bf16x8 o;
  #pragma unroll
  for (int i = 0; i < 8; i++) o[i] = (bf16)(v[i] * r * w[i]);
  return o;
}

__global__ __launch_bounds__(256) void k_qknorm_b(bf16* __restrict__ qkv,
    const float* __restrict__ qn, const float* __restrict__ kn, int chBase) {
  int idx = blockIdx.x * 256 + threadIdx.x;
  if (idx >= 4 * ROWS * NHEADS) return;
  int z = idx / (ROWS * NHEADS);
  int rem = idx - z * (ROWS * NHEADS);
  int row = rem >> 3, head = rem & 7;
  int ch = chBase + z;
  bf16* qp = qkv + (long)z * ROWS * 384 + (long)row * 384 + head * 16;
  bf16x8 q0 = *(bf16x8*)(qp),       q1 = *(bf16x8*)(qp + 8);
  bf16x8 k0 = *(bf16x8*)(qp + 128), k1 = *(bf16x8*)(qp + 136);
  *(bf16x8*)(qp)       = normv(q0, qn + ch * 8, QSCALE);
  *(bf16x8*)(qp + 8)   = normv(q1, qn + ch * 8, QSCALE);
  *(bf16x8*)(qp + 128) = normv(k0, kn + ch * 8, 1.f);
  *(bf16x8*)(qp + 136) = normv(k1, kn + ch * 8, 1.f);
}

// ---------------- MFMA causal differential attention + fused combine ----------------
__global__ __launch_bounds__(256) void k_attn_mfma(
    const bf16* __restrict__ qkv, const float* __restrict__ lam,
    const float* __restrict__ hnw, int chBase, bf16* __restrict__ dc) {
  __shared__ bf16 Qs[576 * 16];
  __shared__ bf16 Ks[576 * 16];
  __shared__ bf16 Vt[16 * 584];
  __shared__ bf16 Ps[4][16 * 40];
  int tid = threadIdx.x;
  int head = blockIdx.y;
  int zz = blockIdx.z; int zc = zz >> 3, b = zz & 7;
  const bf16* qkvb = qkv + ((long)zc * ROWS + (long)b * Lq) * 384;
  for (int i = tid; i < 1152; i += 256) {
    int row = i >> 1, hf = i & 1;
    gl16(qkvb + (long)row * 384 + head * 16 + hf * 8, Qs + i * 8);
    gl16(qkvb + (long)row * 384 + 128 + head * 16 + hf * 8, Ks + i * 8);
  }
  for (int i = tid; i < 1152; i += 256) {
    int row = i >> 1, dh = i & 1;
    bf16x8 v = *(const bf16x8*)(qkvb + (long)row * 384 + 256 + head * 16 + dh * 8);
    #pragma unroll
    for (int j = 0; j < 8; j++) Vt[(dh * 8 + j) * 584 + row] = v[j];
  }
  __syncthreads();
  int wv = tid >> 6, lane = tid & 63;
  int lm = lane & 15, lq = lane >> 4;
  float lamv = lam[chBase + zc];
  float hwv = hnw[(chBase + zc) * 16 + lm];
  bf16* Pw = &Ps[wv][0];
  for (int qt = blockIdx.x * 4 + wv; qt < 36; qt += 8) {
    bf16x8 aq = {};
    if (lq < 2) aq = *(const bf16x8*)(Qs + (qt * 16 + lm) * 16 + lq * 8);
    f32x4 o[2] = {{0,0,0,0},{0,0,0,0}};
    float den[2][4] = {};
    int nch = (qt >> 1) + 1;
    for (int kc = 0; kc < nch; kc++) {
      f32x4 s[2][2] = {{{0,0,0,0},{0,0,0,0}},{{0,0,0,0},{0,0,0,0}}};
      #pragma unroll
      for (int t = 0; t < 2; t++) {
        int krow = kc * 32 + t * 16 + lm;
        bf16x8 b1 = {}, b2 = {};
        if (lq == 0) b1 = *(const bf16x8*)(Ks + krow * 16);
        if (lq == 1) b2 = *(const bf16x8*)(Ks + krow * 16 + 8);
        s[0][t] = __builtin_amdgcn_mfma_f32_16x16x32_bf16(aq, b1, s[0][t], 0, 0, 0);
        s[1][t] = __builtin_amdgcn_mfma_f32_16x16x32_bf16(aq, b2, s[1][t], 0, 0, 0);
      }
      bf16x8 vb = *(const bf16x8*)(Vt + lm * 584 + kc * 32 + lq * 8);
      #pragma unroll
      for (int w2 = 0; w2 < 2; w2++) {
        #pragma unroll
        for (int t = 0; t < 2; t++) {
          int gc = kc * 32 + t * 16 + lm;
          #pragma unroll
          for (int r = 0; r < 4; r++) {
            int gr = qt * 16 + lq * 4 + r;
            float e = (gc <= gr) ? __expf(s[w2][t][r]) : 0.f;
            bf16 pb = (bf16)e;
            Pw[(lq * 4 + r) * 40 + t * 16 + lm] = pb;
            den[w2][r] += (float)pb;
          }
        }
        bf16x8 pa = *(const bf16x8*)(Pw + lm * 40 + lq * 8);
        o[w2] = __builtin_amdgcn_mfma_f32_16x16x32_bf16(pa, vb, o[w2], 0, 0, 0);
      }
    }
    #pragma unroll
    for (int r = 0; r < 4; r++)
      #pragma unroll
      for (int m = 1; m < 16; m <<= 1) {
        den[0][r] += __shfl_xor(den[0][r], m);
        den[1][r] += __shfl_xor(den[1][r], m);
      }
    #pragma unroll
    for (int r = 0; r < 4; r++) {
      float dff = o[0][r] / den[0][r] - lamv * (o[1][r] / den[1][r]);
      float ss = dff * dff;
      #pragma unroll
      for (int m = 1; m < 16; m <<= 1) ss += __shfl_xor(ss, m);
      float rr = rsqrtf(ss / 16.f + EPS);
      long rowg = (long)zc * ROWS + (long)b * Lq + qt * 16 + lq * 4 + r;
      dc[rowg * 128 + head * 16 + lm] = (bf16)(dff * rr * hwv * (1.f - LAMINIT));
    }
  }
}

// ---------------- seg: g2 = (h_ch + rmsnorm(oproj, segw)) * rw ----------------
__global__ __launch_bounds__(128) void k_seg_b(const bf16* __restrict__ h,
    const bf16* __restrict__ op, const float* __restrict__ segw,
    const float* __restrict__ rw, int chBase, bf16* __restrict__ g2) {
  __shared__ float red[2];
  int row = blockIdx.x;
  int z = blockIdx.y;
  int ch = chBase + z;
  int b = row / Lq;
  int c = threadIdx.x;
  float y = (float)op[(long)z * ROWS * CW + (long)row * CW + c];
  float ss = y * y;
  #pragma unroll
  for (int off = 32; off; off >>= 1) ss += __shfl_down(ss, off, 64);
  int lane = c & 63, wid = c >> 6;
  if (lane == 0) red[wid] = ss;
  __syncthreads();
  float tot = red[0] + red[1];
  float r = rsqrtf(tot / CW + EPS);
  float hv = (float)h[(long)row * WIDTH + ch * CW + c];
  float outv = (hv + y * r * segw[ch * CW + c]) * rw[b * NCH + ch];
  g2[(long)row * WIDTH + ch * CW + c] = (bf16)outv;
}

// ---------------- head: one block per b ----------------
__global__ __launch_bounds__(256) void k_head(const float* __restrict__ pooled,
    const float* __restrict__ hw, const float* __restrict__ hb, float* __restrict__ out) {
  __shared__ float red[256];
  int b = blockIdx.x, t = threadIdx.x;
  int j = t & 15, part = t >> 4;
  float acc = 0.f;
  if (j < 10)
    for (int c = part * 64; c < part * 64 + 64; c++)
      acc += pooled[b * 1024 + c] * hw[c * 10 + j];
  red[t] = acc;
  __syncthreads();
  if (t < 10) {
    float a = hb[t];
    for (int p = 0; p < 16; p++) a += red[p * 16 + t];
    out[b * 10 + t] = a;
  }
}

// ---------------- launcher ----------------
extern "C" void kernel_launch(void* const* d_in, const int* in_sizes, int n_in,
                              void* d_out, int out_size, void* d_ws, size_t ws_size,
                              hipStream_t stream) {
  const float* x          = (const float*)d_in[0];
  const float* pixel_embed= (const float*)d_in[2];
  const float* freq_h     = (const float*)d_in[3];
  const float* freq_w     = (const float*)d_in[4];
  const float* phase_h    = (const float*)d_in[5];
  const float* phase_w    = (const float*)d_in[6];
  const float* pos_proj_w = (const float*)d_in[7];
  const float* pos_proj_b = (const float*)d_in[8];
  const float* embed_norm = (const float*)d_in[9];
  const float* se_w1      = (const float*)d_in[10];
  const float* se_b1      = (const float*)d_in[11];
  const float* se_w2      = (const float*)d_in[12];
  const float* se_b2      = (const float*)d_in[13];
  const float* mix_norm   = (const float*)d_in[14];
  const float* mlp_w1     = (const float*)d_in[15];
  const float* mlp_b1     = (const float*)d_in[16];
  const float* mlp_w2     = (const float*)d_in[17];
  const float* mlp_b2     = (const float*)d_in[18];
  const float* mlp_norm   = (const float*)d_in[19];
  const float* router_w   = (const float*)d_in[20];
  const float* router_b   = (const float*)d_in[21];
  const float* qkv_w      = (const float*)d_in[22];
  const float* qkv_b      = (const float*)d_in[23];
  const float* q_norm_w   = (const float*)d_in[24];
  const float* k_norm_w   = (const float*)d_in[25];
  const float* head_norm_w= (const float*)d_in[26];
  const float* lam_q1     = (const float*)d_in[27];
  const float* lam_k1     = (const float*)d_in[28];
  const float* lam_q2     = (const float*)d_in[29];
  const float* lam_k2     = (const float*)d_in[30];
  const float* out_w      = (const float*)d_in[31];
  const float* out_b      = (const float*)d_in[32];
  const float* seg_norm_w = (const float*)d_in[33];
  const float* head_w     = (const float*)d_in[34];
  const float* head_b     = (const float*)d_in[35];

  char* W = (char*)d_ws;
  bf16*  HB    = (bf16*)(W + B_HB);
  bf16*  G2B   = (bf16*)(W + B_G2B);
  bf16*  ENCB  = (bf16*)(W + B_ENCB);
  bf16*  POSWT = (bf16*)(W + B_POSWT);
  bf16*  QKVWT = (bf16*)(W + B_QKVWT);
  bf16*  OWT   = (bf16*)(W + B_OWT);
  float* SE    = (float*)(W + B_SE);
  float* S2    = (float*)(W + B_S2);
  float* T1    = (float*)(W + B_T1);
  float* MP    = (float*)(W + B_MP);
  float* RW    = (float*)(W + B_RW);
  float* LAM   = (float*)(W + B_LAM);
  char*  P     = W + B_POOL;
  float* POS   = (float*)P;
  bf16*  W1T   = (bf16*)P;
  bf16*  W2T   = (bf16*)(P + 8388608);
  bf16*  HID   = (bf16*)(P + 16777216);
  bf16*  QKV   = (bf16*)P;
  bf16*  DC    = (bf16*)(P + 14155776);
  bf16*  OP    = (bf16*)(P + 18874368);
  float* out   = (float*)d_out;

  // 1. positional encoding -> bf16, weight cast, gemm -> POS (f32)
  k_enc_b<<<288, 256, 0, stream>>>(freq_h, freq_w, phase_h, phase_w, ENCB);
  k_tcast<<<dim3(32, 4, 1), 256, 0, stream>>>(pos_proj_w, POSWT, 128, 1024);
  gemm64<0, 0, 0><<<dim3(8, 10, 1), 256, 0, stream>>>(
      ENCB, 128, 0, POSWT, 128, 0, pos_proj_b, 0, POS, 1024, 0, 640, 1024, 128);
  // 2. embed + rmsnorm -> bf16 h
  k_embed<<<ROWS, 256, 0, stream>>>(x, pixel_embed, POS, embed_norm, HB);
  // 3. SE gate (parallelized: 256 blocks per matvec)
  k_meanl_p<<<dim3(8, 8), 256, 0, stream>>>(HB, MP);
  k_meanl_r<<<32, 256, 0, stream>>>(MP, SE);
  k_se1<<<dim3(32, 8), 256, 0, stream>>>(SE, se_w1, se_b1, T1);
  k_se2<<<dim3(32, 8), 256, 0, stream>>>(T1, se_w2, se_b2, SE);
  k_mix_b<<<ROWS, 256, 0, stream>>>(HB, SE, mix_norm);
  // 4. MLP: split along hidden dim (2 halves of 2048), bf16 MFMA
  k_tcast<<<dim3(128, 32, 1), 256, 0, stream>>>(mlp_w1, W1T, 1024, 4096);
  k_tcast<<<dim3(32, 128, 1), 256, 0, stream>>>(mlp_w2, W2T, 4096, 1024);
  gemm_bt<1, 1><<<dim3(16, 36, 1), 256, 0, stream>>>(
      HB, 1024, 0, W1T, 0, mlp_b1, 0, HID, 2048, 0, 4608, 2048, 1024);
  gemm64<0, 1, 0><<<dim3(8, 72, 1), 256, 0, stream>>>(
      HID, 2048, 0, W2T, 4096, 0, mlp_b2, 0, G2B, 1024, 0, 4608, 1024, 2048);
  gemm_bt<1, 1><<<dim3(16, 36, 1), 256, 0, stream>>>(
      HB, 1024, 0, W1T + 2048L * 1024, 0, mlp_b1 + 2048, 0, HID, 2048, 0, 4608, 2048, 1024);
  gemm64<0, 1, 1><<<dim3(8, 72, 1), 256, 0, stream>>>(
      HID, 2048, 0, W2T + 2048, 4096, 0, nullptr, 0, G2B, 1024, 0, 4608, 1024, 2048);
  k_addnorm_b<<<ROWS, 256, 0, stream>>>(HB, G2B, mlp_norm);
  // 5. router + lambdas
  k_meanl_p<<<dim3(8, 8), 256, 0, stream>>>(HB, MP);
  k_meanl_r<<<32, 256, 0, stream>>>(MP, S2);
  k_router<<<8, 256, 0, stream>>>(S2, router_w, router_b,
                                  lam_q1, lam_k1, lam_q2, lam_k2, RW, LAM);
  // 6. channel weights cast
  k_tcast<<<dim3(12, 4, 8), 256, 0, stream>>>(qkv_w, QKVWT, 128, 384);
  k_tcast<<<dim3(4, 4, 8), 256, 0, stream>>>(out_w, OWT, 128, 128);
  // 7. channels in 2 groups of 4
  for (int g = 0; g < 2; g++) {
    gemm64<1, 1, 0><<<dim3(3, 72, 4), 256, 0, stream>>>(
        HB + g * 4 * CW, 1024, CW,
        QKVWT + (long)g * 4 * 384 * 128, 128, 384 * 128,
        qkv_b + g * 4 * 384, 384,
        QKV, 384, (long)ROWS * 384, ROWS, 384, 128);
    k_qknorm_b<<<576, 256, 0, stream>>>(QKV, q_norm_w, k_norm_w, g * 4);
    k_attn_mfma<<<dim3(2, NHEADS, 32), 256, 0, stream>>>(
        QKV, LAM, head_norm_w, g * 4, DC);
    gemm64<1, 1, 0><<<dim3(1, 72, 4), 256, 0, stream>>>(
        DC, 128, (long)ROWS * 128,
        OWT + (long)g * 4 * 128 * 128, 128, 128 * 128,
        out_b + g * 4 * 128, 128,
        OP, 128, (long)ROWS * 128, ROWS, 128, 128);
    k_seg_b<<<dim3(ROWS, 4), 128, 0, stream>>>(HB, OP, seg_norm_w, RW, g * 4, G2B);
  }
  // 8. pool + head
  k_meanl_p<<<dim3(8, 8), 256, 0, stream>>>(G2B, MP);
  k_meanl_r<<<32, 256, 0, stream>>>(MP, S2);
  k_head<<<8, 256, 0, stream>>>(S2, head_w, head_b, out);
}

// Round 5
// 549.461 us; speedup vs baseline: 5.2930x; 1.0899x over previous
//
#include <hip/hip_runtime.h>
#include <math.h>

typedef __bf16 bf16;
typedef __bf16 bf16x8 __attribute__((ext_vector_type(8)));
typedef __bf16 bf16x4 __attribute__((ext_vector_type(4)));
typedef float f32x4 __attribute__((ext_vector_type(4)));

// ---------------- constants ----------------
constexpr int Bsz = 8, HIMG = 24, WIMG = 24;
constexpr int Lq = 576;
constexpr int WIDTH = 1024, NCH = 8, CW = 128;
constexpr int NHEADS = 8, HD = 16, HALF = 8;
constexpr float EPS = 1e-6f;
constexpr float LAMINIT = 0.2f;
constexpr float QSCALE = 0.35355339059327373f;  // 1/sqrt(8)
constexpr int ROWS = Bsz * Lq;              // 4608

// ---------------- workspace byte offsets ----------------
constexpr size_t B_HB    = 0;                        // bf16 h [4608][1024]
constexpr size_t B_G2B   = B_HB    + 9437184;        // bf16 g2 [4608][1024]
constexpr size_t B_ENCB  = B_G2B   + 9437184;        // bf16 enc [640][128]
constexpr size_t B_POSWT = B_ENCB  + 163840;         // bf16 [1024][128]
constexpr size_t B_QKVWT = B_POSWT + 262144;         // bf16 [8][384][128]
constexpr size_t B_OWT   = B_QKVWT + 786432;         // bf16 [8][128][128]
constexpr size_t B_SE    = B_OWT   + 262144;         // f32 [8][1024]
constexpr size_t B_S2    = B_SE    + 32768;          // f32 [8][1024]
constexpr size_t B_T1    = B_S2    + 32768;          // f32 [8][256] SE hidden
constexpr size_t B_MP    = B_T1    + 8192;           // f32 [8][8][1024] meanl partials
constexpr size_t B_RW    = B_MP    + 262144;         // f32 [64]
constexpr size_t B_LAM   = B_RW    + 256;            // f32 [8]
constexpr size_t B_POOL  = B_LAM   + 256;            // phase-shared pool (~20.7MB base)
// pool (pos phase):  POS f32 [640][1024] = 2621440
// pool (MLP phase):  W1T 8388608 | W2T 8388608 | HID bf16 [4608][2048] 18874368 = 35651584
// pool (chan phase): QKV (8ch) 28311552 | DC 9437184  (out-proj runs IN-PLACE on DC)
// high water: B_POOL + 37748736 = 58434048 < 59375616 proven in R1

// ---------------- helpers ----------------
__device__ __forceinline__ float blockReduceSum256(float v, float* red) {
  #pragma unroll
  for (int off = 32; off; off >>= 1) v += __shfl_down(v, off, 64);
  int lane = threadIdx.x & 63, wid = threadIdx.x >> 6;
  if (lane == 0) red[wid] = v;
  __syncthreads();
  float total = 0.f;
  #pragma unroll
  for (int i = 0; i < 4; i++) total += red[i];
  return total;
}
__device__ __forceinline__ float silu(float x) { return x / (1.f + __expf(-x)); }

__device__ __forceinline__ void gl16(const bf16* g, bf16* l) {
  __builtin_amdgcn_global_load_lds(
      (const __attribute__((address_space(1))) void*)g,
      (__attribute__((address_space(3))) void*)l, 16, 0, 0);
}

// ---------------- cast+transpose: W fp32 [K][N] -> Wt bf16 [N][K] ----------------
__global__ __launch_bounds__(256) void k_tcast(const float* __restrict__ W,
    bf16* __restrict__ Wt, int K, int N) {
  __shared__ float t[32][33];
  int n0 = blockIdx.x * 32, k0 = blockIdx.y * 32;
  long zo = (long)blockIdx.z * K * N;
  int tid = threadIdx.x;
  int r = tid >> 3, c4 = (tid & 7) * 4;
  const float4 v = *(const float4*)(W + zo + (long)(k0 + r) * N + n0 + c4);
  t[c4 + 0][r] = v.x; t[c4 + 1][r] = v.y; t[c4 + 2][r] = v.z; t[c4 + 3][r] = v.w;
  __syncthreads();
  bf16* dst = Wt + zo + (long)(n0 + r) * K + k0 + c4;
  dst[0] = (bf16)t[r][c4 + 0]; dst[1] = (bf16)t[r][c4 + 1];
  dst[2] = (bf16)t[r][c4 + 2]; dst[3] = (bf16)t[r][c4 + 3];
}

// ---------------- positional encoding (bf16 out) ----------------
__global__ void k_enc_b(const float* __restrict__ fh, const float* __restrict__ fw,
                        const float* __restrict__ ph, const float* __restrict__ pw,
                        bf16* __restrict__ enc) {
  int idx = blockIdx.x * blockDim.x + threadIdx.x;
  if (idx >= Lq * 128) return;
  int l = idx >> 7, c = idx & 127;
  int hh = l / WIMG, ww = l % WIMG;
  float v;
  if (c < 64) {
    int f = c & 31;
    float fr = log1pf(__expf(fh[f])) * 10.f;
    float a = (hh / (float)HIMG) * fr + ph[f];
    v = (c < 32) ? sinf(a) : cosf(a);
  } else {
    int f = c & 31;
    float fr = log1pf(__expf(fw[f])) * 10.f;
    float a = (ww / (float)WIMG) * fr + pw[f];
    v = (c < 96) ? sinf(a) : cosf(a);
  }
  enc[idx] = (bf16)v;
}

// ---------------- bf16 MFMA GEMM 128x128: C = act(A @ Bt^T + bias) ----------------
template <int ACT, int OUTBF>
__global__ __launch_bounds__(256) void gemm_bt(
    const bf16* __restrict__ A, int lda, long aZs,
    const bf16* __restrict__ Bt, long bZs,
    const float* __restrict__ bias, int biasZs,
    void* __restrict__ Cv, int ldc, long cZs,
    int M, int N, int K) {
  __shared__ bf16 As[128 * 32];
  __shared__ bf16 Bs[128 * 32];
  int tid = threadIdx.x;
  int m0 = blockIdx.y * 128, n0 = blockIdx.x * 128;
  int z = blockIdx.z;
  const bf16* Ab = A + (long)z * aZs;
  const bf16* Bb = Bt + (long)z * bZs;
  f32x4 acc[4][4] = {};
  int wv = tid >> 6, lane = tid & 63;
  int wrow = (wv >> 1) * 64, wcol = (wv & 1) * 64;
  int lm = lane & 15, lq = lane >> 4;
  const bf16* ag = Ab + (long)(m0 + (tid >> 2)) * lda + (tid & 3) * 8;
  const bf16* bg = Bb + (long)(n0 + (tid >> 2)) * K + (tid & 3) * 8;
  bf16* asd = As + tid * 8;
  bf16* bsd = Bs + tid * 8;
  for (int k0 = 0; k0 < K; k0 += 32) {
    gl16(ag + k0, asd);
    gl16(ag + k0 + 64L * lda, asd + 2048);
    gl16(bg + k0, bsd);
    gl16(bg + k0 + 64L * K, bsd + 2048);
    __syncthreads();
    bf16x8 af[4], bfr[4];
    #pragma unroll
    for (int i = 0; i < 4; i++) {
      af[i]  = *(const bf16x8*)(As + (wrow + i * 16 + lm) * 32 + lq * 8);
      bfr[i] = *(const bf16x8*)(Bs + (wcol + i * 16 + lm) * 32 + lq * 8);
    }
    #pragma unroll
    for (int i = 0; i < 4; i++)
      #pragma unroll
      for (int j = 0; j < 4; j++)
        acc[i][j] = __builtin_amdgcn_mfma_f32_16x16x32_bf16(af[i], bfr[j], acc[i][j], 0, 0, 0);
    __syncthreads();
  }
  long cz = (long)z * cZs;
  const float* bz = bias ? bias + (long)z * biasZs : nullptr;
  #pragma unroll
  for (int i = 0; i < 4; i++) {
    int row = m0 + wrow + i * 16 + lq * 4;
    #pragma unroll
    for (int j = 0; j < 4; j++) {
      int col = n0 + wcol + j * 16 + lm;
      float bv = bz ? bz[col] : 0.f;
      #pragma unroll
      for (int r = 0; r < 4; r++) {
        float v = acc[i][j][r] + bv;
        if (ACT == 1) v = silu(v);
        long off = cz + (long)(row + r) * ldc + col;
        if (OUTBF) ((bf16*)Cv)[off] = (bf16)v;
        else       ((float*)Cv)[off] = v;
      }
    }
  }
}

// ---------------- bf16 MFMA GEMM 64x128 tile ----------------
template <int ACT, int OUTBF, int ACC>
__global__ __launch_bounds__(256) void gemm64(
    const bf16* __restrict__ A, int lda, long aZs,
    const bf16* __restrict__ Bt, int ldb, long bZs,
    const float* __restrict__ bias, int biasZs,
    void* __restrict__ Cv, int ldc, long cZs,
    int M, int N, int K) {
  __shared__ bf16 As[64 * 32];
  __shared__ bf16 Bs[128 * 32];
  int tid = threadIdx.x;
  int m0 = blockIdx.y * 64, n0 = blockIdx.x * 128;
  int z = blockIdx.z;
  const bf16* Ab = A + (long)z * aZs;
  const bf16* Bb = Bt + (long)z * bZs;
  f32x4 acc[4][2] = {};
  int wv = tid >> 6, lane = tid & 63;
  int lm = lane & 15, lq = lane >> 4;
  int wcol = wv * 32;
  const bf16* ag = Ab + (long)(m0 + (tid >> 2)) * lda + (tid & 3) * 8;
  const bf16* bg = Bb + (long)(n0 + (tid >> 2)) * ldb + (tid & 3) * 8;
  bf16* asd = As + tid * 8;
  bf16* bsd = Bs + tid * 8;
  for (int k0 = 0; k0 < K; k0 += 32) {
    if (tid < 256) gl16(ag + k0, asd);
    gl16(bg + k0, bsd);
    gl16(bg + k0 + 64L * ldb, bsd + 2048);
    __syncthreads();
    bf16x8 af[4], bfr[2];
    #pragma unroll
    for (int i = 0; i < 4; i++)
      af[i] = *(const bf16x8*)(As + (i * 16 + lm) * 32 + lq * 8);
    #pragma unroll
    for (int j = 0; j < 2; j++)
      bfr[j] = *(const bf16x8*)(Bs + (wcol + j * 16 + lm) * 32 + lq * 8);
    #pragma unroll
    for (int i = 0; i < 4; i++)
      #pragma unroll
      for (int j = 0; j < 2; j++)
        acc[i][j] = __builtin_amdgcn_mfma_f32_16x16x32_bf16(af[i], bfr[j], acc[i][j], 0, 0, 0);
    __syncthreads();
  }
  long cz = (long)z * cZs;
  const float* bz = bias ? bias + (long)z * biasZs : nullptr;
  #pragma unroll
  for (int i = 0; i < 4; i++) {
    int row = m0 + i * 16 + lq * 4;
    #pragma unroll
    for (int j = 0; j < 2; j++) {
      int col = n0 + wcol + j * 16 + lm;
      float bv = bz ? bz[col] : 0.f;
      #pragma unroll
      for (int r = 0; r < 4; r++) {
        float v = acc[i][j][r] + bv;
        long off = cz + (long)(row + r) * ldc + col;
        if (ACC) v += (float)((bf16*)Cv)[off];
        if (ACT == 1) v = silu(v);
        if (OUTBF) ((bf16*)Cv)[off] = (bf16)v;
        else       ((float*)Cv)[off] = v;
      }
    }
  }
}

// ---------------- embed + rmsnorm -> bf16 h ----------------
__global__ __launch_bounds__(256) void k_embed(const float* __restrict__ x,
    const float* __restrict__ emb, const float* __restrict__ pos,
    const float* __restrict__ nw, bf16* __restrict__ h) {
  __shared__ float red[4];
  int row = blockIdx.x;
  int l = row % Lq;
  int xi = (int)(x[row] * 255.f);
  xi = min(max(xi, 0), 255);
  const float* er = emb + (long)xi * WIDTH;
  const float* pr = pos + (long)l * WIDTH;
  int c0 = threadIdx.x * 4;
  float v[4]; float ss = 0.f;
  #pragma unroll
  for (int i = 0; i < 4; i++) { v[i] = er[c0 + i] + pr[c0 + i]; ss += v[i] * v[i]; }
  ss = blockReduceSum256(ss, red);
  float r = rsqrtf(ss / WIDTH + EPS);
  bf16* hr = h + (long)row * WIDTH;
  #pragma unroll
  for (int i = 0; i < 4; i++) hr[c0 + i] = (bf16)(v[i] * r * nw[c0 + i]);
}

// ---------------- mean over L: 2-phase ----------------
__global__ void k_meanl_p(const bf16* __restrict__ h, float* __restrict__ part) {
  int lp = blockIdx.x, b = blockIdx.y, t = threadIdx.x;
  const bf16* p = h + ((long)b * Lq + (long)lp * 72) * WIDTH + t * 4;
  float a0 = 0, a1 = 0, a2 = 0, a3 = 0;
  for (int l = 0; l < 72; l++) {
    bf16x4 v = *(const bf16x4*)(p + (long)l * WIDTH);
    a0 += (float)v[0]; a1 += (float)v[1]; a2 += (float)v[2]; a3 += (float)v[3];
  }
  float* dst = part + ((long)b * 8 + lp) * WIDTH + t * 4;
  dst[0] = a0; dst[1] = a1; dst[2] = a2; dst[3] = a3;
}
__global__ void k_meanl_r(const float* __restrict__ part, float* __restrict__ s) {
  int idx = blockIdx.x * 256 + threadIdx.x;
  if (idx >= Bsz * WIDTH) return;
  int b = idx >> 10, c = idx & 1023;
  float a = 0.f;
  for (int lp = 0; lp < 8; lp++) a += part[((long)b * 8 + lp) * WIDTH + c];
  s[idx] = a / 576.f;
}

// ---------------- SE phase 1: t1 = silu(s @ w1 + b1), grid (32 jb, 8 b) ----------------
__global__ __launch_bounds__(256) void k_se1(const float* __restrict__ s,
    const float* __restrict__ w1, const float* __restrict__ b1,
    float* __restrict__ t1) {
  __shared__ float red[256];
  int jb = blockIdx.x, b = blockIdx.y, t = threadIdx.x;
  int j = t & 7, part = t >> 3;
  int j0 = jb * 8;
  const float* sb = s + b * 1024;
  float acc = 0.f;
  int c0 = part * 32;
  #pragma unroll 8
  for (int c = c0; c < c0 + 32; c++) acc += sb[c] * w1[c * 256 + j0 + j];
  red[t] = acc;
  __syncthreads();
  if (t < 8) {
    float a = b1[j0 + t];
    #pragma unroll
    for (int p = 0; p < 32; p++) a += red[p * 8 + t];
    t1[b * 256 + j0 + t] = silu(a);
  }
}

// ---------------- SE phase 2: s = sigmoid(t1 @ w2 + b2), grid (32 jb, 8 b) ----------------
__global__ __launch_bounds__(256) void k_se2(const float* __restrict__ t1,
    const float* __restrict__ w2, const float* __restrict__ b2,
    float* __restrict__ s) {
  __shared__ float red[256];
  int jb = blockIdx.x, b = blockIdx.y, t = threadIdx.x;
  int j = t & 31, part = t >> 5;
  int j0 = jb * 32;
  const float* tb = t1 + b * 256;
  float acc = 0.f;
  int c0 = part * 32;
  #pragma unroll 8
  for (int c = c0; c < c0 + 32; c++) acc += tb[c] * w2[c * 1024 + j0 + j];
  red[t] = acc;
  __syncthreads();
  if (t < 32) {
    float a = b2[j0 + t];
    #pragma unroll
    for (int p = 0; p < 8; p++) a += red[p * 32 + t];
    s[b * 1024 + j0 + t] = 1.f / (1.f + __expf(-a));
  }
}

// ---------------- mix: h += rmsnorm(h*(s-1), mw)  (bf16 h) ----------------
__global__ __launch_bounds__(256) void k_mix_b(bf16* __restrict__ h,
    const float* __restrict__ s, const float* __restrict__ mw) {
  __shared__ float red[4];
  int row = blockIdx.x;
  int b = row / Lq;
  bf16* hr = h + (long)row * WIDTH;
  const float* sb = s + b * WIDTH;
  int c0 = threadIdx.x * 4;
  float hv[4], y[4]; float ss = 0.f;
  #pragma unroll
  for (int i = 0; i < 4; i++) {
    hv[i] = (float)hr[c0 + i];
    y[i] = hv[i] * (sb[c0 + i] - 1.f); ss += y[i] * y[i];
  }
  ss = blockReduceSum256(ss, red);
  float r = rsqrtf(ss / WIDTH + EPS);
  #pragma unroll
  for (int i = 0; i < 4; i++) hr[c0 + i] = (bf16)(hv[i] + y[i] * r * mw[c0 + i]);
}

// ---------------- h += rmsnorm(g, mw) (bf16) ----------------
__global__ __launch_bounds__(256) void k_addnorm_b(bf16* __restrict__ h,
    const bf16* __restrict__ g, const float* __restrict__ mw) {
  __shared__ float red[4];
  int row = blockIdx.x;
  bf16* hr = h + (long)row * WIDTH;
  const bf16* gr = g + (long)row * WIDTH;
  int c0 = threadIdx.x * 4;
  float y[4]; float ss = 0.f;
  #pragma unroll
  for (int i = 0; i < 4; i++) { y[i] = (float)gr[c0 + i]; ss += y[i] * y[i]; }
  ss = blockReduceSum256(ss, red);
  float r = rsqrtf(ss / WIDTH + EPS);
  #pragma unroll
  for (int i = 0; i < 4; i++)
    hr[c0 + i] = (bf16)((float)hr[c0 + i] + y[i] * r * mw[c0 + i]);
}

// ---------------- router + lambdas, one block per b ----------------
__global__ __launch_bounds__(256) void k_router(const float* __restrict__ s2,
    const float* __restrict__ rwgt, const float* __restrict__ rb,
    const float* __restrict__ lq1, const float* __restrict__ lk1,
    const float* __restrict__ lq2, const float* __restrict__ lk2,
    float* __restrict__ rw, float* __restrict__ lam) {
  __shared__ float red[256];
  __shared__ float lg[8];
  int b = blockIdx.x, t = threadIdx.x;
  int j = t & 7, part = t >> 3;
  const float* sb = s2 + b * 1024;
  float acc = 0.f;
  int c0 = part * 32;
  #pragma unroll 8
  for (int c = c0; c < c0 + 32; c++) acc += sb[c] * rwgt[c * 8 + j];
  red[t] = acc;
  __syncthreads();
  if (t < 8) {
    float a = rb[t];
    for (int p = 0; p < 32; p++) a += red[p * 8 + t];
    lg[t] = a;
  }
  __syncthreads();
  if (t == 0) {
    float v[8]; bool sel[8];
    #pragma unroll
    for (int i = 0; i < 8; i++) { v[i] = lg[i]; sel[i] = false; }
    int idxs[4]; float vals[4];
    for (int s = 0; s < 4; s++) {
      int bi = -1; float bv = -1e30f;
      for (int i = 0; i < 8; i++) if (!sel[i] && v[i] > bv) { bv = v[i]; bi = i; }
      sel[bi] = true; idxs[s] = bi; vals[s] = bv;
    }
    float m = vals[0], den = 0.f, e[4];
    for (int s = 0; s < 4; s++) { e[s] = __expf(vals[s] - m); den += e[s]; }
    for (int i = 0; i < 8; i++) rw[b * 8 + i] = 0.f;
    for (int s = 0; s < 4; s++) rw[b * 8 + idxs[s]] = e[s] / den;
  }
  if (b == 0 && t >= 8 && t < 16) {
    int c = t - 8;
    float d1 = 0.f, d2 = 0.f;
    for (int i = 0; i < 8; i++) {
      d1 += lq1[c * 8 + i] * lk1[c * 8 + i];
      d2 += lq2[c * 8 + i] * lk2[c * 8 + i];
    }
    lam[c] = __expf(d1) - __expf(d2) + LAMINIT;
  }
}

// ---------------- q/k rmsnorm, all 8 channels; q pre-scaled by 1/sqrt(8) ----------------
__device__ __forceinline__ bf16x8 normv(bf16x8 x, const float* w, float mul) {
  float v[8]; float ss = 0.f;
  #pragma unroll
  for (int i = 0; i < 8; i++) { v[i] = (float)x[i]; ss += v[i] * v[i]; }
  float r = rsqrtf(ss / 8.f + EPS) * mul;
  bf16x8 o;
  #pragma unroll
  for (int i = 0; i < 8; i++) o[i] = (bf16)(v[i] * r * w[i]);
  return o;
}

__global__ __launch_bounds__(256) void k_qknorm_b(bf16* __restrict__ qkv,
    const float* __restrict__ qn, const float* __restrict__ kn) {
  int idx = blockIdx.x * 256 + threadIdx.x;
  if (idx >= NCH * ROWS * NHEADS) return;
  int z = idx / (ROWS * NHEADS);
  int rem = idx - z * (ROWS * NHEADS);
  int row = rem >> 3, head = rem & 7;
  bf16* qp = qkv + (long)z * ROWS * 384 + (long)row * 384 + head * 16;
  bf16x8 q0 = *(bf16x8*)(qp),       q1 = *(bf16x8*)(qp + 8);
  bf16x8 k0 = *(bf16x8*)(qp + 128), k1 = *(bf16x8*)(qp + 136);
  *(bf16x8*)(qp)       = normv(q0, qn + z * 8, QSCALE);
  *(bf16x8*)(qp + 8)   = normv(q1, qn + z * 8, QSCALE);
  *(bf16x8*)(qp + 128) = normv(k0, kn + z * 8, 1.f);
  *(bf16x8*)(qp + 136) = normv(k1, kn + z * 8, 1.f);
}

// ---------------- MFMA causal differential attention + fused combine ----------------
// grid (2, 8 heads, 64 = zc*8+b), 256 threads = 4 waves.
// Paired q-tiles (32 rows per iteration). Q read from global (not staged).
// LDS: Ks[576][16] 18432B + Vt[16][584] 18688B + Ps[4][2][16*40] 10240B = 47360B
//      -> 3 blocks/CU (vs 2 at R4's 60.9KB)
__global__ __launch_bounds__(256) void k_attn_mfma(
    const bf16* __restrict__ qkv, const float* __restrict__ lam,
    const float* __restrict__ hnw, bf16* __restrict__ dc) {
  __shared__ bf16 Ks[576 * 16];
  __shared__ bf16 Vt[16 * 584];
  __shared__ bf16 Ps[4][2][16 * 40];
  int tid = threadIdx.x;
  int head = blockIdx.y;
  int zz = blockIdx.z; int zc = zz >> 3, b = zz & 7;
  const bf16* qkvb = qkv + ((long)zc * ROWS + (long)b * Lq) * 384;
  for (int i = tid; i < 1152; i += 256) {
    int row = i >> 1, hf = i & 1;
    gl16(qkvb + (long)row * 384 + 128 + head * 16 + hf * 8, Ks + i * 8);
  }
  for (int i = tid; i < 1152; i += 256) {
    int row = i >> 1, dh = i & 1;
    bf16x8 v = *(const bf16x8*)(qkvb + (long)row * 384 + 256 + head * 16 + dh * 8);
    #pragma unroll
    for (int j = 0; j < 8; j++) Vt[(dh * 8 + j) * 584 + row] = v[j];
  }
  __syncthreads();
  int wv = tid >> 6, lane = tid & 63;
  int lm = lane & 15, lq = lane >> 4;
  float lamv = lam[zc];
  float hwv = hnw[zc * 16 + lm] * (1.f - LAMINIT);
  bf16* P0 = &Ps[wv][0][0];
  bf16* P1 = &Ps[wv][1][0];
  for (int pr = blockIdx.x * 4 + wv; pr < 18; pr += 8) {
    // q A-frags for tiles qt0=2pr, qt1=2pr+1 direct from global
    bf16x8 aq0 = {}, aq1 = {};
    if (lq < 2) {
      aq0 = *(const bf16x8*)(qkvb + (long)(pr * 32 + lm) * 384 + head * 16 + lq * 8);
      aq1 = *(const bf16x8*)(qkvb + (long)(pr * 32 + 16 + lm) * 384 + head * 16 + lq * 8);
    }
    f32x4 o[2][2] = {};
    float den[2][2][4] = {};
    for (int kc = 0; kc <= pr; kc++) {
      f32x4 s[2][2][2] = {};  // [tile][w2][t]
      #pragma unroll
      for (int t = 0; t < 2; t++) {
        int krow = kc * 32 + t * 16 + lm;
        bf16x8 b1 = {}, b2 = {};
        if (lq == 0) b1 = *(const bf16x8*)(Ks + krow * 16);
        if (lq == 1) b2 = *(const bf16x8*)(Ks + krow * 16 + 8);
        s[0][0][t] = __builtin_amdgcn_mfma_f32_16x16x32_bf16(aq0, b1, s[0][0][t], 0, 0, 0);
        s[0][1][t] = __builtin_amdgcn_mfma_f32_16x16x32_bf16(aq0, b2, s[0][1][t], 0, 0, 0);
        s[1][0][t] = __builtin_amdgcn_mfma_f32_16x16x32_bf16(aq1, b1, s[1][0][t], 0, 0, 0);
        s[1][1][t] = __builtin_amdgcn_mfma_f32_16x16x32_bf16(aq1, b2, s[1][1][t], 0, 0, 0);
      }
      bf16x8 vb = *(const bf16x8*)(Vt + lm * 584 + kc * 32 + lq * 8);
      if (kc < pr) {
        // full chunks: no causal mask anywhere
        #pragma unroll
        for (int w2 = 0; w2 < 2; w2++) {
          #pragma unroll
          for (int t = 0; t < 2; t++)
            #pragma unroll
            for (int r = 0; r < 4; r++) {
              float e0 = __expf(s[0][w2][t][r]);
              float e1 = __expf(s[1][w2][t][r]);
              P0[(lq * 4 + r) * 40 + t * 16 + lm] = (bf16)e0;
              P1[(lq * 4 + r) * 40 + t * 16 + lm] = (bf16)e1;
              den[0][w2][r] += e0;
              den[1][w2][r] += e1;
            }
          bf16x8 pa0 = *(const bf16x8*)(P0 + lm * 40 + lq * 8);
          bf16x8 pa1 = *(const bf16x8*)(P1 + lm * 40 + lq * 8);
          o[0][w2] = __builtin_amdgcn_mfma_f32_16x16x32_bf16(pa0, vb, o[0][w2], 0, 0, 0);
          o[1][w2] = __builtin_amdgcn_mfma_f32_16x16x32_bf16(pa1, vb, o[1][w2], 0, 0, 0);
        }
      } else {
        // diagonal chunk kc==pr:
        //  tile0: t=0 triangular (lm <= lq*4+r), t=1 all masked (zero)
        //  tile1: t=0 full, t=1 triangular (lm <= lq*4+r)
        #pragma unroll
        for (int w2 = 0; w2 < 2; w2++) {
          #pragma unroll
          for (int r = 0; r < 4; r++) {
            bool keep = (lm <= lq * 4 + r);
            float e00 = keep ? __expf(s[0][w2][0][r]) : 0.f;
            float e10 = __expf(s[1][w2][0][r]);
            float e11 = keep ? __expf(s[1][w2][1][r]) : 0.f;
            P0[(lq * 4 + r) * 40 + lm] = (bf16)e00;
            P0[(lq * 4 + r) * 40 + 16 + lm] = (bf16)0.f;
            P1[(lq * 4 + r) * 40 + lm] = (bf16)e10;
            P1[(lq * 4 + r) * 40 + 16 + lm] = (bf16)e11;
            den[0][w2][r] += e00;
            den[1][w2][r] += e10 + e11;
          }
          bf16x8 pa0 = *(const bf16x8*)(P0 + lm * 40 + lq * 8);
          bf16x8 pa1 = *(const bf16x8*)(P1 + lm * 40 + lq * 8);
          o[0][w2] = __builtin_amdgcn_mfma_f32_16x16x32_bf16(pa0, vb, o[0][w2], 0, 0, 0);
          o[1][w2] = __builtin_amdgcn_mfma_f32_16x16x32_bf16(pa1, vb, o[1][w2], 0, 0, 0);
        }
      }
    }
    #pragma unroll
    for (int tile = 0; tile < 2; tile++)
      #pragma unroll
      for (int w2 = 0; w2 < 2; w2++)
        #pragma unroll
        for (int r = 0; r < 4; r++)
          #pragma unroll
          for (int m = 1; m < 16; m <<= 1)
            den[tile][w2][r] += __shfl_xor(den[tile][w2][r], m);
    #pragma unroll
    for (int tile = 0; tile < 2; tile++)
      #pragma unroll
      for (int r = 0; r < 4; r++) {
        float dff = o[tile][0][r] / den[tile][0][r]
                  - lamv * (o[tile][1][r] / den[tile][1][r]);
        float ss = dff * dff;
        #pragma unroll
        for (int m = 1; m < 16; m <<= 1) ss += __shfl_xor(ss, m);
        float rr = rsqrtf(ss / 16.f + EPS);
        long rowg = (long)zc * ROWS + (long)b * Lq + pr * 32 + tile * 16 + lq * 4 + r;
        dc[rowg * 128 + head * 16 + lm] = (bf16)(dff * rr * hwv);
      }
  }
}

// ---------------- seg: g2 = (h_ch + rmsnorm(oproj, segw)) * rw ----------------
__global__ __launch_bounds__(128) void k_seg_b(const bf16* __restrict__ h,
    const bf16* __restrict__ op, const float* __restrict__ segw,
    const float* __restrict__ rw, bf16* __restrict__ g2) {
  __shared__ float red[2];
  int row = blockIdx.x;
  int ch = blockIdx.y;
  int b = row / Lq;
  int c = threadIdx.x;
  float y = (float)op[(long)ch * ROWS * CW + (long)row * CW + c];
  float ss = y * y;
  #pragma unroll
  for (int off = 32; off; off >>= 1) ss += __shfl_down(ss, off, 64);
  int lane = c & 63, wid = c >> 6;
  if (lane == 0) red[wid] = ss;
  __syncthreads();
  float tot = red[0] + red[1];
  float r = rsqrtf(tot / CW + EPS);
  float hv = (float)h[(long)row * WIDTH + ch * CW + c];
  float outv = (hv + y * r * segw[ch * CW + c]) * rw[b * NCH + ch];
  g2[(long)row * WIDTH + ch * CW + c] = (bf16)outv;
}

// ---------------- head: one block per b ----------------
__global__ __launch_bounds__(256) void k_head(const float* __restrict__ pooled,
    const float* __restrict__ hw, const float* __restrict__ hb, float* __restrict__ out) {
  __shared__ float red[256];
  int b = blockIdx.x, t = threadIdx.x;
  int j = t & 15, part = t >> 4;
  float acc = 0.f;
  if (j < 10)
    for (int c = part * 64; c < part * 64 + 64; c++)
      acc += pooled[b * 1024 + c] * hw[c * 10 + j];
  red[t] = acc;
  __syncthreads();
  if (t < 10) {
    float a = hb[t];
    for (int p = 0; p < 16; p++) a += red[p * 16 + t];
    out[b * 10 + t] = a;
  }
}

// ---------------- launcher ----------------
extern "C" void kernel_launch(void* const* d_in, const int* in_sizes, int n_in,
                              void* d_out, int out_size, void* d_ws, size_t ws_size,
                              hipStream_t stream) {
  const float* x          = (const float*)d_in[0];
  const float* pixel_embed= (const float*)d_in[2];
  const float* freq_h     = (const float*)d_in[3];
  const float* freq_w     = (const float*)d_in[4];
  const float* phase_h    = (const float*)d_in[5];
  const float* phase_w    = (const float*)d_in[6];
  const float* pos_proj_w = (const float*)d_in[7];
  const float* pos_proj_b = (const float*)d_in[8];
  const float* embed_norm = (const float*)d_in[9];
  const float* se_w1      = (const float*)d_in[10];
  const float* se_b1      = (const float*)d_in[11];
  const float* se_w2      = (const float*)d_in[12];
  const float* se_b2      = (const float*)d_in[13];
  const float* mix_norm   = (const float*)d_in[14];
  const float* mlp_w1     = (const float*)d_in[15];
  const float* mlp_b1     = (const float*)d_in[16];
  const float* mlp_w2     = (const float*)d_in[17];
  const float* mlp_b2     = (const float*)d_in[18];
  const float* mlp_norm   = (const float*)d_in[19];
  const float* router_w   = (const float*)d_in[20];
  const float* router_b   = (const float*)d_in[21];
  const float* qkv_w      = (const float*)d_in[22];
  const float* qkv_b      = (const float*)d_in[23];
  const float* q_norm_w   = (const float*)d_in[24];
  const float* k_norm_w   = (const float*)d_in[25];
  const float* head_norm_w= (const float*)d_in[26];
  const float* lam_q1     = (const float*)d_in[27];
  const float* lam_k1     = (const float*)d_in[28];
  const float* lam_q2     = (const float*)d_in[29];
  const float* lam_k2     = (const float*)d_in[30];
  const float* out_w      = (const float*)d_in[31];
  const float* out_b      = (const float*)d_in[32];
  const float* seg_norm_w = (const float*)d_in[33];
  const float* head_w     = (const float*)d_in[34];
  const float* head_b     = (const float*)d_in[35];

  char* W = (char*)d_ws;
  bf16*  HB    = (bf16*)(W + B_HB);
  bf16*  G2B   = (bf16*)(W + B_G2B);
  bf16*  ENCB  = (bf16*)(W + B_ENCB);
  bf16*  POSWT = (bf16*)(W + B_POSWT);
  bf16*  QKVWT = (bf16*)(W + B_QKVWT);
  bf16*  OWT   = (bf16*)(W + B_OWT);
  float* SE    = (float*)(W + B_SE);
  float* S2    = (float*)(W + B_S2);
  float* T1    = (float*)(W + B_T1);
  float* MP    = (float*)(W + B_MP);
  float* RW    = (float*)(W + B_RW);
  float* LAM   = (float*)(W + B_LAM);
  char*  P     = W + B_POOL;
  float* POS   = (float*)P;
  bf16*  W1T   = (bf16*)P;
  bf16*  W2T   = (bf16*)(P + 8388608);
  bf16*  HID   = (bf16*)(P + 16777216);
  bf16*  QKV   = (bf16*)P;
  bf16*  DC    = (bf16*)(P + 28311552);
  float* out   = (float*)d_out;

  // 1. positional encoding -> bf16, weight cast, gemm -> POS (f32)
  k_enc_b<<<288, 256, 0, stream>>>(freq_h, freq_w, phase_h, phase_w, ENCB);
  k_tcast<<<dim3(32, 4, 1), 256, 0, stream>>>(pos_proj_w, POSWT, 128, 1024);
  gemm64<0, 0, 0><<<dim3(8, 10, 1), 256, 0, stream>>>(
      ENCB, 128, 0, POSWT, 128, 0, pos_proj_b, 0, POS, 1024, 0, 640, 1024, 128);
  // 2. embed + rmsnorm -> bf16 h
  k_embed<<<ROWS, 256, 0, stream>>>(x, pixel_embed, POS, embed_norm, HB);
  // 3. SE gate
  k_meanl_p<<<dim3(8, 8), 256, 0, stream>>>(HB, MP);
  k_meanl_r<<<32, 256, 0, stream>>>(MP, SE);
  k_se1<<<dim3(32, 8), 256, 0, stream>>>(SE, se_w1, se_b1, T1);
  k_se2<<<dim3(32, 8), 256, 0, stream>>>(T1, se_w2, se_b2, SE);
  k_mix_b<<<ROWS, 256, 0, stream>>>(HB, SE, mix_norm);
  // 4. MLP: split along hidden dim (2 halves of 2048), bf16 MFMA
  k_tcast<<<dim3(128, 32, 1), 256, 0, stream>>>(mlp_w1, W1T, 1024, 4096);
  k_tcast<<<dim3(32, 128, 1), 256, 0, stream>>>(mlp_w2, W2T, 4096, 1024);
  gemm_bt<1, 1><<<dim3(16, 36, 1), 256, 0, stream>>>(
      HB, 1024, 0, W1T, 0, mlp_b1, 0, HID, 2048, 0, 4608, 2048, 1024);
  gemm64<0, 1, 0><<<dim3(8, 72, 1), 256, 0, stream>>>(
      HID, 2048, 0, W2T, 4096, 0, mlp_b2, 0, G2B, 1024, 0, 4608, 1024, 2048);
  gemm_bt<1, 1><<<dim3(16, 36, 1), 256, 0, stream>>>(
      HB, 1024, 0, W1T + 2048L * 1024, 0, mlp_b1 + 2048, 0, HID, 2048, 0, 4608, 2048, 1024);
  gemm64<0, 1, 1><<<dim3(8, 72, 1), 256, 0, stream>>>(
      HID, 2048, 0, W2T + 2048, 4096, 0, nullptr, 0, G2B, 1024, 0, 4608, 1024, 2048);
  k_addnorm_b<<<ROWS, 256, 0, stream>>>(HB, G2B, mlp_norm);
  // 5. router + lambdas
  k_meanl_p<<<dim3(8, 8), 256, 0, stream>>>(HB, MP);
  k_meanl_r<<<32, 256, 0, stream>>>(MP, S2);
  k_router<<<8, 256, 0, stream>>>(S2, router_w, router_b,
                                  lam_q1, lam_k1, lam_q2, lam_k2, RW, LAM);
  // 6. channel weights cast
  k_tcast<<<dim3(12, 4, 8), 256, 0, stream>>>(qkv_w, QKVWT, 128, 384);
  k_tcast<<<dim3(4, 4, 8), 256, 0, stream>>>(out_w, OWT, 128, 128);
  // 7. all 8 channels in one pass
  gemm64<1, 1, 0><<<dim3(3, 72, 8), 256, 0, stream>>>(
      HB, 1024, CW, QKVWT, 128, 384 * 128, qkv_b, 384,
      QKV, 384, (long)ROWS * 384, ROWS, 384, 128);
  k_qknorm_b<<<1152, 256, 0, stream>>>(QKV, q_norm_w, k_norm_w);
  k_attn_mfma<<<dim3(2, NHEADS, 64), 256, 0, stream>>>(QKV, LAM, head_norm_w, DC);
  // out-proj IN-PLACE on DC (block reads exactly the rows it writes; reads complete
  // before the epilogue stores, and grid.x==1 gives a 1:1 block<->tile mapping)
  gemm64<1, 1, 0><<<dim3(1, 72, 8), 256, 0, stream>>>(
      DC, 128, (long)ROWS * 128, OWT, 128, 128 * 128, out_b, 128,
      DC, 128, (long)ROWS * 128, ROWS, 128, 128);
  k_seg_b<<<dim3(ROWS, 8), 128, 0, stream>>>(HB, DC, seg_norm_w, RW, G2B);
  // 8. pool + head
  k_meanl_p<<<dim3(8, 8), 256, 0, stream>>>(G2B, MP);
  k_meanl_r<<<32, 256, 0, stream>>>(MP, S2);
  k_head<<<8, 256, 0, stream>>>(S2, head_w, head_b, out);
}

// Round 6
// 503.180 us; speedup vs baseline: 5.7799x; 1.0920x over previous
//
#include <hip/hip_runtime.h>
#include <math.h>

typedef __bf16 bf16;
typedef __bf16 bf16x8 __attribute__((ext_vector_type(8)));
typedef __bf16 bf16x4 __attribute__((ext_vector_type(4)));
typedef __bf16 bf16x2 __attribute__((ext_vector_type(2)));
typedef float f32x4 __attribute__((ext_vector_type(4)));
typedef short s16x4 __attribute__((ext_vector_type(4)));

// ---------------- constants ----------------
constexpr int Bsz = 8, HIMG = 24, WIMG = 24;
constexpr int Lq = 576;
constexpr int WIDTH = 1024, NCH = 8, CW = 128;
constexpr int NHEADS = 8, HD = 16, HALF = 8;
constexpr float EPS = 1e-6f;
constexpr float LAMINIT = 0.2f;
constexpr float QSCALE = 0.35355339059327373f;  // 1/sqrt(8)
constexpr int ROWS = Bsz * Lq;              // 4608

// ---------------- workspace byte offsets ----------------
constexpr size_t B_HB    = 0;                        // bf16 h [4608][1024]
constexpr size_t B_G2B   = B_HB    + 9437184;        // bf16 g2 [4608][1024] (MLP out)
constexpr size_t B_ENCB  = B_G2B   + 9437184;        // bf16 enc [640][128]
constexpr size_t B_POSWT = B_ENCB  + 163840;         // bf16 [1024][128]
constexpr size_t B_QKVWT = B_POSWT + 262144;         // bf16 [8][384][128]
constexpr size_t B_OWT   = B_QKVWT + 786432;         // bf16 [8][128][128]
constexpr size_t B_SE    = B_OWT   + 262144;         // f32 [8][1024]
constexpr size_t B_T1    = B_SE    + 32768;          // f32 [8][256] SE hidden
constexpr size_t B_MP    = B_T1    + 8192;           // f32 [8][8][1024] pool partials
constexpr size_t B_RW    = B_MP    + 262144;         // f32 [64]
constexpr size_t B_LAM   = B_RW    + 256;            // f32 [8]
constexpr size_t B_POOL  = B_LAM   + 256;            // phase-shared pool
// pool (pos phase):  POS f32 [640][1024] = 2621440
// pool (MLP phase):  W1T 8388608 | W2T 8388608 | HID bf16 [4608][2048] 18874368 = 35651584
// pool (chan phase): QKV (8ch) 28311552 | DC 9437184 (out-proj IN-PLACE on DC)
// high water: B_POOL + 37748736 ~= 58.4 MB (< 59.4 MB proven in R1)

// ---------------- helpers ----------------
__device__ __forceinline__ float blockReduceSum256(float v, float* red) {
  #pragma unroll
  for (int off = 32; off; off >>= 1) v += __shfl_down(v, off, 64);
  int lane = threadIdx.x & 63, wid = threadIdx.x >> 6;
  if (lane == 0) red[wid] = v;
  __syncthreads();
  float total = 0.f;
  #pragma unroll
  for (int i = 0; i < 4; i++) total += red[i];
  return total;
}
__device__ __forceinline__ float silu(float x) { return x / (1.f + __expf(-x)); }

__device__ __forceinline__ void gl16(const bf16* g, bf16* l) {
  __builtin_amdgcn_global_load_lds(
      (const __attribute__((address_space(1))) void*)g,
      (__attribute__((address_space(3))) void*)l, 16, 0, 0);
}

// v_mfma_f32_16x16x16_bf16 wrapper (A,B = 4 bf16/lane; k = quad*4+j)
__device__ __forceinline__ f32x4 mfma16(bf16x4 a, bf16x4 b, f32x4 c) {
#if __has_builtin(__builtin_amdgcn_mfma_f32_16x16x16bf16_1k)
  union { bf16x4 h; s16x4 s; } ua, ub;
  ua.h = a; ub.h = b;
  return __builtin_amdgcn_mfma_f32_16x16x16bf16_1k(ua.s, ub.s, c, 0, 0, 0);
#else
  f32x4 d = c;
  asm volatile("v_mfma_f32_16x16x16_bf16 %0, %1, %2, %0"
               : "+v"(d) : "v"(a), "v"(b));
  return d;
#endif
}

// ---------------- cast+transpose: W fp32 [K][N] -> Wt bf16 [N][K] ----------------
__global__ __launch_bounds__(256) void k_tcast(const float* __restrict__ W,
    bf16* __restrict__ Wt, int K, int N) {
  __shared__ float t[32][33];
  int n0 = blockIdx.x * 32, k0 = blockIdx.y * 32;
  long zo = (long)blockIdx.z * K * N;
  int tid = threadIdx.x;
  int r = tid >> 3, c4 = (tid & 7) * 4;
  const float4 v = *(const float4*)(W + zo + (long)(k0 + r) * N + n0 + c4);
  t[c4 + 0][r] = v.x; t[c4 + 1][r] = v.y; t[c4 + 2][r] = v.z; t[c4 + 3][r] = v.w;
  __syncthreads();
  bf16* dst = Wt + zo + (long)(n0 + r) * K + k0 + c4;
  dst[0] = (bf16)t[r][c4 + 0]; dst[1] = (bf16)t[r][c4 + 1];
  dst[2] = (bf16)t[r][c4 + 2]; dst[3] = (bf16)t[r][c4 + 3];
}

// ---------------- positional encoding (bf16 out) ----------------
__global__ void k_enc_b(const float* __restrict__ fh, const float* __restrict__ fw,
                        const float* __restrict__ ph, const float* __restrict__ pw,
                        bf16* __restrict__ enc) {
  int idx = blockIdx.x * blockDim.x + threadIdx.x;
  if (idx >= Lq * 128) return;
  int l = idx >> 7, c = idx & 127;
  int hh = l / WIMG, ww = l % WIMG;
  float v;
  if (c < 64) {
    int f = c & 31;
    float fr = log1pf(__expf(fh[f])) * 10.f;
    float a = (hh / (float)HIMG) * fr + ph[f];
    v = (c < 32) ? sinf(a) : cosf(a);
  } else {
    int f = c & 31;
    float fr = log1pf(__expf(fw[f])) * 10.f;
    float a = (ww / (float)WIMG) * fr + pw[f];
    v = (c < 96) ? sinf(a) : cosf(a);
  }
  enc[idx] = (bf16)v;
}

// ---------------- bf16 MFMA GEMM 128x128 ----------------
template <int ACT, int OUTBF>
__global__ __launch_bounds__(256) void gemm_bt(
    const bf16* __restrict__ A, int lda, long aZs,
    const bf16* __restrict__ Bt, long bZs,
    const float* __restrict__ bias, int biasZs,
    void* __restrict__ Cv, int ldc, long cZs,
    int M, int N, int K) {
  __shared__ bf16 As[128 * 32];
  __shared__ bf16 Bs[128 * 32];
  int tid = threadIdx.x;
  int m0 = blockIdx.y * 128, n0 = blockIdx.x * 128;
  int z = blockIdx.z;
  const bf16* Ab = A + (long)z * aZs;
  const bf16* Bb = Bt + (long)z * bZs;
  f32x4 acc[4][4] = {};
  int wv = tid >> 6, lane = tid & 63;
  int wrow = (wv >> 1) * 64, wcol = (wv & 1) * 64;
  int lm = lane & 15, lq = lane >> 4;
  const bf16* ag = Ab + (long)(m0 + (tid >> 2)) * lda + (tid & 3) * 8;
  const bf16* bg = Bb + (long)(n0 + (tid >> 2)) * K + (tid & 3) * 8;
  bf16* asd = As + tid * 8;
  bf16* bsd = Bs + tid * 8;
  for (int k0 = 0; k0 < K; k0 += 32) {
    gl16(ag + k0, asd);
    gl16(ag + k0 + 64L * lda, asd + 2048);
    gl16(bg + k0, bsd);
    gl16(bg + k0 + 64L * K, bsd + 2048);
    __syncthreads();
    bf16x8 af[4], bfr[4];
    #pragma unroll
    for (int i = 0; i < 4; i++) {
      af[i]  = *(const bf16x8*)(As + (wrow + i * 16 + lm) * 32 + lq * 8);
      bfr[i] = *(const bf16x8*)(Bs + (wcol + i * 16 + lm) * 32 + lq * 8);
    }
    #pragma unroll
    for (int i = 0; i < 4; i++)
      #pragma unroll
      for (int j = 0; j < 4; j++)
        acc[i][j] = __builtin_amdgcn_mfma_f32_16x16x32_bf16(af[i], bfr[j], acc[i][j], 0, 0, 0);
    __syncthreads();
  }
  long cz = (long)z * cZs;
  const float* bz = bias ? bias + (long)z * biasZs : nullptr;
  #pragma unroll
  for (int i = 0; i < 4; i++) {
    int row = m0 + wrow + i * 16 + lq * 4;
    #pragma unroll
    for (int j = 0; j < 4; j++) {
      int col = n0 + wcol + j * 16 + lm;
      float bv = bz ? bz[col] : 0.f;
      #pragma unroll
      for (int r = 0; r < 4; r++) {
        float v = acc[i][j][r] + bv;
        if (ACT == 1) v = silu(v);
        long off = cz + (long)(row + r) * ldc + col;
        if (OUTBF) ((bf16*)Cv)[off] = (bf16)v;
        else       ((float*)Cv)[off] = v;
      }
    }
  }
}

// ---------------- bf16 MFMA GEMM 64x128 tile ----------------
template <int ACT, int OUTBF, int ACC>
__global__ __launch_bounds__(256) void gemm64(
    const bf16* __restrict__ A, int lda, long aZs,
    const bf16* __restrict__ Bt, int ldb, long bZs,
    const float* __restrict__ bias, int biasZs,
    void* __restrict__ Cv, int ldc, long cZs,
    int M, int N, int K) {
  __shared__ bf16 As[64 * 32];
  __shared__ bf16 Bs[128 * 32];
  int tid = threadIdx.x;
  int m0 = blockIdx.y * 64, n0 = blockIdx.x * 128;
  int z = blockIdx.z;
  const bf16* Ab = A + (long)z * aZs;
  const bf16* Bb = Bt + (long)z * bZs;
  f32x4 acc[4][2] = {};
  int wv = tid >> 6, lane = tid & 63;
  int lm = lane & 15, lq = lane >> 4;
  int wcol = wv * 32;
  const bf16* ag = Ab + (long)(m0 + (tid >> 2)) * lda + (tid & 3) * 8;
  const bf16* bg = Bb + (long)(n0 + (tid >> 2)) * ldb + (tid & 3) * 8;
  bf16* asd = As + tid * 8;
  bf16* bsd = Bs + tid * 8;
  for (int k0 = 0; k0 < K; k0 += 32) {
    if (tid < 256) gl16(ag + k0, asd);
    gl16(bg + k0, bsd);
    gl16(bg + k0 + 64L * ldb, bsd + 2048);
    __syncthreads();
    bf16x8 af[4], bfr[2];
    #pragma unroll
    for (int i = 0; i < 4; i++)
      af[i] = *(const bf16x8*)(As + (i * 16 + lm) * 32 + lq * 8);
    #pragma unroll
    for (int j = 0; j < 2; j++)
      bfr[j] = *(const bf16x8*)(Bs + (wcol + j * 16 + lm) * 32 + lq * 8);
    #pragma unroll
    for (int i = 0; i < 4; i++)
      #pragma unroll
      for (int j = 0; j < 2; j++)
        acc[i][j] = __builtin_amdgcn_mfma_f32_16x16x32_bf16(af[i], bfr[j], acc[i][j], 0, 0, 0);
    __syncthreads();
  }
  long cz = (long)z * cZs;
  const float* bz = bias ? bias + (long)z * biasZs : nullptr;
  #pragma unroll
  for (int i = 0; i < 4; i++) {
    int row = m0 + i * 16 + lq * 4;
    #pragma unroll
    for (int j = 0; j < 2; j++) {
      int col = n0 + wcol + j * 16 + lm;
      float bv = bz ? bz[col] : 0.f;
      #pragma unroll
      for (int r = 0; r < 4; r++) {
        float v = acc[i][j][r] + bv;
        long off = cz + (long)(row + r) * ldc + col;
        if (ACC) v += (float)((bf16*)Cv)[off];
        if (ACT == 1) v = silu(v);
        if (OUTBF) ((bf16*)Cv)[off] = (bf16)v;
        else       ((float*)Cv)[off] = v;
      }
    }
  }
}

// ---------------- embed + rmsnorm -> bf16 h ----------------
__global__ __launch_bounds__(256) void k_embed(const float* __restrict__ x,
    const float* __restrict__ emb, const float* __restrict__ pos,
    const float* __restrict__ nw, bf16* __restrict__ h) {
  __shared__ float red[4];
  int row = blockIdx.x;
  int l = row % Lq;
  int xi = (int)(x[row] * 255.f);
  xi = min(max(xi, 0), 255);
  const float* er = emb + (long)xi * WIDTH;
  const float* pr = pos + (long)l * WIDTH;
  int c0 = threadIdx.x * 4;
  float v[4]; float ss = 0.f;
  #pragma unroll
  for (int i = 0; i < 4; i++) { v[i] = er[c0 + i] + pr[c0 + i]; ss += v[i] * v[i]; }
  ss = blockReduceSum256(ss, red);
  float r = rsqrtf(ss / WIDTH + EPS);
  bf16* hr = h + (long)row * WIDTH;
  #pragma unroll
  for (int i = 0; i < 4; i++) hr[c0 + i] = (bf16)(v[i] * r * nw[c0 + i]);
}

// ---------------- mean over L, phase 1 (partials into MP) ----------------
__global__ void k_meanl_p(const bf16* __restrict__ h, float* __restrict__ part) {
  int lp = blockIdx.x, b = blockIdx.y, t = threadIdx.x;
  const bf16* p = h + ((long)b * Lq + (long)lp * 72) * WIDTH + t * 4;
  float a0 = 0, a1 = 0, a2 = 0, a3 = 0;
  for (int l = 0; l < 72; l++) {
    bf16x4 v = *(const bf16x4*)(p + (long)l * WIDTH);
    a0 += (float)v[0]; a1 += (float)v[1]; a2 += (float)v[2]; a3 += (float)v[3];
  }
  float* dst = part + ((long)b * 8 + lp) * WIDTH + t * 4;
  dst[0] = a0; dst[1] = a1; dst[2] = a2; dst[3] = a3;
}

// ---------------- SE phase 1 (reads MP partials): t1 = silu(mean @ w1 + b1) ----------
__global__ __launch_bounds__(256) void k_se1(const float* __restrict__ part,
    const float* __restrict__ w1, const float* __restrict__ b1,
    float* __restrict__ t1) {
  __shared__ float sv[1024];
  __shared__ float red[256];
  int jb = blockIdx.x, b = blockIdx.y, t = threadIdx.x;
  for (int c = t; c < 1024; c += 256) {
    float a = 0.f;
    #pragma unroll
    for (int lp = 0; lp < 8; lp++) a += part[((long)b * 8 + lp) * 1024 + c];
    sv[c] = a * (1.f / 576.f);
  }
  __syncthreads();
  int j = t & 7, pt = t >> 3;
  int j0 = jb * 8;
  float acc = 0.f;
  int c0 = pt * 32;
  #pragma unroll 8
  for (int c = c0; c < c0 + 32; c++) acc += sv[c] * w1[c * 256 + j0 + j];
  red[t] = acc;
  __syncthreads();
  if (t < 8) {
    float a = b1[j0 + t];
    #pragma unroll
    for (int p = 0; p < 32; p++) a += red[p * 8 + t];
    t1[b * 256 + j0 + t] = silu(a);
  }
}

// ---------------- SE phase 2: s = sigmoid(t1 @ w2 + b2) ----------------
__global__ __launch_bounds__(256) void k_se2(const float* __restrict__ t1,
    const float* __restrict__ w2, const float* __restrict__ b2,
    float* __restrict__ s) {
  __shared__ float red[256];
  int jb = blockIdx.x, b = blockIdx.y, t = threadIdx.x;
  int j = t & 31, pt = t >> 5;
  int j0 = jb * 32;
  const float* tb = t1 + b * 256;
  float acc = 0.f;
  int c0 = pt * 32;
  #pragma unroll 8
  for (int c = c0; c < c0 + 32; c++) acc += tb[c] * w2[c * 1024 + j0 + j];
  red[t] = acc;
  __syncthreads();
  if (t < 32) {
    float a = b2[j0 + t];
    #pragma unroll
    for (int p = 0; p < 8; p++) a += red[p * 32 + t];
    s[b * 1024 + j0 + t] = 1.f / (1.f + __expf(-a));
  }
}

// ---------------- mix: h += rmsnorm(h*(s-1), mw)  (bf16 h) ----------------
__global__ __launch_bounds__(256) void k_mix_b(bf16* __restrict__ h,
    const float* __restrict__ s, const float* __restrict__ mw) {
  __shared__ float red[4];
  int row = blockIdx.x;
  int b = row / Lq;
  bf16* hr = h + (long)row * WIDTH;
  const float* sb = s + b * WIDTH;
  int c0 = threadIdx.x * 4;
  float hv[4], y[4]; float ss = 0.f;
  #pragma unroll
  for (int i = 0; i < 4; i++) {
    hv[i] = (float)hr[c0 + i];
    y[i] = hv[i] * (sb[c0 + i] - 1.f); ss += y[i] * y[i];
  }
  ss = blockReduceSum256(ss, red);
  float r = rsqrtf(ss / WIDTH + EPS);
  #pragma unroll
  for (int i = 0; i < 4; i++) hr[c0 + i] = (bf16)(hv[i] + y[i] * r * mw[c0 + i]);
}

// ---------------- h += rmsnorm(g, mw) (bf16) ----------------
__global__ __launch_bounds__(256) void k_addnorm_b(bf16* __restrict__ h,
    const bf16* __restrict__ g, const float* __restrict__ mw) {
  __shared__ float red[4];
  int row = blockIdx.x;
  bf16* hr = h + (long)row * WIDTH;
  const bf16* gr = g + (long)row * WIDTH;
  int c0 = threadIdx.x * 4;
  float y[4]; float ss = 0.f;
  #pragma unroll
  for (int i = 0; i < 4; i++) { y[i] = (float)gr[c0 + i]; ss += y[i] * y[i]; }
  ss = blockReduceSum256(ss, red);
  float r = rsqrtf(ss / WIDTH + EPS);
  #pragma unroll
  for (int i = 0; i < 4; i++)
    hr[c0 + i] = (bf16)((float)hr[c0 + i] + y[i] * r * mw[c0 + i]);
}

// ---------------- router + lambdas (reads MP partials), one block per b ------------
__global__ __launch_bounds__(256) void k_router(const float* __restrict__ part,
    const float* __restrict__ rwgt, const float* __restrict__ rb,
    const float* __restrict__ lq1, const float* __restrict__ lk1,
    const float* __restrict__ lq2, const float* __restrict__ lk2,
    float* __restrict__ rw, float* __restrict__ lam) {
  __shared__ float sv[1024];
  __shared__ float red[256];
  __shared__ float lg[8];
  int b = blockIdx.x, t = threadIdx.x;
  for (int c = t; c < 1024; c += 256) {
    float a = 0.f;
    #pragma unroll
    for (int lp = 0; lp < 8; lp++) a += part[((long)b * 8 + lp) * 1024 + c];
    sv[c] = a * (1.f / 576.f);
  }
  __syncthreads();
  int j = t & 7, pt = t >> 3;
  float acc = 0.f;
  int c0 = pt * 32;
  #pragma unroll 8
  for (int c = c0; c < c0 + 32; c++) acc += sv[c] * rwgt[c * 8 + j];
  red[t] = acc;
  __syncthreads();
  if (t < 8) {
    float a = rb[t];
    for (int p = 0; p < 32; p++) a += red[p * 8 + t];
    lg[t] = a;
  }
  __syncthreads();
  if (t == 0) {
    float v[8]; bool sel[8];
    #pragma unroll
    for (int i = 0; i < 8; i++) { v[i] = lg[i]; sel[i] = false; }
    int idxs[4]; float vals[4];
    for (int s = 0; s < 4; s++) {
      int bi = -1; float bv = -1e30f;
      for (int i = 0; i < 8; i++) if (!sel[i] && v[i] > bv) { bv = v[i]; bi = i; }
      sel[bi] = true; idxs[s] = bi; vals[s] = bv;
    }
    float m = vals[0], den = 0.f, e[4];
    for (int s = 0; s < 4; s++) { e[s] = __expf(vals[s] - m); den += e[s]; }
    for (int i = 0; i < 8; i++) rw[b * 8 + i] = 0.f;
    for (int s = 0; s < 4; s++) rw[b * 8 + idxs[s]] = e[s] / den;
  }
  if (b == 0 && t >= 8 && t < 16) {
    int c = t - 8;
    float d1 = 0.f, d2 = 0.f;
    for (int i = 0; i < 8; i++) {
      d1 += lq1[c * 8 + i] * lk1[c * 8 + i];
      d2 += lq2[c * 8 + i] * lk2[c * 8 + i];
    }
    lam[c] = __expf(d1) - __expf(d2) + LAMINIT;
  }
}

// ---------------- MFMA causal differential attention, S^T formulation -------------
// grid (slice=64, prhalf=2, head=8): same-slice blocks share linear_id%8 -> same XCD L2.
// S^T = K·Q^T (halves via quad-predicated Q B-frags); P^T C-layout == 16x16x16 B-operand
// -> PV (O^T = V^T·P^T) straight from registers, no LDS P round-trip.
// Q/K rmsnorm fused (K once in LDS post-staging; Q in-register per tile).
// LDS: Ks 18432 + Vt 18688 = 37120 B -> 4 blocks/CU; grid 1024 = exactly 4/CU.
__global__ __launch_bounds__(256) void k_attn_mfma(
    const bf16* __restrict__ qkv, const float* __restrict__ lam,
    const float* __restrict__ hnw, const float* __restrict__ qn,
    const float* __restrict__ kn, bf16* __restrict__ dc) {
  __shared__ bf16 Ks[576 * 16];
  __shared__ bf16 Vt[16 * 584];
  int tid = threadIdx.x;
  int slice = blockIdx.x; int zc = slice >> 3, b = slice & 7;
  int head = blockIdx.z;
  const bf16* qkvb = qkv + ((long)zc * ROWS + (long)b * Lq) * 384;
  for (int i = tid; i < 1152; i += 256) {
    int row = i >> 1, hf = i & 1;
    gl16(qkvb + (long)row * 384 + 128 + head * 16 + hf * 8, Ks + i * 8);
  }
  for (int i = tid; i < 1152; i += 256) {
    int row = i >> 1, dh = i & 1;
    bf16x8 v = *(const bf16x8*)(qkvb + (long)row * 384 + 256 + head * 16 + dh * 8);
    #pragma unroll
    for (int j = 0; j < 8; j++) Vt[(dh * 8 + j) * 584 + row] = v[j];
  }
  __syncthreads();
  // K rmsnorm in LDS (per 8-elem half)
  {
    float kw[8];
    #pragma unroll
    for (int j = 0; j < 8; j++) kw[j] = kn[zc * 8 + j];
    for (int i = tid; i < 1152; i += 256) {
      bf16x8 kv = *(const bf16x8*)(Ks + i * 8);
      float f[8], s = 0.f;
      #pragma unroll
      for (int j = 0; j < 8; j++) { f[j] = (float)kv[j]; s += f[j] * f[j]; }
      float r = rsqrtf(s * 0.125f + EPS);
      bf16x8 o;
      #pragma unroll
      for (int j = 0; j < 8; j++) o[j] = (bf16)(f[j] * r * kw[j]);
      *(bf16x8*)(Ks + i * 8) = o;
    }
  }
  __syncthreads();
  int wv = tid >> 6, lane = tid & 63;
  int lm = lane & 15, lq = lane >> 4;
  float lamv = lam[zc];
  float hwv[4];
  #pragma unroll
  for (int r = 0; r < 4; r++) hwv[r] = hnw[zc * 16 + lq * 4 + r] * (1.f - LAMINIT);
  float qw[8];
  #pragma unroll
  for (int j = 0; j < 8; j++) qw[j] = qn[zc * 8 + j];
  for (int pr = blockIdx.y * 4 + wv; pr < 18; pr += 8) {
    // Q B-frags (normed + pre-scaled in-register); bq0 live on quad0, bq1 on quad1
    bf16x8 bq0[2] = {{}, {}}, bq1[2] = {{}, {}};
    if (lq < 2) {
      #pragma unroll
      for (int tile = 0; tile < 2; tile++) {
        bf16x8 t8 = *(const bf16x8*)(
            qkvb + (long)(pr * 32 + tile * 16 + lm) * 384 + head * 16 + lq * 8);
        float f[8], s = 0.f;
        #pragma unroll
        for (int j = 0; j < 8; j++) { f[j] = (float)t8[j]; s += f[j] * f[j]; }
        float r = rsqrtf(s * 0.125f + EPS) * QSCALE;
        bf16x8 n;
        #pragma unroll
        for (int j = 0; j < 8; j++) n[j] = (bf16)(f[j] * r * qw[j]);
        if (lq == 0) bq0[tile] = n; else bq1[tile] = n;
      }
    }
    f32x4 o[2][2] = {};
    float den[2][2] = {};
    for (int kc = 0; kc <= pr; kc++) {
      f32x4 sT[2][2][2] = {};   // [t][tile][half]; C-tile: col=q, row=k=lq*4+r
      #pragma unroll
      for (int t = 0; t < 2; t++) {
        bf16x8 aK = {};
        if (lq < 2) aK = *(const bf16x8*)(Ks + (kc * 32 + t * 16 + lm) * 16 + lq * 8);
        #pragma unroll
        for (int tile = 0; tile < 2; tile++) {
          sT[t][tile][0] = __builtin_amdgcn_mfma_f32_16x16x32_bf16(aK, bq0[tile], sT[t][tile][0], 0, 0, 0);
          sT[t][tile][1] = __builtin_amdgcn_mfma_f32_16x16x32_bf16(aK, bq1[tile], sT[t][tile][1], 0, 0, 0);
        }
      }
      bool diag = (kc == pr);
      #pragma unroll
      for (int t = 0; t < 2; t++) {
        bf16x4 aV = *(const bf16x4*)(Vt + lm * 584 + kc * 32 + t * 16 + lq * 4);
        #pragma unroll
        for (int tile = 0; tile < 2; tile++) {
          if (diag && tile == 0 && t == 1) continue;      // fully masked sub-chunk
          bool masked = diag && (tile == t);              // triangular sub-chunk
          #pragma unroll
          for (int h2 = 0; h2 < 2; h2++) {
            bf16x4 pb;
            float dsum = 0.f;
            #pragma unroll
            for (int r = 0; r < 4; r++) {
              float ev = __expf(sT[t][tile][h2][r]);
              if (masked && (lq * 4 + r > lm)) ev = 0.f;
              dsum += ev;
              pb[r] = (bf16)ev;
            }
            den[tile][h2] += dsum;
            o[tile][h2] = mfma16(aV, pb, o[tile][h2]);    // O^T += V^T · P^T
          }
        }
      }
    }
    #pragma unroll
    for (int tile = 0; tile < 2; tile++)
      #pragma unroll
      for (int h2 = 0; h2 < 2; h2++) {
        den[tile][h2] += __shfl_xor(den[tile][h2], 16);
        den[tile][h2] += __shfl_xor(den[tile][h2], 32);
      }
    #pragma unroll
    for (int tile = 0; tile < 2; tile++) {
      float inv1 = 1.f / den[tile][0];
      float inv2 = lamv / den[tile][1];
      float dff[4]; float ss = 0.f;
      #pragma unroll
      for (int r = 0; r < 4; r++) {
        dff[r] = o[tile][0][r] * inv1 - o[tile][1][r] * inv2;
        ss += dff[r] * dff[r];
      }
      ss += __shfl_xor(ss, 16);
      ss += __shfl_xor(ss, 32);
      float rr = rsqrtf(ss * 0.0625f + EPS);
      bf16x4 outp;
      #pragma unroll
      for (int r = 0; r < 4; r++) outp[r] = (bf16)(dff[r] * rr * hwv[r]);
      long rowg = (long)zc * ROWS + (long)b * Lq + pr * 32 + tile * 16 + lm;
      *(bf16x4*)(dc + rowg * 128 + head * 16 + lq * 4) = outp;
    }
  }
}

// ---------------- seg + pool fused: partials of (h_ch + rmsnorm(op))*rw ----------
// grid (lp=8, b=8, ch=8), 64 threads; per-row reduce via wave shuffles only.
__global__ __launch_bounds__(64) void k_segpool(const bf16* __restrict__ h,
    const bf16* __restrict__ op, const float* __restrict__ segw,
    const float* __restrict__ rw, float* __restrict__ part) {
  int lp = blockIdx.x, b = blockIdx.y, ch = blockIdx.z;
  int t = threadIdx.x;
  int c0 = t * 2;
  float w0 = segw[ch * 128 + c0], w1 = segw[ch * 128 + c0 + 1];
  float rwv = rw[b * 8 + ch];
  float a0 = 0.f, a1 = 0.f;
  for (int l = 0; l < 72; l++) {
    int row = b * Lq + lp * 72 + l;
    const bf16* oprow = op + (long)ch * ROWS * CW + (long)row * CW;
    bf16x2 yv = *(const bf16x2*)(oprow + c0);
    float y0 = (float)yv[0], y1 = (float)yv[1];
    float ss = y0 * y0 + y1 * y1;
    #pragma unroll
    for (int m = 1; m < 64; m <<= 1) ss += __shfl_xor(ss, m);
    float r = rsqrtf(ss * (1.f / 128.f) + EPS);
    bf16x2 hv = *(const bf16x2*)(h + (long)row * WIDTH + ch * 128 + c0);
    a0 += ((float)hv[0] + y0 * r * w0) * rwv;
    a1 += ((float)hv[1] + y1 * r * w1) * rwv;
  }
  float* dst = part + ((long)b * 8 + lp) * 1024 + ch * 128 + c0;
  dst[0] = a0; dst[1] = a1;
}

// ---------------- head (reads pool partials): out = pooled @ hw + hb --------------
__global__ __launch_bounds__(256) void k_head(const float* __restrict__ part,
    const float* __restrict__ hw, const float* __restrict__ hb, float* __restrict__ out) {
  __shared__ float pool[1024];
  __shared__ float red[256];
  int b = blockIdx.x, t = threadIdx.x;
  for (int c = t; c < 1024; c += 256) {
    float a = 0.f;
    #pragma unroll
    for (int lp = 0; lp < 8; lp++) a += part[((long)b * 8 + lp) * 1024 + c];
    pool[c] = a * (1.f / 576.f);
  }
  __syncthreads();
  int j = t & 15, pt = t >> 4;
  float acc = 0.f;
  if (j < 10)
    for (int c = pt * 64; c < pt * 64 + 64; c++)
      acc += pool[c] * hw[c * 10 + j];
  red[t] = acc;
  __syncthreads();
  if (t < 10) {
    float a = hb[t];
    for (int p = 0; p < 16; p++) a += red[p * 16 + t];
    out[b * 10 + t] = a;
  }
}

// ---------------- launcher ----------------
extern "C" void kernel_launch(void* const* d_in, const int* in_sizes, int n_in,
                              void* d_out, int out_size, void* d_ws, size_t ws_size,
                              hipStream_t stream) {
  const float* x          = (const float*)d_in[0];
  const float* pixel_embed= (const float*)d_in[2];
  const float* freq_h     = (const float*)d_in[3];
  const float* freq_w     = (const float*)d_in[4];
  const float* phase_h    = (const float*)d_in[5];
  const float* phase_w    = (const float*)d_in[6];
  const float* pos_proj_w = (const float*)d_in[7];
  const float* pos_proj_b = (const float*)d_in[8];
  const float* embed_norm = (const float*)d_in[9];
  const float* se_w1      = (const float*)d_in[10];
  const float* se_b1      = (const float*)d_in[11];
  const float* se_w2      = (const float*)d_in[12];
  const float* se_b2      = (const float*)d_in[13];
  const float* mix_norm   = (const float*)d_in[14];
  const float* mlp_w1     = (const float*)d_in[15];
  const float* mlp_b1     = (const float*)d_in[16];
  const float* mlp_w2     = (const float*)d_in[17];
  const float* mlp_b2     = (const float*)d_in[18];
  const float* mlp_norm   = (const float*)d_in[19];
  const float* router_w   = (const float*)d_in[20];
  const float* router_b   = (const float*)d_in[21];
  const float* qkv_w      = (const float*)d_in[22];
  const float* qkv_b      = (const float*)d_in[23];
  const float* q_norm_w   = (const float*)d_in[24];
  const float* k_norm_w   = (const float*)d_in[25];
  const float* head_norm_w= (const float*)d_in[26];
  const float* lam_q1     = (const float*)d_in[27];
  const float* lam_k1     = (const float*)d_in[28];
  const float* lam_q2     = (const float*)d_in[29];
  const float* lam_k2     = (const float*)d_in[30];
  const float* out_w      = (const float*)d_in[31];
  const float* out_b      = (const float*)d_in[32];
  const float* seg_norm_w = (const float*)d_in[33];
  const float* head_w     = (const float*)d_in[34];
  const float* head_b     = (const float*)d_in[35];

  char* W = (char*)d_ws;
  bf16*  HB    = (bf16*)(W + B_HB);
  bf16*  G2B   = (bf16*)(W + B_G2B);
  bf16*  ENCB  = (bf16*)(W + B_ENCB);
  bf16*  POSWT = (bf16*)(W + B_POSWT);
  bf16*  QKVWT = (bf16*)(W + B_QKVWT);
  bf16*  OWT   = (bf16*)(W + B_OWT);
  float* SE    = (float*)(W + B_SE);
  float* T1    = (float*)(W + B_T1);
  float* MP    = (float*)(W + B_MP);
  float* RW    = (float*)(W + B_RW);
  float* LAM   = (float*)(W + B_LAM);
  char*  P     = W + B_POOL;
  float* POS   = (float*)P;
  bf16*  W1T   = (bf16*)P;
  bf16*  W2T   = (bf16*)(P + 8388608);
  bf16*  HID   = (bf16*)(P + 16777216);
  bf16*  QKV   = (bf16*)P;
  bf16*  DC    = (bf16*)(P + 28311552);
  float* out   = (float*)d_out;

  // 1. positional encoding -> bf16, weight cast, gemm -> POS (f32)
  k_enc_b<<<288, 256, 0, stream>>>(freq_h, freq_w, phase_h, phase_w, ENCB);
  k_tcast<<<dim3(32, 4, 1), 256, 0, stream>>>(pos_proj_w, POSWT, 128, 1024);
  gemm64<0, 0, 0><<<dim3(8, 10, 1), 256, 0, stream>>>(
      ENCB, 128, 0, POSWT, 128, 0, pos_proj_b, 0, POS, 1024, 0, 640, 1024, 128);
  // 2. embed + rmsnorm -> bf16 h
  k_embed<<<ROWS, 256, 0, stream>>>(x, pixel_embed, POS, embed_norm, HB);
  // 3. SE gate (meanl_r folded into se1)
  k_meanl_p<<<dim3(8, 8), 256, 0, stream>>>(HB, MP);
  k_se1<<<dim3(32, 8), 256, 0, stream>>>(MP, se_w1, se_b1, T1);
  k_se2<<<dim3(32, 8), 256, 0, stream>>>(T1, se_w2, se_b2, SE);
  k_mix_b<<<ROWS, 256, 0, stream>>>(HB, SE, mix_norm);
  // 4. MLP: split along hidden dim (2 halves of 2048), bf16 MFMA
  k_tcast<<<dim3(128, 32, 1), 256, 0, stream>>>(mlp_w1, W1T, 1024, 4096);
  k_tcast<<<dim3(32, 128, 1), 256, 0, stream>>>(mlp_w2, W2T, 4096, 1024);
  gemm_bt<1, 1><<<dim3(16, 36, 1), 256, 0, stream>>>(
      HB, 1024, 0, W1T, 0, mlp_b1, 0, HID, 2048, 0, 4608, 2048, 1024);
  gemm64<0, 1, 0><<<dim3(8, 72, 1), 256, 0, stream>>>(
      HID, 2048, 0, W2T, 4096, 0, mlp_b2, 0, G2B, 1024, 0, 4608, 1024, 2048);
  gemm_bt<1, 1><<<dim3(16, 36, 1), 256, 0, stream>>>(
      HB, 1024, 0, W1T + 2048L * 1024, 0, mlp_b1 + 2048, 0, HID, 2048, 0, 4608, 2048, 1024);
  gemm64<0, 1, 1><<<dim3(8, 72, 1), 256, 0, stream>>>(
      HID, 2048, 0, W2T + 2048, 4096, 0, nullptr, 0, G2B, 1024, 0, 4608, 1024, 2048);
  k_addnorm_b<<<ROWS, 256, 0, stream>>>(HB, G2B, mlp_norm);
  // 5. router + lambdas (meanl_r folded into router)
  k_meanl_p<<<dim3(8, 8), 256, 0, stream>>>(HB, MP);
  k_router<<<8, 256, 0, stream>>>(MP, router_w, router_b,
                                  lam_q1, lam_k1, lam_q2, lam_k2, RW, LAM);
  // 6. channel weights cast
  k_tcast<<<dim3(12, 4, 8), 256, 0, stream>>>(qkv_w, QKVWT, 128, 384);
  k_tcast<<<dim3(4, 4, 8), 256, 0, stream>>>(out_w, OWT, 128, 128);
  // 7. all 8 channels: qkv-proj, fused attention (q/k-norm inside), out-proj in-place
  gemm64<1, 1, 0><<<dim3(3, 72, 8), 256, 0, stream>>>(
      HB, 1024, CW, QKVWT, 128, 384 * 128, qkv_b, 384,
      QKV, 384, (long)ROWS * 384, ROWS, 384, 128);
  k_attn_mfma<<<dim3(64, 2, 8), 256, 0, stream>>>(
      QKV, LAM, head_norm_w, q_norm_w, k_norm_w, DC);
  gemm64<1, 1, 0><<<dim3(1, 72, 8), 256, 0, stream>>>(
      DC, 128, (long)ROWS * 128, OWT, 128, 128 * 128, out_b, 128,
      DC, 128, (long)ROWS * 128, ROWS, 128, 128);
  // 8. seg + pool fused -> partials; head folds the final reduce
  k_segpool<<<dim3(8, 8, 8), 64, 0, stream>>>(HB, DC, seg_norm_w, RW, MP);
  k_head<<<8, 256, 0, stream>>>(MP, head_w, head_b, out);
}

// Round 7
// 500.730 us; speedup vs baseline: 5.8082x; 1.0049x over previous
//
#include <hip/hip_runtime.h>
#include <math.h>

typedef __bf16 bf16;
typedef __bf16 bf16x8 __attribute__((ext_vector_type(8)));
typedef __bf16 bf16x4 __attribute__((ext_vector_type(4)));
typedef __bf16 bf16x2 __attribute__((ext_vector_type(2)));
typedef float f32x4 __attribute__((ext_vector_type(4)));
typedef short s16x4 __attribute__((ext_vector_type(4)));

// ---------------- constants ----------------
constexpr int Bsz = 8, HIMG = 24, WIMG = 24;
constexpr int Lq = 576;
constexpr int WIDTH = 1024, NCH = 8, CW = 128;
constexpr int NHEADS = 8, HD = 16, HALF = 8;
constexpr float EPS = 1e-6f;
constexpr float LAMINIT = 0.2f;
// 1/sqrt(8) * log2(e): scores come out of MFMA in log2 domain -> v_exp_f32 directly
constexpr float QSCALE_E = 0.35355339059327373f * 1.4426950408889634f;
constexpr int ROWS = Bsz * Lq;              // 4608

__device__ __forceinline__ float fexp2(float x) {
#if __has_builtin(__builtin_amdgcn_exp2f)
  return __builtin_amdgcn_exp2f(x);
#else
  return exp2f(x);
#endif
}

// ---------------- workspace byte offsets ----------------
constexpr size_t B_HB    = 0;                        // bf16 h [4608][1024]
constexpr size_t B_G2B   = B_HB    + 9437184;        // bf16 g2 [4608][1024] (MLP out)
constexpr size_t B_ENCB  = B_G2B   + 9437184;        // bf16 enc [640][128]
constexpr size_t B_POSWT = B_ENCB  + 163840;         // bf16 [1024][128]
constexpr size_t B_QKVWT = B_POSWT + 262144;         // bf16 [8][384][128]
constexpr size_t B_OWT   = B_QKVWT + 786432;         // bf16 [8][128][128]
constexpr size_t B_SE    = B_OWT   + 262144;         // f32 [8][1024]
constexpr size_t B_T1    = B_SE    + 32768;          // f32 [8][256] SE hidden
constexpr size_t B_MP    = B_T1    + 8192;           // f32 [8][16][1024] pool partials
constexpr size_t B_RW    = B_MP    + 524288;         // f32 [64]
constexpr size_t B_LAM   = B_RW    + 256;            // f32 [8]
constexpr size_t B_POOL  = B_LAM   + 256;            // phase-shared pool
// pool (pos phase):  POS f32 [640][1024] = 2621440
// pool (MLP phase):  W1T 8388608 | W2T 8388608 | HID bf16 [4608][2048] 18874368 = 35651584
// pool (chan phase): QKV (8ch) 28311552 | DC 9437184 (out-proj IN-PLACE on DC)
// high water: B_POOL + 37748736 ~= 58.7 MB (< 59.4 MB proven in R1)

// ---------------- helpers ----------------
__device__ __forceinline__ float blockReduceSum256(float v, float* red) {
  #pragma unroll
  for (int off = 32; off; off >>= 1) v += __shfl_down(v, off, 64);
  int lane = threadIdx.x & 63, wid = threadIdx.x >> 6;
  if (lane == 0) red[wid] = v;
  __syncthreads();
  float total = 0.f;
  #pragma unroll
  for (int i = 0; i < 4; i++) total += red[i];
  return total;
}
__device__ __forceinline__ float silu(float x) { return x / (1.f + __expf(-x)); }

__device__ __forceinline__ void gl16(const bf16* g, bf16* l) {
  __builtin_amdgcn_global_load_lds(
      (const __attribute__((address_space(1))) void*)g,
      (__attribute__((address_space(3))) void*)l, 16, 0, 0);
}

// v_mfma_f32_16x16x16_bf16 wrapper (A,B = 4 bf16/lane; k = quad*4+j)
__device__ __forceinline__ f32x4 mfma16(bf16x4 a, bf16x4 b, f32x4 c) {
#if __has_builtin(__builtin_amdgcn_mfma_f32_16x16x16bf16_1k)
  union { bf16x4 h; s16x4 s; } ua, ub;
  ua.h = a; ub.h = b;
  return __builtin_amdgcn_mfma_f32_16x16x16bf16_1k(ua.s, ub.s, c, 0, 0, 0);
#else
  f32x4 d = c;
  asm volatile("v_mfma_f32_16x16x16_bf16 %0, %1, %2, %0"
               : "+v"(d) : "v"(a), "v"(b));
  return d;
#endif
}

// ---------------- cast+transpose: W fp32 [K][N] -> Wt bf16 [N][K] ----------------
__global__ __launch_bounds__(256) void k_tcast(const float* __restrict__ W,
    bf16* __restrict__ Wt, int K, int N) {
  __shared__ float t[32][33];
  int n0 = blockIdx.x * 32, k0 = blockIdx.y * 32;
  long zo = (long)blockIdx.z * K * N;
  int tid = threadIdx.x;
  int r = tid >> 3, c4 = (tid & 7) * 4;
  const float4 v = *(const float4*)(W + zo + (long)(k0 + r) * N + n0 + c4);
  t[c4 + 0][r] = v.x; t[c4 + 1][r] = v.y; t[c4 + 2][r] = v.z; t[c4 + 3][r] = v.w;
  __syncthreads();
  bf16* dst = Wt + zo + (long)(n0 + r) * K + k0 + c4;
  dst[0] = (bf16)t[r][c4 + 0]; dst[1] = (bf16)t[r][c4 + 1];
  dst[2] = (bf16)t[r][c4 + 2]; dst[3] = (bf16)t[r][c4 + 3];
}

// ---------------- positional encoding (bf16 out) ----------------
__global__ void k_enc_b(const float* __restrict__ fh, const float* __restrict__ fw,
                        const float* __restrict__ ph, const float* __restrict__ pw,
                        bf16* __restrict__ enc) {
  int idx = blockIdx.x * blockDim.x + threadIdx.x;
  if (idx >= Lq * 128) return;
  int l = idx >> 7, c = idx & 127;
  int hh = l / WIMG, ww = l % WIMG;
  float v;
  if (c < 64) {
    int f = c & 31;
    float fr = log1pf(__expf(fh[f])) * 10.f;
    float a = (hh / (float)HIMG) * fr + ph[f];
    v = (c < 32) ? sinf(a) : cosf(a);
  } else {
    int f = c & 31;
    float fr = log1pf(__expf(fw[f])) * 10.f;
    float a = (ww / (float)WIMG) * fr + pw[f];
    v = (c < 96) ? sinf(a) : cosf(a);
  }
  enc[idx] = (bf16)v;
}

// ---------------- bf16 MFMA GEMM 128x128 ----------------
template <int ACT, int OUTBF>
__global__ __launch_bounds__(256) void gemm_bt(
    const bf16* __restrict__ A, int lda, long aZs,
    const bf16* __restrict__ Bt, long bZs,
    const float* __restrict__ bias, int biasZs,
    void* __restrict__ Cv, int ldc, long cZs,
    int M, int N, int K) {
  __shared__ bf16 As[128 * 32];
  __shared__ bf16 Bs[128 * 32];
  int tid = threadIdx.x;
  int m0 = blockIdx.y * 128, n0 = blockIdx.x * 128;
  int z = blockIdx.z;
  const bf16* Ab = A + (long)z * aZs;
  const bf16* Bb = Bt + (long)z * bZs;
  f32x4 acc[4][4] = {};
  int wv = tid >> 6, lane = tid & 63;
  int wrow = (wv >> 1) * 64, wcol = (wv & 1) * 64;
  int lm = lane & 15, lq = lane >> 4;
  const bf16* ag = Ab + (long)(m0 + (tid >> 2)) * lda + (tid & 3) * 8;
  const bf16* bg = Bb + (long)(n0 + (tid >> 2)) * K + (tid & 3) * 8;
  bf16* asd = As + tid * 8;
  bf16* bsd = Bs + tid * 8;
  for (int k0 = 0; k0 < K; k0 += 32) {
    gl16(ag + k0, asd);
    gl16(ag + k0 + 64L * lda, asd + 2048);
    gl16(bg + k0, bsd);
    gl16(bg + k0 + 64L * K, bsd + 2048);
    __syncthreads();
    bf16x8 af[4], bfr[4];
    #pragma unroll
    for (int i = 0; i < 4; i++) {
      af[i]  = *(const bf16x8*)(As + (wrow + i * 16 + lm) * 32 + lq * 8);
      bfr[i] = *(const bf16x8*)(Bs + (wcol + i * 16 + lm) * 32 + lq * 8);
    }
    #pragma unroll
    for (int i = 0; i < 4; i++)
      #pragma unroll
      for (int j = 0; j < 4; j++)
        acc[i][j] = __builtin_amdgcn_mfma_f32_16x16x32_bf16(af[i], bfr[j], acc[i][j], 0, 0, 0);
    __syncthreads();
  }
  long cz = (long)z * cZs;
  const float* bz = bias ? bias + (long)z * biasZs : nullptr;
  #pragma unroll
  for (int i = 0; i < 4; i++) {
    int row = m0 + wrow + i * 16 + lq * 4;
    #pragma unroll
    for (int j = 0; j < 4; j++) {
      int col = n0 + wcol + j * 16 + lm;
      float bv = bz ? bz[col] : 0.f;
      #pragma unroll
      for (int r = 0; r < 4; r++) {
        float v = acc[i][j][r] + bv;
        if (ACT == 1) v = silu(v);
        long off = cz + (long)(row + r) * ldc + col;
        if (OUTBF) ((bf16*)Cv)[off] = (bf16)v;
        else       ((float*)Cv)[off] = v;
      }
    }
  }
}

// ---------------- bf16 MFMA GEMM 64x128 tile ----------------
template <int ACT, int OUTBF, int ACC>
__global__ __launch_bounds__(256) void gemm64(
    const bf16* __restrict__ A, int lda, long aZs,
    const bf16* __restrict__ Bt, int ldb, long bZs,
    const float* __restrict__ bias, int biasZs,
    void* __restrict__ Cv, int ldc, long cZs,
    int M, int N, int K) {
  __shared__ bf16 As[64 * 32];
  __shared__ bf16 Bs[128 * 32];
  int tid = threadIdx.x;
  int m0 = blockIdx.y * 64, n0 = blockIdx.x * 128;
  int z = blockIdx.z;
  const bf16* Ab = A + (long)z * aZs;
  const bf16* Bb = Bt + (long)z * bZs;
  f32x4 acc[4][2] = {};
  int wv = tid >> 6, lane = tid & 63;
  int lm = lane & 15, lq = lane >> 4;
  int wcol = wv * 32;
  const bf16* ag = Ab + (long)(m0 + (tid >> 2)) * lda + (tid & 3) * 8;
  const bf16* bg = Bb + (long)(n0 + (tid >> 2)) * ldb + (tid & 3) * 8;
  bf16* asd = As + tid * 8;
  bf16* bsd = Bs + tid * 8;
  for (int k0 = 0; k0 < K; k0 += 32) {
    if (tid < 256) gl16(ag + k0, asd);
    gl16(bg + k0, bsd);
    gl16(bg + k0 + 64L * ldb, bsd + 2048);
    __syncthreads();
    bf16x8 af[4], bfr[2];
    #pragma unroll
    for (int i = 0; i < 4; i++)
      af[i] = *(const bf16x8*)(As + (i * 16 + lm) * 32 + lq * 8);
    #pragma unroll
    for (int j = 0; j < 2; j++)
      bfr[j] = *(const bf16x8*)(Bs + (wcol + j * 16 + lm) * 32 + lq * 8);
    #pragma unroll
    for (int i = 0; i < 4; i++)
      #pragma unroll
      for (int j = 0; j < 2; j++)
        acc[i][j] = __builtin_amdgcn_mfma_f32_16x16x32_bf16(af[i], bfr[j], acc[i][j], 0, 0, 0);
    __syncthreads();
  }
  long cz = (long)z * cZs;
  const float* bz = bias ? bias + (long)z * biasZs : nullptr;
  #pragma unroll
  for (int i = 0; i < 4; i++) {
    int row = m0 + i * 16 + lq * 4;
    #pragma unroll
    for (int j = 0; j < 2; j++) {
      int col = n0 + wcol + j * 16 + lm;
      float bv = bz ? bz[col] : 0.f;
      #pragma unroll
      for (int r = 0; r < 4; r++) {
        float v = acc[i][j][r] + bv;
        long off = cz + (long)(row + r) * ldc + col;
        if (ACC) v += (float)((bf16*)Cv)[off];
        if (ACT == 1) v = silu(v);
        if (OUTBF) ((bf16*)Cv)[off] = (bf16)v;
        else       ((float*)Cv)[off] = v;
      }
    }
  }
}

// ---------------- embed + rmsnorm -> bf16 h ----------------
__global__ __launch_bounds__(256) void k_embed(const float* __restrict__ x,
    const float* __restrict__ emb, const float* __restrict__ pos,
    const float* __restrict__ nw, bf16* __restrict__ h) {
  __shared__ float red[4];
  int row = blockIdx.x;
  int l = row % Lq;
  int xi = (int)(x[row] * 255.f);
  xi = min(max(xi, 0), 255);
  const float* er = emb + (long)xi * WIDTH;
  const float* pr = pos + (long)l * WIDTH;
  int c0 = threadIdx.x * 4;
  float v[4]; float ss = 0.f;
  #pragma unroll
  for (int i = 0; i < 4; i++) { v[i] = er[c0 + i] + pr[c0 + i]; ss += v[i] * v[i]; }
  ss = blockReduceSum256(ss, red);
  float r = rsqrtf(ss / WIDTH + EPS);
  bf16* hr = h + (long)row * WIDTH;
  #pragma unroll
  for (int i = 0; i < 4; i++) hr[c0 + i] = (bf16)(v[i] * r * nw[c0 + i]);
}

// ---------------- mean over L, phase 1: 16 partials per b -> MP[b][16][1024] --------
__global__ void k_meanl_p(const bf16* __restrict__ h, float* __restrict__ part) {
  int lp = blockIdx.x, b = blockIdx.y, t = threadIdx.x;
  const bf16* p = h + ((long)b * Lq + (long)lp * 36) * WIDTH + t * 4;
  float a0 = 0, a1 = 0, a2 = 0, a3 = 0;
  for (int l = 0; l < 36; l++) {
    bf16x4 v = *(const bf16x4*)(p + (long)l * WIDTH);
    a0 += (float)v[0]; a1 += (float)v[1]; a2 += (float)v[2]; a3 += (float)v[3];
  }
  float* dst = part + ((long)b * 16 + lp) * WIDTH + t * 4;
  dst[0] = a0; dst[1] = a1; dst[2] = a2; dst[3] = a3;
}

// ---------------- SE phase 1 (reads 16 MP partials): t1 = silu(mean @ w1 + b1) ------
__global__ __launch_bounds__(256) void k_se1(const float* __restrict__ part,
    const float* __restrict__ w1, const float* __restrict__ b1,
    float* __restrict__ t1) {
  __shared__ float sv[1024];
  __shared__ float red[256];
  int jb = blockIdx.x, b = blockIdx.y, t = threadIdx.x;
  for (int c = t; c < 1024; c += 256) {
    float a = 0.f;
    #pragma unroll
    for (int lp = 0; lp < 16; lp++) a += part[((long)b * 16 + lp) * 1024 + c];
    sv[c] = a * (1.f / 576.f);
  }
  __syncthreads();
  int j = t & 7, pt = t >> 3;
  int j0 = jb * 8;
  float acc = 0.f;
  int c0 = pt * 32;
  #pragma unroll 8
  for (int c = c0; c < c0 + 32; c++) acc += sv[c] * w1[c * 256 + j0 + j];
  red[t] = acc;
  __syncthreads();
  if (t < 8) {
    float a = b1[j0 + t];
    #pragma unroll
    for (int p = 0; p < 32; p++) a += red[p * 8 + t];
    t1[b * 256 + j0 + t] = silu(a);
  }
}

// ---------------- SE phase 2: s = sigmoid(t1 @ w2 + b2) ----------------
__global__ __launch_bounds__(256) void k_se2(const float* __restrict__ t1,
    const float* __restrict__ w2, const float* __restrict__ b2,
    float* __restrict__ s) {
  __shared__ float red[256];
  int jb = blockIdx.x, b = blockIdx.y, t = threadIdx.x;
  int j = t & 31, pt = t >> 5;
  int j0 = jb * 32;
  const float* tb = t1 + b * 256;
  float acc = 0.f;
  int c0 = pt * 32;
  #pragma unroll 8
  for (int c = c0; c < c0 + 32; c++) acc += tb[c] * w2[c * 1024 + j0 + j];
  red[t] = acc;
  __syncthreads();
  if (t < 32) {
    float a = b2[j0 + t];
    #pragma unroll
    for (int p = 0; p < 8; p++) a += red[p * 32 + t];
    s[b * 1024 + j0 + t] = 1.f / (1.f + __expf(-a));
  }
}

// ---------------- mix: h += rmsnorm(h*(s-1), mw)  (bf16 h) ----------------
__global__ __launch_bounds__(256) void k_mix_b(bf16* __restrict__ h,
    const float* __restrict__ s, const float* __restrict__ mw) {
  __shared__ float red[4];
  int row = blockIdx.x;
  int b = row / Lq;
  bf16* hr = h + (long)row * WIDTH;
  const float* sb = s + b * WIDTH;
  int c0 = threadIdx.x * 4;
  float hv[4], y[4]; float ss = 0.f;
  #pragma unroll
  for (int i = 0; i < 4; i++) {
    hv[i] = (float)hr[c0 + i];
    y[i] = hv[i] * (sb[c0 + i] - 1.f); ss += y[i] * y[i];
  }
  ss = blockReduceSum256(ss, red);
  float r = rsqrtf(ss / WIDTH + EPS);
  #pragma unroll
  for (int i = 0; i < 4; i++) hr[c0 + i] = (bf16)(hv[i] + y[i] * r * mw[c0 + i]);
}

// ---------------- h += rmsnorm(g, mw) (bf16) ----------------
__global__ __launch_bounds__(256) void k_addnorm_b(bf16* __restrict__ h,
    const bf16* __restrict__ g, const float* __restrict__ mw) {
  __shared__ float red[4];
  int row = blockIdx.x;
  bf16* hr = h + (long)row * WIDTH;
  const bf16* gr = g + (long)row * WIDTH;
  int c0 = threadIdx.x * 4;
  float y[4]; float ss = 0.f;
  #pragma unroll
  for (int i = 0; i < 4; i++) { y[i] = (float)gr[c0 + i]; ss += y[i] * y[i]; }
  ss = blockReduceSum256(ss, red);
  float r = rsqrtf(ss / WIDTH + EPS);
  #pragma unroll
  for (int i = 0; i < 4; i++)
    hr[c0 + i] = (bf16)((float)hr[c0 + i] + y[i] * r * mw[c0 + i]);
}

// ---------------- router + lambdas (reads 16 MP partials), one block per b ---------
__global__ __launch_bounds__(256) void k_router(const float* __restrict__ part,
    const float* __restrict__ rwgt, const float* __restrict__ rb,
    const float* __restrict__ lq1, const float* __restrict__ lk1,
    const float* __restrict__ lq2, const float* __restrict__ lk2,
    float* __restrict__ rw, float* __restrict__ lam) {
  __shared__ float sv[1024];
  __shared__ float red[256];
  __shared__ float lg[8];
  int b = blockIdx.x, t = threadIdx.x;
  for (int c = t; c < 1024; c += 256) {
    float a = 0.f;
    #pragma unroll
    for (int lp = 0; lp < 16; lp++) a += part[((long)b * 16 + lp) * 1024 + c];
    sv[c] = a * (1.f / 576.f);
  }
  __syncthreads();
  int j = t & 7, pt = t >> 3;
  float acc = 0.f;
  int c0 = pt * 32;
  #pragma unroll 8
  for (int c = c0; c < c0 + 32; c++) acc += sv[c] * rwgt[c * 8 + j];
  red[t] = acc;
  __syncthreads();
  if (t < 8) {
    float a = rb[t];
    for (int p = 0; p < 32; p++) a += red[p * 8 + t];
    lg[t] = a;
  }
  __syncthreads();
  if (t == 0) {
    float v[8]; bool sel[8];
    #pragma unroll
    for (int i = 0; i < 8; i++) { v[i] = lg[i]; sel[i] = false; }
    int idxs[4]; float vals[4];
    for (int s = 0; s < 4; s++) {
      int bi = -1; float bv = -1e30f;
      for (int i = 0; i < 8; i++) if (!sel[i] && v[i] > bv) { bv = v[i]; bi = i; }
      sel[bi] = true; idxs[s] = bi; vals[s] = bv;
    }
    float m = vals[0], den = 0.f, e[4];
    for (int s = 0; s < 4; s++) { e[s] = __expf(vals[s] - m); den += e[s]; }
    for (int i = 0; i < 8; i++) rw[b * 8 + i] = 0.f;
    for (int s = 0; s < 4; s++) rw[b * 8 + idxs[s]] = e[s] / den;
  }
  if (b == 0 && t >= 8 && t < 16) {
    int c = t - 8;
    float d1 = 0.f, d2 = 0.f;
    for (int i = 0; i < 8; i++) {
      d1 += lq1[c * 8 + i] * lk1[c * 8 + i];
      d2 += lq2[c * 8 + i] * lk2[c * 8 + i];
    }
    lam[c] = __expf(d1) - __expf(d2) + LAMINIT;
  }
}

// ---------------- MFMA causal differential attention, S^T formulation -------------
// Balanced pr-schedule across 8 (y,wave) workers: max 23 chunk-iters (was 36).
// S^T = K·Q^T; P^T feeds 16x16x16 PV from registers; Q/K rmsnorm fused; exp2 domain.
// LDS 37120 B -> 4 blocks/CU; grid 1024 = exactly 4/CU (one co-resident round).
__global__ __launch_bounds__(256) void k_attn_mfma(
    const bf16* __restrict__ qkv, const float* __restrict__ lam,
    const float* __restrict__ hnw, const float* __restrict__ qn,
    const float* __restrict__ kn, bf16* __restrict__ dc) {
  __shared__ bf16 Ks[576 * 16];
  __shared__ bf16 Vt[16 * 584];
  int tid = threadIdx.x;
  int slice = blockIdx.x; int zc = slice >> 3, b = slice & 7;
  int head = blockIdx.z;
  const bf16* qkvb = qkv + ((long)zc * ROWS + (long)b * Lq) * 384;
  for (int i = tid; i < 1152; i += 256) {
    int row = i >> 1, hf = i & 1;
    gl16(qkvb + (long)row * 384 + 128 + head * 16 + hf * 8, Ks + i * 8);
  }
  for (int i = tid; i < 1152; i += 256) {
    int row = i >> 1, dh = i & 1;
    bf16x8 v = *(const bf16x8*)(qkvb + (long)row * 384 + 256 + head * 16 + dh * 8);
    #pragma unroll
    for (int j = 0; j < 8; j++) Vt[(dh * 8 + j) * 584 + row] = v[j];
  }
  __syncthreads();
  // K rmsnorm in LDS (per 8-elem half)
  {
    float kw[8];
    #pragma unroll
    for (int j = 0; j < 8; j++) kw[j] = kn[zc * 8 + j];
    for (int i = tid; i < 1152; i += 256) {
      bf16x8 kv = *(const bf16x8*)(Ks + i * 8);
      float f[8], s = 0.f;
      #pragma unroll
      for (int j = 0; j < 8; j++) { f[j] = (float)kv[j]; s += f[j] * f[j]; }
      float r = rsqrtf(s * 0.125f + EPS);
      bf16x8 o;
      #pragma unroll
      for (int j = 0; j < 8; j++) o[j] = (bf16)(f[j] * r * kw[j]);
      *(bf16x8*)(Ks + i * 8) = o;
    }
  }
  __syncthreads();
  int wv = tid >> 6, lane = tid & 63;
  int lm = lane & 15, lq = lane >> 4;
  float lamv = lam[zc];
  float hwv[4];
  #pragma unroll
  for (int r = 0; r < 4; r++) hwv[r] = hnw[zc * 16 + lq * 4 + r] * (1.f - LAMINIT);
  float qw[8];
  #pragma unroll
  for (int j = 0; j < 8; j++) qw[j] = qn[zc * 8 + j];
  // balanced schedule: worker u = blockIdx.y*4 + wv
  int u = blockIdx.y * 4 + wv;
  int prA, prB, prC;
  if (u < 6) { prA = u + 2; prB = 17 - u; prC = -1; }
  else       { int v2 = u - 6; prA = v2; prB = 8 + v2; prC = 11 - v2; }
  for (int pi = 0; pi < 3; pi++) {
    int pr = (pi == 0) ? prA : (pi == 1) ? prB : prC;
    if (pr < 0) continue;
    // Q B-frags (normed + pre-scaled by 1/sqrt(8)*log2e); bq0 on quad0, bq1 on quad1
    bf16x8 bq0[2] = {{}, {}}, bq1[2] = {{}, {}};
    if (lq < 2) {
      #pragma unroll
      for (int tile = 0; tile < 2; tile++) {
        bf16x8 t8 = *(const bf16x8*)(
            qkvb + (long)(pr * 32 + tile * 16 + lm) * 384 + head * 16 + lq * 8);
        float f[8], s = 0.f;
        #pragma unroll
        for (int j = 0; j < 8; j++) { f[j] = (float)t8[j]; s += f[j] * f[j]; }
        float r = rsqrtf(s * 0.125f + EPS) * QSCALE_E;
        bf16x8 n;
        #pragma unroll
        for (int j = 0; j < 8; j++) n[j] = (bf16)(f[j] * r * qw[j]);
        if (lq == 0) bq0[tile] = n; else bq1[tile] = n;
      }
    }
    f32x4 o[2][2] = {};
    float den[2][2] = {};
    for (int kc = 0; kc <= pr; kc++) {
      f32x4 sT[2][2][2] = {};   // [t][tile][half]; C-tile: col=q, row=k=lq*4+r
      #pragma unroll
      for (int t = 0; t < 2; t++) {
        bf16x8 aK = {};
        if (lq < 2) aK = *(const bf16x8*)(Ks + (kc * 32 + t * 16 + lm) * 16 + lq * 8);
        #pragma unroll
        for (int tile = 0; tile < 2; tile++) {
          sT[t][tile][0] = __builtin_amdgcn_mfma_f32_16x16x32_bf16(aK, bq0[tile], sT[t][tile][0], 0, 0, 0);
          sT[t][tile][1] = __builtin_amdgcn_mfma_f32_16x16x32_bf16(aK, bq1[tile], sT[t][tile][1], 0, 0, 0);
        }
      }
      bool diag = (kc == pr);
      #pragma unroll
      for (int t = 0; t < 2; t++) {
        bf16x4 aV = *(const bf16x4*)(Vt + lm * 584 + kc * 32 + t * 16 + lq * 4);
        #pragma unroll
        for (int tile = 0; tile < 2; tile++) {
          if (diag && tile == 0 && t == 1) continue;      // fully masked sub-chunk
          bool masked = diag && (tile == t);              // triangular sub-chunk
          #pragma unroll
          for (int h2 = 0; h2 < 2; h2++) {
            bf16x4 pb;
            float dsum = 0.f;
            #pragma unroll
            for (int r = 0; r < 4; r++) {
              float ev = fexp2(sT[t][tile][h2][r]);
              if (masked && (lq * 4 + r > lm)) ev = 0.f;
              dsum += ev;
              pb[r] = (bf16)ev;
            }
            den[tile][h2] += dsum;
            o[tile][h2] = mfma16(aV, pb, o[tile][h2]);    // O^T += V^T · P^T
          }
        }
      }
    }
    #pragma unroll
    for (int tile = 0; tile < 2; tile++)
      #pragma unroll
      for (int h2 = 0; h2 < 2; h2++) {
        den[tile][h2] += __shfl_xor(den[tile][h2], 16);
        den[tile][h2] += __shfl_xor(den[tile][h2], 32);
      }
    #pragma unroll
    for (int tile = 0; tile < 2; tile++) {
      float inv1 = 1.f / den[tile][0];
      float inv2 = lamv / den[tile][1];
      float dff[4]; float ss = 0.f;
      #pragma unroll
      for (int r = 0; r < 4; r++) {
        dff[r] = o[tile][0][r] * inv1 - o[tile][1][r] * inv2;
        ss += dff[r] * dff[r];
      }
      ss += __shfl_xor(ss, 16);
      ss += __shfl_xor(ss, 32);
      float rr = rsqrtf(ss * 0.0625f + EPS);
      bf16x4 outp;
      #pragma unroll
      for (int r = 0; r < 4; r++) outp[r] = (bf16)(dff[r] * rr * hwv[r]);
      long rowg = (long)zc * ROWS + (long)b * Lq + pr * 32 + tile * 16 + lm;
      *(bf16x4*)(dc + rowg * 128 + head * 16 + lq * 4) = outp;
    }
  }
}

// ---------------- seg + pool fused: partials of (h_ch + rmsnorm(op))*rw ----------
// grid (lp=8, b=8, ch=8), 64 threads; writes MP as [b][8][1024] (stride 8).
__global__ __launch_bounds__(64) void k_segpool(const bf16* __restrict__ h,
    const bf16* __restrict__ op, const float* __restrict__ segw,
    const float* __restrict__ rw, float* __restrict__ part) {
  int lp = blockIdx.x, b = blockIdx.y, ch = blockIdx.z;
  int t = threadIdx.x;
  int c0 = t * 2;
  float w0 = segw[ch * 128 + c0], w1 = segw[ch * 128 + c0 + 1];
  float rwv = rw[b * 8 + ch];
  float a0 = 0.f, a1 = 0.f;
  for (int l = 0; l < 72; l++) {
    int row = b * Lq + lp * 72 + l;
    const bf16* oprow = op + (long)ch * ROWS * CW + (long)row * CW;
    bf16x2 yv = *(const bf16x2*)(oprow + c0);
    float y0 = (float)yv[0], y1 = (float)yv[1];
    float ss = y0 * y0 + y1 * y1;
    #pragma unroll
    for (int m = 1; m < 64; m <<= 1) ss += __shfl_xor(ss, m);
    float r = rsqrtf(ss * (1.f / 128.f) + EPS);
    bf16x2 hv = *(const bf16x2*)(h + (long)row * WIDTH + ch * 128 + c0);
    a0 += ((float)hv[0] + y0 * r * w0) * rwv;
    a1 += ((float)hv[1] + y1 * r * w1) * rwv;
  }
  float* dst = part + ((long)b * 8 + lp) * 1024 + ch * 128 + c0;
  dst[0] = a0; dst[1] = a1;
}

// ---------------- head (reads 8 pool partials): out = pooled @ hw + hb ------------
__global__ __launch_bounds__(256) void k_head(const float* __restrict__ part,
    const float* __restrict__ hw, const float* __restrict__ hb, float* __restrict__ out) {
  __shared__ float pool[1024];
  __shared__ float red[256];
  int b = blockIdx.x, t = threadIdx.x;
  for (int c = t; c < 1024; c += 256) {
    float a = 0.f;
    #pragma unroll
    for (int lp = 0; lp < 8; lp++) a += part[((long)b * 8 + lp) * 1024 + c];
    pool[c] = a * (1.f / 576.f);
  }
  __syncthreads();
  int j = t & 15, pt = t >> 4;
  float acc = 0.f;
  if (j < 10)
    for (int c = pt * 64; c < pt * 64 + 64; c++)
      acc += pool[c] * hw[c * 10 + j];
  red[t] = acc;
  __syncthreads();
  if (t < 10) {
    float a = hb[t];
    for (int p = 0; p < 16; p++) a += red[p * 16 + t];
    out[b * 10 + t] = a;
  }
}

// ---------------- launcher ----------------
extern "C" void kernel_launch(void* const* d_in, const int* in_sizes, int n_in,
                              void* d_out, int out_size, void* d_ws, size_t ws_size,
                              hipStream_t stream) {
  const float* x          = (const float*)d_in[0];
  const float* pixel_embed= (const float*)d_in[2];
  const float* freq_h     = (const float*)d_in[3];
  const float* freq_w     = (const float*)d_in[4];
  const float* phase_h    = (const float*)d_in[5];
  const float* phase_w    = (const float*)d_in[6];
  const float* pos_proj_w = (const float*)d_in[7];
  const float* pos_proj_b = (const float*)d_in[8];
  const float* embed_norm = (const float*)d_in[9];
  const float* se_w1      = (const float*)d_in[10];
  const float* se_b1      = (const float*)d_in[11];
  const float* se_w2      = (const float*)d_in[12];
  const float* se_b2      = (const float*)d_in[13];
  const float* mix_norm   = (const float*)d_in[14];
  const float* mlp_w1     = (const float*)d_in[15];
  const float* mlp_b1     = (const float*)d_in[16];
  const float* mlp_w2     = (const float*)d_in[17];
  const float* mlp_b2     = (const float*)d_in[18];
  const float* mlp_norm   = (const float*)d_in[19];
  const float* router_w   = (const float*)d_in[20];
  const float* router_b   = (const float*)d_in[21];
  const float* qkv_w      = (const float*)d_in[22];
  const float* qkv_b      = (const float*)d_in[23];
  const float* q_norm_w   = (const float*)d_in[24];
  const float* k_norm_w   = (const float*)d_in[25];
  const float* head_norm_w= (const float*)d_in[26];
  const float* lam_q1     = (const float*)d_in[27];
  const float* lam_k1     = (const float*)d_in[28];
  const float* lam_q2     = (const float*)d_in[29];
  const float* lam_k2     = (const float*)d_in[30];
  const float* out_w      = (const float*)d_in[31];
  const float* out_b      = (const float*)d_in[32];
  const float* seg_norm_w = (const float*)d_in[33];
  const float* head_w     = (const float*)d_in[34];
  const float* head_b     = (const float*)d_in[35];

  char* W = (char*)d_ws;
  bf16*  HB    = (bf16*)(W + B_HB);
  bf16*  G2B   = (bf16*)(W + B_G2B);
  bf16*  ENCB  = (bf16*)(W + B_ENCB);
  bf16*  POSWT = (bf16*)(W + B_POSWT);
  bf16*  QKVWT = (bf16*)(W + B_QKVWT);
  bf16*  OWT   = (bf16*)(W + B_OWT);
  float* SE    = (float*)(W + B_SE);
  float* T1    = (float*)(W + B_T1);
  float* MP    = (float*)(W + B_MP);
  float* RW    = (float*)(W + B_RW);
  float* LAM   = (float*)(W + B_LAM);
  char*  P     = W + B_POOL;
  float* POS   = (float*)P;
  bf16*  W1T   = (bf16*)P;
  bf16*  W2T   = (bf16*)(P + 8388608);
  bf16*  HID   = (bf16*)(P + 16777216);
  bf16*  QKV   = (bf16*)P;
  bf16*  DC    = (bf16*)(P + 28311552);
  float* out   = (float*)d_out;

  // 1. positional encoding -> bf16, weight cast, gemm -> POS (f32)
  k_enc_b<<<288, 256, 0, stream>>>(freq_h, freq_w, phase_h, phase_w, ENCB);
  k_tcast<<<dim3(32, 4, 1), 256, 0, stream>>>(pos_proj_w, POSWT, 128, 1024);
  gemm64<0, 0, 0><<<dim3(8, 10, 1), 256, 0, stream>>>(
      ENCB, 128, 0, POSWT, 128, 0, pos_proj_b, 0, POS, 1024, 0, 640, 1024, 128);
  // 2. embed + rmsnorm -> bf16 h
  k_embed<<<ROWS, 256, 0, stream>>>(x, pixel_embed, POS, embed_norm, HB);
  // 3. SE gate
  k_meanl_p<<<dim3(16, 8), 256, 0, stream>>>(HB, MP);
  k_se1<<<dim3(32, 8), 256, 0, stream>>>(MP, se_w1, se_b1, T1);
  k_se2<<<dim3(32, 8), 256, 0, stream>>>(T1, se_w2, se_b2, SE);
  k_mix_b<<<ROWS, 256, 0, stream>>>(HB, SE, mix_norm);
  // 4. MLP: split along hidden dim (2 halves of 2048), bf16 MFMA
  k_tcast<<<dim3(128, 32, 1), 256, 0, stream>>>(mlp_w1, W1T, 1024, 4096);
  k_tcast<<<dim3(32, 128, 1), 256, 0, stream>>>(mlp_w2, W2T, 4096, 1024);
  gemm_bt<1, 1><<<dim3(16, 36, 1), 256, 0, stream>>>(
      HB, 1024, 0, W1T, 0, mlp_b1, 0, HID, 2048, 0, 4608, 2048, 1024);
  gemm64<0, 1, 0><<<dim3(8, 72, 1), 256, 0, stream>>>(
      HID, 2048, 0, W2T, 4096, 0, mlp_b2, 0, G2B, 1024, 0, 4608, 1024, 2048);
  gemm_bt<1, 1><<<dim3(16, 36, 1), 256, 0, stream>>>(
      HB, 1024, 0, W1T + 2048L * 1024, 0, mlp_b1 + 2048, 0, HID, 2048, 0, 4608, 2048, 1024);
  gemm64<0, 1, 1><<<dim3(8, 72, 1), 256, 0, stream>>>(
      HID, 2048, 0, W2T + 2048, 4096, 0, nullptr, 0, G2B, 1024, 0, 4608, 1024, 2048);
  k_addnorm_b<<<ROWS, 256, 0, stream>>>(HB, G2B, mlp_norm);
  // 5. router + lambdas
  k_meanl_p<<<dim3(16, 8), 256, 0, stream>>>(HB, MP);
  k_router<<<8, 256, 0, stream>>>(MP, router_w, router_b,
                                  lam_q1, lam_k1, lam_q2, lam_k2, RW, LAM);
  // 6. channel weights cast
  k_tcast<<<dim3(12, 4, 8), 256, 0, stream>>>(qkv_w, QKVWT, 128, 384);
  k_tcast<<<dim3(4, 4, 8), 256, 0, stream>>>(out_w, OWT, 128, 128);
  // 7. all 8 channels: qkv-proj, fused attention (q/k-norm inside), out-proj in-place
  gemm64<1, 1, 0><<<dim3(3, 72, 8), 256, 0, stream>>>(
      HB, 1024, CW, QKVWT, 128, 384 * 128, qkv_b, 384,
      QKV, 384, (long)ROWS * 384, ROWS, 384, 128);
  k_attn_mfma<<<dim3(64, 2, 8), 256, 0, stream>>>(
      QKV, LAM, head_norm_w, q_norm_w, k_norm_w, DC);
  gemm64<1, 1, 0><<<dim3(1, 72, 8), 256, 0, stream>>>(
      DC, 128, (long)ROWS * 128, OWT, 128, 128 * 128, out_b, 128,
      DC, 128, (long)ROWS * 128, ROWS, 128, 128);
  // 8. seg + pool fused -> partials; head folds the final reduce
  k_segpool<<<dim3(8, 8, 8), 64, 0, stream>>>(HB, DC, seg_norm_w, RW, MP);
  k_head<<<8, 256, 0, stream>>>(MP, head_w, head_b, out);
}